// Round 1
// baseline (7075.880 us; speedup 1.0000x reference)
//
#include <hip/hip_runtime.h>
#include <math.h>

#define HH 128
#define WW 128
#define HWSZ 16384   // 128*128
#define CC 256
#define KK 64
#define BB 2

__device__ __forceinline__ float silu_f(float v) { return v / (1.f + expf(-v)); }
__device__ __forceinline__ float sigm_f(float v) { return 1.f / (1.f + expf(-v)); }

// ---------------------------------------------------------------------------
// 1. Normalize tracklets: tn[b,k,:] = trk / max(||trk||, 1e-12)
// ---------------------------------------------------------------------------
__global__ __launch_bounds__(128) void tnorm_kernel(const float* __restrict__ trk,
                                                    float* __restrict__ tn) {
    int r = threadIdx.x;            // 0..127 -> (b,k)
    if (r >= BB * KK) return;
    const float* p = trk + (size_t)r * CC;
    float ss = 0.f;
    for (int c = 0; c < CC; c++) { float v = p[c]; ss += v * v; }
    float sc = 1.f / fmaxf(sqrtf(ss), 1e-12f);
    float* q = tn + (size_t)r * CC;
    for (int c = 0; c < CC; c++) q[c] = p[c] * sc;
}

// ---------------------------------------------------------------------------
// 2. y[b,k,hw] = relu( dot(e_norm[pix], tn[b,k]) ).  One wave per pixel.
// ---------------------------------------------------------------------------
__global__ __launch_bounds__(256) void y_kernel(const float* __restrict__ emb,
                                                const float* __restrict__ tn,
                                                float* __restrict__ y) {
    int wave = threadIdx.x >> 6;
    int lane = threadIdx.x & 63;
    int pix  = blockIdx.x * 4 + wave;          // 0..32767 = b*16384 + hw
    int b    = pix >> 14;
    int hw   = pix & (HWSZ - 1);

    __shared__ __align__(16) float els[4][CC];

    const float4* e4 = (const float4*)(emb + (size_t)pix * CC);
    float4 ev = e4[lane];
    float ss = ev.x * ev.x + ev.y * ev.y + ev.z * ev.z + ev.w * ev.w;
    #pragma unroll
    for (int d = 1; d < 64; d <<= 1) ss += __shfl_xor(ss, d);
    float sc = 1.f / fmaxf(sqrtf(ss), 1e-12f);
    ((float4*)els[wave])[lane] = make_float4(ev.x * sc, ev.y * sc, ev.z * sc, ev.w * sc);
    __syncthreads();

    // lane == tracklet index k
    const float4* t4  = (const float4*)(tn + ((size_t)b * KK + lane) * CC);
    const float4* el4 = (const float4*)els[wave];
    float acc = 0.f;
    #pragma unroll 8
    for (int c4 = 0; c4 < CC / 4; c4++) {
        float4 t = t4[c4];
        float4 e = el4[c4];
        acc = fmaf(e.x, t.x, acc);
        acc = fmaf(e.y, t.y, acc);
        acc = fmaf(e.z, t.z, acc);
        acc = fmaf(e.w, t.w, acc);
    }
    y[((size_t)b * KK + lane) * HWSZ + hw] = fmaxf(acc, 0.f);
}

// ---------------------------------------------------------------------------
// 3. First-occurrence argmax over HW per (b,k).
// ---------------------------------------------------------------------------
__global__ __launch_bounds__(256) void argmax_kernel(const float* __restrict__ y,
                                                     int* __restrict__ idxout) {
    int bk = blockIdx.x;                       // 0..127
    const float* p = y + (size_t)bk * HWSZ;
    int t = threadIdx.x;
    float best = -1.f; int bi = 1 << 30;
    for (int i = t; i < HWSZ; i += 256) {      // increasing i -> first max per thread
        float v = p[i];
        if (v > best) { best = v; bi = i; }
    }
    __shared__ float sv[256];
    __shared__ int   si[256];
    sv[t] = best; si[t] = bi;
    __syncthreads();
    for (int s = 128; s > 0; s >>= 1) {
        if (t < s) {
            float v2 = sv[t + s]; int i2 = si[t + s];
            if (v2 > sv[t] || (v2 == sv[t] && i2 < si[t])) { sv[t] = v2; si[t] = i2; }
        }
        __syncthreads();
    }
    if (t == 0) idxout[bk] = si[0];
}

// ---------------------------------------------------------------------------
// 4. s[b,hw] = sum_k y[b,k,hw] * in_box(k)
// ---------------------------------------------------------------------------
__global__ __launch_bounds__(256) void smap_kernel(const float* __restrict__ y,
                                                   const int* __restrict__ idx,
                                                   float* __restrict__ s) {
    int b  = blockIdx.y;
    int hw = blockIdx.x * 256 + threadIdx.x;
    int h  = hw >> 7, w = hw & 127;
    __shared__ int ai[KK], aj[KK];
    if (threadIdx.x < KK) {
        int v = idx[b * KK + threadIdx.x];
        ai[threadIdx.x] = v >> 7;
        aj[threadIdx.x] = v & 127;
    }
    __syncthreads();
    const float* yb = y + (size_t)b * KK * HWSZ;
    float acc = 0.f;
    #pragma unroll 8
    for (int k = 0; k < KK; k++) {
        float v = yb[(size_t)k * HWSZ + hw];
        bool in = (h >= ai[k] - 8) && (h < ai[k] + 8) && (w >= aj[k] - 8) && (w < aj[k] + 8);
        acc += in ? v : 0.f;
    }
    s[(size_t)b * HWSZ + hw] = acc;
}

// ---------------------------------------------------------------------------
// 5. invmax[b] = 1 / max(s[b,:])
// ---------------------------------------------------------------------------
__global__ __launch_bounds__(256) void smax_kernel(const float* __restrict__ s,
                                                   float* __restrict__ invmax) {
    int b = blockIdx.x;
    const float* p = s + (size_t)b * HWSZ;
    float m = -1e30f;
    for (int i = threadIdx.x; i < HWSZ; i += 256) m = fmaxf(m, p[i]);
    __shared__ float sm[256];
    sm[threadIdx.x] = m;
    __syncthreads();
    for (int st = 128; st > 0; st >>= 1) {
        if (threadIdx.x < st) sm[threadIdx.x] = fmaxf(sm[threadIdx.x], sm[threadIdx.x + st]);
        __syncthreads();
    }
    if (threadIdx.x == 0) invmax[b] = 1.f / sm[0];
}

// ---------------------------------------------------------------------------
// 6. Grouped deconvs (lhs-dilated convs): out = b2 + b3.
//    b2: ConvT(2CB->CB, k4, s2, p1, g=CB);  b3: ConvT(4CB->CB, k8, s4, p2, g=CB)
// ---------------------------------------------------------------------------
__global__ __launch_bounds__(256) void deconv_kernel(const float* __restrict__ l1,
                                                     const float* __restrict__ l2,
                                                     const float* __restrict__ w2,
                                                     const float* __restrict__ w3,
                                                     float* __restrict__ out) {
    int x = blockIdx.x * 32 + threadIdx.x;
    int y = blockIdx.y * 8 + threadIdx.y;
    int g = blockIdx.z & 255;
    int b = blockIdx.z >> 8;

    float acc = 0.f;

    // ---- b2: kernel 4, lhs_dil 2, pad 2.  taps p in {p0, p0+2}, p0 = v&1,
    //      m = (v + p - 2)/2 in [0,64)
    {
        const float* l1b = l1 + ((size_t)b * 2 * CC + 2 * g) * 4096; // 64*64
        const float* w2g = w2 + (size_t)g * 32;                      // [2][4][4]
        int pyo = y & 1, pxo = x & 1;
        int my0 = (y + pyo - 2) >> 1;
        int mx0 = (x + pxo - 2) >> 1;
        #pragma unroll
        for (int i = 0; i < 2; i++) {
            const float* li = l1b + (size_t)i * 4096;
            const float* wi = w2g + i * 16;
            #pragma unroll
            for (int a = 0; a < 2; a++) {
                int m = my0 + a;
                if ((unsigned)m >= 64u) continue;
                int p = pyo + 2 * a;
                #pragma unroll
                for (int c = 0; c < 2; c++) {
                    int n = mx0 + c;
                    if ((unsigned)n >= 64u) continue;
                    int q = pxo + 2 * c;
                    acc = fmaf(wi[p * 4 + q], li[m * 64 + n], acc);
                }
            }
        }
    }

    // ---- b3: kernel 8, lhs_dil 4, pad 5.  p in {p0, p0+4}, p0 = (5-(v&3))&3,
    //      m = (v + p - 5)/4 in [0,32)
    {
        const float* l2b = l2 + ((size_t)b * 4 * CC + 4 * g) * 1024; // 32*32
        const float* w3g = w3 + (size_t)g * 256;                     // [4][8][8]
        int py3 = (5 - (y & 3)) & 3, px3 = (5 - (x & 3)) & 3;
        int my0 = (y + py3 - 5) >> 2;
        int mx0 = (x + px3 - 5) >> 2;
        #pragma unroll
        for (int i = 0; i < 4; i++) {
            const float* li = l2b + (size_t)i * 1024;
            const float* wi = w3g + i * 64;
            #pragma unroll
            for (int a = 0; a < 2; a++) {
                int m = my0 + a;
                if ((unsigned)m >= 32u) continue;
                int p = py3 + 4 * a;
                #pragma unroll
                for (int c = 0; c < 2; c++) {
                    int n = mx0 + c;
                    if ((unsigned)n >= 32u) continue;
                    int q = px3 + 4 * c;
                    acc = fmaf(wi[p * 8 + q], li[m * 32 + n], acc);
                }
            }
        }
    }

    out[(((size_t)b * CC + g) * HWSZ) + y * WW + x] = acc;
}

// ---------------------------------------------------------------------------
// 7. Big 3x3 conv 256->256, fp32 direct, LDS input tiling, 16 co per thread.
//    EP=0: out = silu(acc+bias);  EP=1: out = silu(acc+bias) + addb
// ---------------------------------------------------------------------------
template <int EP>
__global__ __launch_bounds__(256) void conv_big_kernel(const float* __restrict__ in,
                                                       const float* __restrict__ w,
                                                       const float* __restrict__ bias,
                                                       const float* __restrict__ addb,
                                                       float* __restrict__ out) {
    const int tx = threadIdx.x, ty = threadIdx.y;
    const int x = blockIdx.x * 32 + tx, y = blockIdx.y * 8 + ty;
    const int b = blockIdx.z >> 4;
    const int co0 = (blockIdx.z & 15) << 4;
    const int x0 = blockIdx.x * 32 - 1, y0 = blockIdx.y * 8 - 1;

    __shared__ float lds[8][10][34];

    float acc[16];
    #pragma unroll
    for (int j = 0; j < 16; j++) acc[j] = 0.f;

    const int tid = ty * 32 + tx;
    const float* inB = in + (size_t)b * CC * HWSZ;

    for (int ci0 = 0; ci0 < CC; ci0 += 8) {
        for (int e = tid; e < 8 * 10 * 34; e += 256) {
            int cl = e / 340, rem = e % 340;
            int yy = rem / 34, xx = rem % 34;
            int gy = y0 + yy, gx = x0 + xx;
            float v = 0.f;
            if ((unsigned)gy < 128u && (unsigned)gx < 128u)
                v = inB[(size_t)(ci0 + cl) * HWSZ + gy * WW + gx];
            lds[cl][yy][xx] = v;
        }
        __syncthreads();
        #pragma unroll
        for (int cl = 0; cl < 8; cl++) {
            float i00 = lds[cl][ty][tx],     i01 = lds[cl][ty][tx + 1],     i02 = lds[cl][ty][tx + 2];
            float i10 = lds[cl][ty + 1][tx], i11 = lds[cl][ty + 1][tx + 1], i12 = lds[cl][ty + 1][tx + 2];
            float i20 = lds[cl][ty + 2][tx], i21 = lds[cl][ty + 2][tx + 1], i22 = lds[cl][ty + 2][tx + 2];
            const float* wp = w + ((size_t)co0 * CC + (ci0 + cl)) * 9;
            #pragma unroll
            for (int j = 0; j < 16; j++) {
                const float* wj = wp + (size_t)j * CC * 9;
                acc[j] = fmaf(i00, wj[0], acc[j]);
                acc[j] = fmaf(i01, wj[1], acc[j]);
                acc[j] = fmaf(i02, wj[2], acc[j]);
                acc[j] = fmaf(i10, wj[3], acc[j]);
                acc[j] = fmaf(i11, wj[4], acc[j]);
                acc[j] = fmaf(i12, wj[5], acc[j]);
                acc[j] = fmaf(i20, wj[6], acc[j]);
                acc[j] = fmaf(i21, wj[7], acc[j]);
                acc[j] = fmaf(i22, wj[8], acc[j]);
            }
        }
        __syncthreads();
    }

    size_t obase = ((size_t)b * CC + co0) * HWSZ + (size_t)y * WW + x;
    #pragma unroll
    for (int j = 0; j < 16; j++) {
        float v = silu_f(acc[j] + bias[co0 + j]);
        if (EP == 1) v += addb[obase + (size_t)j * HWSZ];
        out[obase + (size_t)j * HWSZ] = v;
    }
}

// ---------------------------------------------------------------------------
// 8. conv 1->256 (input = s * invmax), + bias, silu
// ---------------------------------------------------------------------------
__global__ __launch_bounds__(256) void conv_c1a_kernel(const float* __restrict__ s,
                                                       const float* __restrict__ invmax,
                                                       const float* __restrict__ w,
                                                       const float* __restrict__ bias,
                                                       float* __restrict__ out) {
    int x = blockIdx.x * 32 + threadIdx.x;
    int y = blockIdx.y * 8 + threadIdx.y;
    int co = blockIdx.z & 255;
    int b  = blockIdx.z >> 8;
    float im = invmax[b];
    const float* sb = s + (size_t)b * HWSZ;
    const float* wp = w + (size_t)co * 9;
    float sum = 0.f;
    #pragma unroll
    for (int dy = 0; dy < 3; dy++) {
        int yy = y + dy - 1;
        if ((unsigned)yy >= 128u) continue;
        #pragma unroll
        for (int dx = 0; dx < 3; dx++) {
            int xx = x + dx - 1;
            if ((unsigned)xx >= 128u) continue;
            sum = fmaf(wp[dy * 3 + dx], sb[yy * WW + xx], sum);
        }
    }
    float v = silu_f(sum * im + bias[co]);
    out[(((size_t)b * CC + co) * HWSZ) + y * WW + x] = v;
}

// ---------------------------------------------------------------------------
// 9. conv 256->1 (+bias, optional sigmoid)
// ---------------------------------------------------------------------------
template <int SIG>
__global__ __launch_bounds__(256) void conv_256to1_kernel(const float* __restrict__ in,
                                                          const float* __restrict__ w,
                                                          const float* __restrict__ bias,
                                                          float* __restrict__ out) {
    int x = blockIdx.x * 32 + threadIdx.x;
    int y = blockIdx.y * 8 + threadIdx.y;
    int b = blockIdx.z;
    const float* ib = in + (size_t)b * CC * HWSZ;
    float acc = 0.f;
    for (int ci = 0; ci < CC; ci++) {
        const float* wp = w + (size_t)ci * 9;
        const float* ip = ib + (size_t)ci * HWSZ;
        #pragma unroll
        for (int dy = 0; dy < 3; dy++) {
            int yy = y + dy - 1;
            if ((unsigned)yy >= 128u) continue;
            #pragma unroll
            for (int dx = 0; dx < 3; dx++) {
                int xx = x + dx - 1;
                if ((unsigned)xx >= 128u) continue;
                acc = fmaf(wp[dy * 3 + dx], ip[yy * WW + xx], acc);
            }
        }
    }
    acc += bias[0];
    if (SIG) acc = sigm_f(acc);
    out[(size_t)b * HWSZ + y * WW + x] = acc;
}

// ---------------------------------------------------------------------------
// 10. t[b,c,hw] = xf[b,hw] * xd[b,c,hw]   (float4 over hw)
// ---------------------------------------------------------------------------
__global__ __launch_bounds__(256) void mul_kernel(const float* __restrict__ xf,
                                                  const float* __restrict__ xd,
                                                  float* __restrict__ out) {
    int i = blockIdx.x * 256 + threadIdx.x;     // 0 .. 2*256*4096-1
    int b = i >> 20;
    int hw4 = i & 4095;
    float4 d = ((const float4*)xd)[i];
    float4 f = ((const float4*)xf)[(size_t)b * 4096 + hw4];
    ((float4*)out)[i] = make_float4(d.x * f.x, d.y * f.y, d.z * f.z, d.w * f.w);
}

// ---------------------------------------------------------------------------
// 11. conv 256->4 + bias, NHWC output (the transpose in the reference)
// ---------------------------------------------------------------------------
__global__ __launch_bounds__(256) void conv_c2box_kernel(const float* __restrict__ in,
                                                         const float* __restrict__ w,
                                                         const float* __restrict__ bias,
                                                         float* __restrict__ out) {
    int x = blockIdx.x * 32 + threadIdx.x;
    int y = blockIdx.y * 8 + threadIdx.y;
    int b = blockIdx.z;
    const float* ib = in + (size_t)b * CC * HWSZ;
    float a0 = 0.f, a1 = 0.f, a2 = 0.f, a3 = 0.f;
    for (int ci = 0; ci < CC; ci++) {
        float iv[9];
        #pragma unroll
        for (int dy = 0; dy < 3; dy++) {
            #pragma unroll
            for (int dx = 0; dx < 3; dx++) {
                int yy = y + dy - 1, xx = x + dx - 1;
                iv[dy * 3 + dx] = ((unsigned)yy < 128u && (unsigned)xx < 128u)
                                      ? ib[(size_t)ci * HWSZ + yy * WW + xx] : 0.f;
            }
        }
        const float* w0 = w + (size_t)(0 * CC + ci) * 9;
        const float* w1 = w + (size_t)(1 * CC + ci) * 9;
        const float* w2 = w + (size_t)(2 * CC + ci) * 9;
        const float* w3 = w + (size_t)(3 * CC + ci) * 9;
        #pragma unroll
        for (int t = 0; t < 9; t++) {
            a0 = fmaf(iv[t], w0[t], a0);
            a1 = fmaf(iv[t], w1[t], a1);
            a2 = fmaf(iv[t], w2[t], a2);
            a3 = fmaf(iv[t], w3[t], a3);
        }
    }
    float4 r = make_float4(a0 + bias[0], a1 + bias[1], a2 + bias[2], a3 + bias[3]);
    ((float4*)out)[(size_t)b * HWSZ + y * WW + x] = r;
}

// ---------------------------------------------------------------------------
extern "C" void kernel_launch(void* const* d_in, const int* in_sizes, int n_in,
                              void* d_out, int out_size, void* d_ws, size_t ws_size,
                              hipStream_t stream) {
    const float* emb    = (const float*)d_in[0];
    const float* trk    = (const float*)d_in[1];
    const float* l0     = (const float*)d_in[2];
    const float* l1     = (const float*)d_in[3];
    const float* l2     = (const float*)d_in[4];
    const float* b_p1w  = (const float*)d_in[5];
    const float* b_p1b  = (const float*)d_in[6];
    const float* b_p2w  = (const float*)d_in[7];
    const float* b_p3w  = (const float*)d_in[8];
    const float* b_c1w  = (const float*)d_in[9];
    const float* b_c1b  = (const float*)d_in[10];
    const float* b_c2w  = (const float*)d_in[11];
    const float* b_c2b  = (const float*)d_in[12];
    const float* h_p1w  = (const float*)d_in[13];
    const float* h_p1b  = (const float*)d_in[14];
    const float* h_p2w  = (const float*)d_in[15];
    const float* h_p3w  = (const float*)d_in[16];
    const float* h_c1aw = (const float*)d_in[17];
    const float* h_c1ab = (const float*)d_in[18];
    const float* h_c1bw = (const float*)d_in[19];
    const float* h_c1bb = (const float*)d_in[20];
    const float* h_c2aw = (const float*)d_in[21];
    const float* h_c2ab = (const float*)d_in[22];
    const float* h_c2bw = (const float*)d_in[23];
    const float* h_c2bb = (const float*)d_in[24];
    const float* h_c2cw = (const float*)d_in[25];
    const float* h_c2cb = (const float*)d_in[26];

    float* outp = (float*)d_out;            // [0,32768): hmmap ; [32768,163840): siambox NHWC

    // workspace carve-up (~67.5 MB)
    const size_t BIG = (size_t)BB * CC * HWSZ;     // 8,388,608 floats
    float* bufA = (float*)d_ws;
    float* bufB = bufA + BIG;
    float* tn     = bufB + BIG;                    // 32768
    float* sbuf   = tn + (size_t)BB * KK * CC;     // 32768
    float* xfb    = sbuf + (size_t)BB * HWSZ;      // 32768
    float* invmax = xfb + (size_t)BB * HWSZ;       // 2
    int*   idxb   = (int*)(invmax + 2);            // 128 ints
    float* ybuf   = bufB;                          // alias: y used only before conv phase

    dim3 blk2d(32, 8);
    dim3 grdConv(4, 16, 32);       // big convs: 16 co-tiles * B
    dim3 grdPerBC(4, 16, BB * CC); // per (b, channel)
    dim3 grdPerB(4, 16, BB);

    // ---- correlation map ----
    tnorm_kernel<<<1, 128, 0, stream>>>(trk, tn);
    y_kernel<<<8192, 256, 0, stream>>>(emb, tn, ybuf);
    argmax_kernel<<<BB * KK, 256, 0, stream>>>(ybuf, idxb);
    smap_kernel<<<dim3(64, BB), 256, 0, stream>>>(ybuf, idxb, sbuf);
    smax_kernel<<<BB, 256, 0, stream>>>(sbuf, invmax);

    // ---- box head ----
    deconv_kernel<<<grdPerBC, blk2d, 0, stream>>>(l1, l2, b_p2w, b_p3w, bufA);
    conv_big_kernel<1><<<grdConv, blk2d, 0, stream>>>(l0, b_p1w, b_p1b, bufA, bufB);   // xd_box
    conv_big_kernel<0><<<grdConv, blk2d, 0, stream>>>(bufB, b_c1w, b_c1b, nullptr, bufA); // xb
    conv_c2box_kernel<<<grdPerB, blk2d, 0, stream>>>(bufA, b_c2w, b_c2b, outp + BB * HWSZ);

    // ---- heatmap head ----
    deconv_kernel<<<grdPerBC, blk2d, 0, stream>>>(l1, l2, h_p2w, h_p3w, bufB);
    conv_big_kernel<1><<<grdConv, blk2d, 0, stream>>>(l0, h_p1w, h_p1b, bufB, bufA);   // xd_hm
    conv_c1a_kernel<<<grdPerBC, blk2d, 0, stream>>>(sbuf, invmax, h_c1aw, h_c1ab, bufB); // t1
    conv_256to1_kernel<0><<<grdPerB, blk2d, 0, stream>>>(bufB, h_c1bw, h_c1bb, xfb);   // xf
    mul_kernel<<<8192, 256, 0, stream>>>(xfb, bufA, bufB);                              // t
    conv_big_kernel<0><<<grdConv, blk2d, 0, stream>>>(bufB, h_c2aw, h_c2ab, nullptr, bufA); // t2
    conv_big_kernel<0><<<grdConv, blk2d, 0, stream>>>(bufA, h_c2bw, h_c2bb, nullptr, bufB); // t3
    conv_256to1_kernel<1><<<grdPerB, blk2d, 0, stream>>>(bufB, h_c2cw, h_c2cb, outp);  // hmmap
}

// Round 2
// 2383.615 us; speedup vs baseline: 2.9686x; 2.9686x over previous
//
#include <hip/hip_runtime.h>
#include <math.h>

#define HH 128
#define WW 128
#define HWSZ 16384   // 128*128
#define CC 256
#define KK 64
#define BB 2

typedef __bf16 bf16x8_t __attribute__((ext_vector_type(8)));
typedef float  f32x4_t  __attribute__((ext_vector_type(4)));

__device__ __forceinline__ float silu_f(float v) { return v / (1.f + expf(-v)); }
__device__ __forceinline__ float sigm_f(float v) { return 1.f / (1.f + expf(-v)); }

__device__ __forceinline__ float b2f(unsigned short u) {
    union { unsigned int i; float f; } x; x.i = ((unsigned int)u) << 16; return x.f;
}
__device__ __forceinline__ unsigned short f2b(float f) {
    union { float f; unsigned int i; } x; x.f = f;
    unsigned int r = x.i + 0x7FFFu + ((x.i >> 16) & 1u);
    return (unsigned short)(r >> 16);
}

// ---------------------------------------------------------------------------
// prep: fp32 -> bf16 copy (8 elems/thread)
// ---------------------------------------------------------------------------
__global__ __launch_bounds__(256) void cvtbf_kernel(const float* __restrict__ in,
                                                    unsigned short* __restrict__ out) {
    size_t i = ((size_t)blockIdx.x * 256 + threadIdx.x) * 8;
    float4 a = *(const float4*)(in + i);
    float4 b = *(const float4*)(in + i + 4);
    union { unsigned short u[8]; uint4 v; } pk;
    pk.u[0] = f2b(a.x); pk.u[1] = f2b(a.y); pk.u[2] = f2b(a.z); pk.u[3] = f2b(a.w);
    pk.u[4] = f2b(b.x); pk.u[5] = f2b(b.y); pk.u[6] = f2b(b.z); pk.u[7] = f2b(b.w);
    *(uint4*)(out + i) = pk.v;
}

// ---------------------------------------------------------------------------
// prep: weights OIHW fp32 [256][256][3][3] -> bf16 [9][8][256][32]
// wt[((t*8+cb)*256 + co)*32 + ci] = w[(co*256 + cb*32+ci)*9 + t]
// ---------------------------------------------------------------------------
__global__ __launch_bounds__(256) void wprep_kernel(const float* __restrict__ w,
                                                    unsigned short* __restrict__ wt) {
    int idx = blockIdx.x * 256 + threadIdx.x;       // 0 .. 589823
    int ci  = idx & 31;
    int co  = (idx >> 5) & 255;
    int tcb = idx >> 13;                            // 0..71
    int t   = tcb >> 3;
    int cb  = tcb & 7;
    wt[idx] = f2b(w[((size_t)co * 256 + cb * 32 + ci) * 9 + t]);
}

// ---------------------------------------------------------------------------
// tracklet normalize
// ---------------------------------------------------------------------------
__global__ __launch_bounds__(128) void tnorm_kernel(const float* __restrict__ trk,
                                                    float* __restrict__ tn) {
    int r = threadIdx.x;
    if (r >= BB * KK) return;
    const float* p = trk + (size_t)r * CC;
    float ss = 0.f;
    for (int c = 0; c < CC; c++) { float v = p[c]; ss += v * v; }
    float sc = 1.f / fmaxf(sqrtf(ss), 1e-12f);
    float* q = tn + (size_t)r * CC;
    for (int c = 0; c < CC; c++) q[c] = p[c] * sc;
}

// ---------------------------------------------------------------------------
// y[b,k,hw] = relu(dot(e_norm, tn))
// ---------------------------------------------------------------------------
__global__ __launch_bounds__(256) void y_kernel(const float* __restrict__ emb,
                                                const float* __restrict__ tn,
                                                float* __restrict__ y) {
    int wave = threadIdx.x >> 6;
    int lane = threadIdx.x & 63;
    int pix  = blockIdx.x * 4 + wave;
    int b    = pix >> 14;
    int hw   = pix & (HWSZ - 1);

    __shared__ __align__(16) float els[4][CC];

    const float4* e4 = (const float4*)(emb + (size_t)pix * CC);
    float4 ev = e4[lane];
    float ss = ev.x * ev.x + ev.y * ev.y + ev.z * ev.z + ev.w * ev.w;
    #pragma unroll
    for (int d = 1; d < 64; d <<= 1) ss += __shfl_xor(ss, d);
    float sc = 1.f / fmaxf(sqrtf(ss), 1e-12f);
    ((float4*)els[wave])[lane] = make_float4(ev.x * sc, ev.y * sc, ev.z * sc, ev.w * sc);
    __syncthreads();

    const float4* t4  = (const float4*)(tn + ((size_t)b * KK + lane) * CC);
    const float4* el4 = (const float4*)els[wave];
    float acc = 0.f;
    #pragma unroll 8
    for (int c4 = 0; c4 < CC / 4; c4++) {
        float4 t = t4[c4];
        float4 e = el4[c4];
        acc = fmaf(e.x, t.x, acc);
        acc = fmaf(e.y, t.y, acc);
        acc = fmaf(e.z, t.z, acc);
        acc = fmaf(e.w, t.w, acc);
    }
    y[((size_t)b * KK + lane) * HWSZ + hw] = fmaxf(acc, 0.f);
}

// ---------------------------------------------------------------------------
// first-occurrence argmax per (b,k)
// ---------------------------------------------------------------------------
__global__ __launch_bounds__(256) void argmax_kernel(const float* __restrict__ y,
                                                     int* __restrict__ idxout) {
    int bk = blockIdx.x;
    const float* p = y + (size_t)bk * HWSZ;
    int t = threadIdx.x;
    float best = -1.f; int bi = 1 << 30;
    for (int i = t; i < HWSZ; i += 256) {
        float v = p[i];
        if (v > best) { best = v; bi = i; }
    }
    __shared__ float sv[256];
    __shared__ int   si[256];
    sv[t] = best; si[t] = bi;
    __syncthreads();
    for (int s = 128; s > 0; s >>= 1) {
        if (t < s) {
            float v2 = sv[t + s]; int i2 = si[t + s];
            if (v2 > sv[t] || (v2 == sv[t] && i2 < si[t])) { sv[t] = v2; si[t] = i2; }
        }
        __syncthreads();
    }
    if (t == 0) idxout[bk] = si[0];
}

// ---------------------------------------------------------------------------
// s[b,hw] = sum_k y * mask
// ---------------------------------------------------------------------------
__global__ __launch_bounds__(256) void smap_kernel(const float* __restrict__ y,
                                                   const int* __restrict__ idx,
                                                   float* __restrict__ s) {
    int b  = blockIdx.y;
    int hw = blockIdx.x * 256 + threadIdx.x;
    int h  = hw >> 7, w = hw & 127;
    __shared__ int ai[KK], aj[KK];
    if (threadIdx.x < KK) {
        int v = idx[b * KK + threadIdx.x];
        ai[threadIdx.x] = v >> 7;
        aj[threadIdx.x] = v & 127;
    }
    __syncthreads();
    const float* yb = y + (size_t)b * KK * HWSZ;
    float acc = 0.f;
    #pragma unroll 8
    for (int k = 0; k < KK; k++) {
        float v = yb[(size_t)k * HWSZ + hw];
        bool in = (h >= ai[k] - 8) && (h < ai[k] + 8) && (w >= aj[k] - 8) && (w < aj[k] + 8);
        acc += in ? v : 0.f;
    }
    s[(size_t)b * HWSZ + hw] = acc;
}

__global__ __launch_bounds__(256) void smax_kernel(const float* __restrict__ s,
                                                   float* __restrict__ invmax) {
    int b = blockIdx.x;
    const float* p = s + (size_t)b * HWSZ;
    float m = -1e30f;
    for (int i = threadIdx.x; i < HWSZ; i += 256) m = fmaxf(m, p[i]);
    __shared__ float sm[256];
    sm[threadIdx.x] = m;
    __syncthreads();
    for (int st = 128; st > 0; st >>= 1) {
        if (threadIdx.x < st) sm[threadIdx.x] = fmaxf(sm[threadIdx.x], sm[threadIdx.x + st]);
        __syncthreads();
    }
    if (threadIdx.x == 0) invmax[b] = 1.f / sm[0];
}

// ---------------------------------------------------------------------------
// grouped deconvs -> bf16 out
// ---------------------------------------------------------------------------
__global__ __launch_bounds__(256) void deconv_kernel(const float* __restrict__ l1,
                                                     const float* __restrict__ l2,
                                                     const float* __restrict__ w2,
                                                     const float* __restrict__ w3,
                                                     unsigned short* __restrict__ out) {
    int x = blockIdx.x * 32 + threadIdx.x;
    int y = blockIdx.y * 8 + threadIdx.y;
    int g = blockIdx.z & 255;
    int b = blockIdx.z >> 8;

    float acc = 0.f;
    {
        const float* l1b = l1 + ((size_t)b * 2 * CC + 2 * g) * 4096;
        const float* w2g = w2 + (size_t)g * 32;
        int pyo = y & 1, pxo = x & 1;
        int my0 = (y + pyo - 2) >> 1;
        int mx0 = (x + pxo - 2) >> 1;
        #pragma unroll
        for (int i = 0; i < 2; i++) {
            const float* li = l1b + (size_t)i * 4096;
            const float* wi = w2g + i * 16;
            #pragma unroll
            for (int a = 0; a < 2; a++) {
                int m = my0 + a;
                if ((unsigned)m >= 64u) continue;
                int p = pyo + 2 * a;
                #pragma unroll
                for (int c = 0; c < 2; c++) {
                    int n = mx0 + c;
                    if ((unsigned)n >= 64u) continue;
                    int q = pxo + 2 * c;
                    acc = fmaf(wi[p * 4 + q], li[m * 64 + n], acc);
                }
            }
        }
    }
    {
        const float* l2b = l2 + ((size_t)b * 4 * CC + 4 * g) * 1024;
        const float* w3g = w3 + (size_t)g * 256;
        int py3 = (5 - (y & 3)) & 3, px3 = (5 - (x & 3)) & 3;
        int my0 = (y + py3 - 5) >> 2;
        int mx0 = (x + px3 - 5) >> 2;
        #pragma unroll
        for (int i = 0; i < 4; i++) {
            const float* li = l2b + (size_t)i * 1024;
            const float* wi = w3g + i * 64;
            #pragma unroll
            for (int a = 0; a < 2; a++) {
                int m = my0 + a;
                if ((unsigned)m >= 32u) continue;
                int p = py3 + 4 * a;
                #pragma unroll
                for (int c = 0; c < 2; c++) {
                    int n = mx0 + c;
                    if ((unsigned)n >= 32u) continue;
                    int q = px3 + 4 * c;
                    acc = fmaf(wi[p * 8 + q], li[m * 32 + n], acc);
                }
            }
        }
    }
    out[(((size_t)b * CC + g) * HWSZ) + y * WW + x] = f2b(acc);
}

// ---------------------------------------------------------------------------
// BIG conv 256->256 3x3, bf16 MFMA implicit GEMM.
// Block: 1 output row (128 px) x 128 co. 4 waves: wave = 64co x 64px.
// LDS: A-spatial [3][130][40] (ci-contig, pad 40), B-weights [2][128][40] dbuf.
// ADDB: out = silu(acc+bias) + addb
// ---------------------------------------------------------------------------
template <int ADDB>
__global__ __launch_bounds__(256) void conv_mfma_kernel(
    const unsigned short* __restrict__ in,    // bf16 NCHW
    const unsigned short* __restrict__ wt,    // bf16 [9][8][256][32]
    const float* __restrict__ bias,
    const unsigned short* __restrict__ addb,  // bf16 NCHW (ADDB=1)
    unsigned short* __restrict__ out)
{
    __shared__ __align__(16) unsigned short Alds[3 * 130 * 40];
    __shared__ __align__(16) unsigned short Blds[2 * 128 * 40];

    const int tid  = threadIdx.x;
    const int lane = tid & 63;
    const int wv   = tid >> 6;
    const int wco  = wv >> 1;
    const int wpx  = wv & 1;
    const int l15  = lane & 15;
    const int kg   = lane >> 4;

    const int y0  = blockIdx.x;
    const int co0 = blockIdx.y * 128;
    const int b   = blockIdx.z;

    const unsigned short* inb = in + (size_t)b * CC * HWSZ;

    int pixbase[4], wbase[4];
    #pragma unroll
    for (int f = 0; f < 4; f++) {
        int x = wpx * 64 + f * 16 + l15;
        pixbase[f] = x * 40 + kg * 8;
        int cr = wco * 64 + f * 16 + l15;
        wbase[f] = cr * 40 + kg * 8;
    }

    f32x4_t acc[4][4];
    #pragma unroll
    for (int i = 0; i < 4; i++)
        #pragma unroll
        for (int j = 0; j < 4; j++)
            acc[i][j] = (f32x4_t){0.f, 0.f, 0.f, 0.f};

    // ---- staging helpers ----
    auto stage_A = [&](int cb) {
        int cbase = cb * 32;
        for (int q = tid; q < 1560; q += 256) {
            int rg = q / 130;
            int xx = q - rg * 130;
            int r = rg >> 2, g = rg & 3;
            int gy = y0 - 1 + r;
            int gx = xx - 1;
            bool ok = ((unsigned)gy < 128u) && ((unsigned)gx < 128u);
            const unsigned short* src = inb + (size_t)(cbase + g * 8) * HWSZ + (gy * 128 + gx);
            union { unsigned short u[8]; uint4 v; } pk;
            #pragma unroll
            for (int e = 0; e < 8; e++)
                pk.u[e] = ok ? src[(size_t)e * HWSZ] : (unsigned short)0;
            *reinterpret_cast<uint4*>(&Alds[(r * 130 + xx) * 40 + g * 8]) = pk.v;
        }
    };
    auto stage_B = [&](int sn) {
        int cbn = sn / 9;
        int tn  = sn - cbn * 9;
        int pn  = sn & 1;
        size_t base = ((size_t)(tn * 8 + cbn) * 256 + co0) * 32;
        #pragma unroll
        for (int h = 0; h < 2; h++) {
            int chunk = tid + h * 256;
            uint4 v = *reinterpret_cast<const uint4*>(wt + base + (size_t)chunk * 8);
            int co = chunk >> 2, g = chunk & 3;
            *reinterpret_cast<uint4*>(&Blds[(pn * 128 + co) * 40 + g * 8]) = v;
        }
    };

    stage_B(0);
    for (int s = 0; s < 72; ++s) {
        int cb = s / 9;
        int t  = s - cb * 9;
        if (t == 0) {
            if (s) __syncthreads();   // prior taps done before overwriting A
            stage_A(cb);
        }
        __syncthreads();              // A + B(s) visible; prev compute done
        if (s + 1 < 72) stage_B(s + 1);

        int ky = t / 3, kx = t - ky * 3;
        int tapoff = (ky * 130 + kx) * 40;
        int bofs = (s & 1) * (128 * 40);

        bf16x8_t pfr[4], wfr[4];
        #pragma unroll
        for (int f = 0; f < 4; f++)
            pfr[f] = *reinterpret_cast<const bf16x8_t*>(&Alds[pixbase[f] + tapoff]);
        #pragma unroll
        for (int f = 0; f < 4; f++)
            wfr[f] = *reinterpret_cast<const bf16x8_t*>(&Blds[wbase[f] + bofs]);

        #pragma unroll
        for (int cf = 0; cf < 4; cf++)
            #pragma unroll
            for (int pf = 0; pf < 4; pf++)
                acc[cf][pf] = __builtin_amdgcn_mfma_f32_16x16x32_bf16(
                    wfr[cf], pfr[pf], acc[cf][pf], 0, 0, 0);
    }

    // ---- epilogue: D[row=co][col=pix]; lane: col=l15, row=kg*4+j ----
    size_t outB = (size_t)b * CC * HWSZ + (size_t)y0 * 128;
    #pragma unroll
    for (int cf = 0; cf < 4; cf++) {
        int cobase = co0 + wco * 64 + cf * 16 + kg * 4;
        #pragma unroll
        for (int j = 0; j < 4; j++) {
            int co = cobase + j;
            float bs = bias[co];
            size_t rowp = outB + (size_t)co * HWSZ;
            #pragma unroll
            for (int pf = 0; pf < 4; pf++) {
                int x = wpx * 64 + pf * 16 + l15;
                float v = silu_f(acc[cf][pf][j] + bs);
                if (ADDB) v += b2f(addb[rowp + x]);
                out[rowp + x] = f2b(v);
            }
        }
    }
}

// ---------------------------------------------------------------------------
// conv 1->256 (input = s * invmax), + bias, silu -> bf16
// ---------------------------------------------------------------------------
__global__ __launch_bounds__(256) void conv_c1a_kernel(const float* __restrict__ s,
                                                       const float* __restrict__ invmax,
                                                       const float* __restrict__ w,
                                                       const float* __restrict__ bias,
                                                       unsigned short* __restrict__ out) {
    int x = blockIdx.x * 32 + threadIdx.x;
    int y = blockIdx.y * 8 + threadIdx.y;
    int co = blockIdx.z & 255;
    int b  = blockIdx.z >> 8;
    float im = invmax[b];
    const float* sb = s + (size_t)b * HWSZ;
    const float* wp = w + (size_t)co * 9;
    float sum = 0.f;
    #pragma unroll
    for (int dy = 0; dy < 3; dy++) {
        int yy = y + dy - 1;
        if ((unsigned)yy >= 128u) continue;
        #pragma unroll
        for (int dx = 0; dx < 3; dx++) {
            int xx = x + dx - 1;
            if ((unsigned)xx >= 128u) continue;
            sum = fmaf(wp[dy * 3 + dx], sb[yy * WW + xx], sum);
        }
    }
    float v = silu_f(sum * im + bias[co]);
    out[(((size_t)b * CC + co) * HWSZ) + y * WW + x] = f2b(v);
}

// ---------------------------------------------------------------------------
// conv 256->1 (+bias, optional sigmoid), bf16 input, fp32 out
// ---------------------------------------------------------------------------
template <int SIG>
__global__ __launch_bounds__(256) void conv_256to1_kernel(const unsigned short* __restrict__ in,
                                                          const float* __restrict__ w,
                                                          const float* __restrict__ bias,
                                                          float* __restrict__ out) {
    int x = blockIdx.x * 32 + threadIdx.x;
    int y = blockIdx.y * 8 + threadIdx.y;
    int b = blockIdx.z;
    const unsigned short* ib = in + (size_t)b * CC * HWSZ;
    float acc = 0.f;
    for (int ci = 0; ci < CC; ci++) {
        const float* wp = w + (size_t)ci * 9;
        const unsigned short* ip = ib + (size_t)ci * HWSZ;
        #pragma unroll
        for (int dy = 0; dy < 3; dy++) {
            int yy = y + dy - 1;
            if ((unsigned)yy >= 128u) continue;
            #pragma unroll
            for (int dx = 0; dx < 3; dx++) {
                int xx = x + dx - 1;
                if ((unsigned)xx >= 128u) continue;
                acc = fmaf(wp[dy * 3 + dx], b2f(ip[yy * WW + xx]), acc);
            }
        }
    }
    acc += bias[0];
    if (SIG) acc = sigm_f(acc);
    out[(size_t)b * HWSZ + y * WW + x] = acc;
}

// ---------------------------------------------------------------------------
// t = xf(fp32,[b,hw]) * xd(bf16) -> bf16
// ---------------------------------------------------------------------------
__global__ __launch_bounds__(256) void mul_kernel(const float* __restrict__ xf,
                                                  const unsigned short* __restrict__ xd,
                                                  unsigned short* __restrict__ out) {
    size_t base = ((size_t)blockIdx.x * 256 + threadIdx.x) * 8;
    int b  = (int)(base >> 22);
    int hw = (int)(base & (HWSZ - 1));
    union { unsigned short u[8]; uint4 v; } d, r;
    d.v = *(const uint4*)(xd + base);
    const float* xfp = xf + (size_t)b * HWSZ + hw;
    float4 f0 = *(const float4*)xfp;
    float4 f1 = *(const float4*)(xfp + 4);
    r.u[0] = f2b(b2f(d.u[0]) * f0.x);
    r.u[1] = f2b(b2f(d.u[1]) * f0.y);
    r.u[2] = f2b(b2f(d.u[2]) * f0.z);
    r.u[3] = f2b(b2f(d.u[3]) * f0.w);
    r.u[4] = f2b(b2f(d.u[4]) * f1.x);
    r.u[5] = f2b(b2f(d.u[5]) * f1.y);
    r.u[6] = f2b(b2f(d.u[6]) * f1.z);
    r.u[7] = f2b(b2f(d.u[7]) * f1.w);
    *(uint4*)(out + base) = r.v;
}

// ---------------------------------------------------------------------------
// conv 256->4 + bias, bf16 input, NHWC fp32 output
// ---------------------------------------------------------------------------
__global__ __launch_bounds__(256) void conv_c2box_kernel(const unsigned short* __restrict__ in,
                                                         const float* __restrict__ w,
                                                         const float* __restrict__ bias,
                                                         float* __restrict__ out) {
    int x = blockIdx.x * 32 + threadIdx.x;
    int y = blockIdx.y * 8 + threadIdx.y;
    int b = blockIdx.z;
    const unsigned short* ib = in + (size_t)b * CC * HWSZ;
    float a0 = 0.f, a1 = 0.f, a2 = 0.f, a3 = 0.f;
    for (int ci = 0; ci < CC; ci++) {
        float iv[9];
        #pragma unroll
        for (int dy = 0; dy < 3; dy++) {
            #pragma unroll
            for (int dx = 0; dx < 3; dx++) {
                int yy = y + dy - 1, xx = x + dx - 1;
                iv[dy * 3 + dx] = ((unsigned)yy < 128u && (unsigned)xx < 128u)
                                      ? b2f(ib[(size_t)ci * HWSZ + yy * WW + xx]) : 0.f;
            }
        }
        const float* w0 = w + (size_t)(0 * CC + ci) * 9;
        const float* w1 = w + (size_t)(1 * CC + ci) * 9;
        const float* w2 = w + (size_t)(2 * CC + ci) * 9;
        const float* w3 = w + (size_t)(3 * CC + ci) * 9;
        #pragma unroll
        for (int t = 0; t < 9; t++) {
            a0 = fmaf(iv[t], w0[t], a0);
            a1 = fmaf(iv[t], w1[t], a1);
            a2 = fmaf(iv[t], w2[t], a2);
            a3 = fmaf(iv[t], w3[t], a3);
        }
    }
    float4 r = make_float4(a0 + bias[0], a1 + bias[1], a2 + bias[2], a3 + bias[3]);
    ((float4*)out)[(size_t)b * HWSZ + y * WW + x] = r;
}

// ---------------------------------------------------------------------------
extern "C" void kernel_launch(void* const* d_in, const int* in_sizes, int n_in,
                              void* d_out, int out_size, void* d_ws, size_t ws_size,
                              hipStream_t stream) {
    const float* emb    = (const float*)d_in[0];
    const float* trk    = (const float*)d_in[1];
    const float* l0     = (const float*)d_in[2];
    const float* l1     = (const float*)d_in[3];
    const float* l2     = (const float*)d_in[4];
    const float* b_p1w  = (const float*)d_in[5];
    const float* b_p1b  = (const float*)d_in[6];
    const float* b_p2w  = (const float*)d_in[7];
    const float* b_p3w  = (const float*)d_in[8];
    const float* b_c1w  = (const float*)d_in[9];
    const float* b_c1b  = (const float*)d_in[10];
    const float* b_c2w  = (const float*)d_in[11];
    const float* b_c2b  = (const float*)d_in[12];
    const float* h_p1w  = (const float*)d_in[13];
    const float* h_p1b  = (const float*)d_in[14];
    const float* h_p2w  = (const float*)d_in[15];
    const float* h_p3w  = (const float*)d_in[16];
    const float* h_c1aw = (const float*)d_in[17];
    const float* h_c1ab = (const float*)d_in[18];
    const float* h_c1bw = (const float*)d_in[19];
    const float* h_c1bb = (const float*)d_in[20];
    const float* h_c2aw = (const float*)d_in[21];
    const float* h_c2ab = (const float*)d_in[22];
    const float* h_c2bw = (const float*)d_in[23];
    const float* h_c2bb = (const float*)d_in[24];
    const float* h_c2cw = (const float*)d_in[25];
    const float* h_c2cb = (const float*)d_in[26];

    float* outp = (float*)d_out;   // [0,32768): hmmap ; [32768,163840): siambox NHWC

    const size_t ACT = (size_t)BB * CC * HWSZ;   // 8,388,608 elems
    const size_t WT  = 9 * 8 * 256 * 32;         // 589,824 elems

    unsigned short* l0bf = (unsigned short*)d_ws;
    unsigned short* wt0  = l0bf + ACT;
    unsigned short* wt1  = wt0 + WT;
    unsigned short* wt2  = wt1 + WT;
    unsigned short* wt3  = wt2 + WT;
    unsigned short* wt4  = wt3 + WT;
    unsigned short* Db   = wt4 + WT;
    unsigned short* X1   = Db + ACT;
    unsigned short* X2   = X1 + ACT;
    float* sbuf   = (float*)(X2 + ACT);
    float* xfb    = sbuf + (size_t)BB * HWSZ;
    float* tn     = xfb + (size_t)BB * HWSZ;
    float* invmax = tn + (size_t)BB * KK * CC;
    int*   idxb   = (int*)(invmax + 2);
    float* ybuf   = (float*)X1;   // alias: y consumed before X1 first written

    dim3 blk2d(32, 8);
    dim3 grdConvM(128, 2, 2);
    dim3 grdPerBC(4, 16, BB * CC);
    dim3 grdPerB(4, 16, BB);

    // ---- preps ----
    cvtbf_kernel<<<(unsigned)(ACT / 8 / 256), 256, 0, stream>>>(l0, l0bf);
    wprep_kernel<<<(unsigned)(WT / 256), 256, 0, stream>>>(b_p1w, wt0);
    wprep_kernel<<<(unsigned)(WT / 256), 256, 0, stream>>>(b_c1w, wt1);
    wprep_kernel<<<(unsigned)(WT / 256), 256, 0, stream>>>(h_p1w, wt2);
    wprep_kernel<<<(unsigned)(WT / 256), 256, 0, stream>>>(h_c2aw, wt3);
    wprep_kernel<<<(unsigned)(WT / 256), 256, 0, stream>>>(h_c2bw, wt4);

    // ---- correlation map ----
    tnorm_kernel<<<1, 128, 0, stream>>>(trk, tn);
    y_kernel<<<8192, 256, 0, stream>>>(emb, tn, ybuf);
    argmax_kernel<<<BB * KK, 256, 0, stream>>>(ybuf, idxb);
    smap_kernel<<<dim3(64, BB), 256, 0, stream>>>(ybuf, idxb, sbuf);
    smax_kernel<<<BB, 256, 0, stream>>>(sbuf, invmax);

    // ---- box head ----
    deconv_kernel<<<grdPerBC, blk2d, 0, stream>>>(l1, l2, b_p2w, b_p3w, Db);
    conv_mfma_kernel<1><<<grdConvM, 256, 0, stream>>>(l0bf, wt0, b_p1b, Db, X1);     // xd_box
    conv_mfma_kernel<0><<<grdConvM, 256, 0, stream>>>(X1, wt1, b_c1b, nullptr, X2);  // xb
    conv_c2box_kernel<<<grdPerB, blk2d, 0, stream>>>(X2, b_c2w, b_c2b, outp + BB * HWSZ);

    // ---- heatmap head ----
    deconv_kernel<<<grdPerBC, blk2d, 0, stream>>>(l1, l2, h_p2w, h_p3w, Db);
    conv_mfma_kernel<1><<<grdConvM, 256, 0, stream>>>(l0bf, wt2, h_p1b, Db, X1);     // xd_hm
    conv_c1a_kernel<<<grdPerBC, blk2d, 0, stream>>>(sbuf, invmax, h_c1aw, h_c1ab, X2);   // t1 (bf16)
    conv_256to1_kernel<0><<<grdPerB, blk2d, 0, stream>>>(X2, h_c1bw, h_c1bb, xfb);   // xf
    mul_kernel<<<4096, 256, 0, stream>>>(xfb, X1, X2);                               // t
    conv_mfma_kernel<0><<<grdConvM, 256, 0, stream>>>(X2, wt3, h_c2ab, nullptr, Db); // t2
    conv_mfma_kernel<0><<<grdConvM, 256, 0, stream>>>(Db, wt4, h_c2bb, nullptr, X1); // t3
    conv_256to1_kernel<1><<<grdPerB, blk2d, 0, stream>>>(X1, h_c2cw, h_c2cb, outp);  // hmmap
}

// Round 3
// 1159.240 us; speedup vs baseline: 6.1039x; 2.0562x over previous
//
#include <hip/hip_runtime.h>
#include <math.h>

#define HH 128
#define WW 128
#define HWSZ 16384   // 128*128
#define CC 256
#define KK 64
#define BB 2

typedef __bf16 bf16x8_t __attribute__((ext_vector_type(8)));
typedef float  f32x4_t  __attribute__((ext_vector_type(4)));

__device__ __forceinline__ float silu_f(float v) { return v / (1.f + expf(-v)); }
__device__ __forceinline__ float sigm_f(float v) { return 1.f / (1.f + expf(-v)); }

__device__ __forceinline__ float b2f(unsigned short u) {
    union { unsigned int i; float f; } x; x.i = ((unsigned int)u) << 16; return x.f;
}
__device__ __forceinline__ unsigned short f2b(float f) {
    union { float f; unsigned int i; } x; x.f = f;
    unsigned int r = x.i + 0x7FFFu + ((x.i >> 16) & 1u);
    return (unsigned short)(r >> 16);
}

// ---------------------------------------------------------------------------
// prep: fp32 -> bf16 copy (8 elems/thread)
// ---------------------------------------------------------------------------
__global__ __launch_bounds__(256) void cvtbf_kernel(const float* __restrict__ in,
                                                    unsigned short* __restrict__ out) {
    size_t i = ((size_t)blockIdx.x * 256 + threadIdx.x) * 8;
    float4 a = *(const float4*)(in + i);
    float4 b = *(const float4*)(in + i + 4);
    union { unsigned short u[8]; uint4 v; } pk;
    pk.u[0] = f2b(a.x); pk.u[1] = f2b(a.y); pk.u[2] = f2b(a.z); pk.u[3] = f2b(a.w);
    pk.u[4] = f2b(b.x); pk.u[5] = f2b(b.y); pk.u[6] = f2b(b.z); pk.u[7] = f2b(b.w);
    *(uint4*)(out + i) = pk.v;
}

// ---------------------------------------------------------------------------
// prep: weights OIHW fp32 [256][256][3][3] -> bf16 [9][8][256][32]
// ---------------------------------------------------------------------------
__global__ __launch_bounds__(256) void wprep_kernel(const float* __restrict__ w,
                                                    unsigned short* __restrict__ wt) {
    int idx = blockIdx.x * 256 + threadIdx.x;       // 0 .. 589823
    int ci  = idx & 31;
    int co  = (idx >> 5) & 255;
    int tcb = idx >> 13;                            // 0..71
    int t   = tcb >> 3;
    int cb  = tcb & 7;
    wt[idx] = f2b(w[((size_t)co * 256 + cb * 32 + ci) * 9 + t]);
}

// ---------------------------------------------------------------------------
// tracklet normalize
// ---------------------------------------------------------------------------
__global__ __launch_bounds__(128) void tnorm_kernel(const float* __restrict__ trk,
                                                    float* __restrict__ tn) {
    int r = threadIdx.x;
    if (r >= BB * KK) return;
    const float* p = trk + (size_t)r * CC;
    float ss = 0.f;
    for (int c = 0; c < CC; c++) { float v = p[c]; ss += v * v; }
    float sc = 1.f / fmaxf(sqrtf(ss), 1e-12f);
    float* q = tn + (size_t)r * CC;
    for (int c = 0; c < CC; c++) q[c] = p[c] * sc;
}

// ---------------------------------------------------------------------------
// y[b,k,hw] = relu(dot(e_norm, tn))
// ---------------------------------------------------------------------------
__global__ __launch_bounds__(256) void y_kernel(const float* __restrict__ emb,
                                                const float* __restrict__ tn,
                                                float* __restrict__ y) {
    int wave = threadIdx.x >> 6;
    int lane = threadIdx.x & 63;
    int pix  = blockIdx.x * 4 + wave;
    int b    = pix >> 14;
    int hw   = pix & (HWSZ - 1);

    __shared__ __align__(16) float els[4][CC];

    const float4* e4 = (const float4*)(emb + (size_t)pix * CC);
    float4 ev = e4[lane];
    float ss = ev.x * ev.x + ev.y * ev.y + ev.z * ev.z + ev.w * ev.w;
    #pragma unroll
    for (int d = 1; d < 64; d <<= 1) ss += __shfl_xor(ss, d);
    float sc = 1.f / fmaxf(sqrtf(ss), 1e-12f);
    ((float4*)els[wave])[lane] = make_float4(ev.x * sc, ev.y * sc, ev.z * sc, ev.w * sc);
    __syncthreads();

    const float4* t4  = (const float4*)(tn + ((size_t)b * KK + lane) * CC);
    const float4* el4 = (const float4*)els[wave];
    float acc = 0.f;
    #pragma unroll 8
    for (int c4 = 0; c4 < CC / 4; c4++) {
        float4 t = t4[c4];
        float4 e = el4[c4];
        acc = fmaf(e.x, t.x, acc);
        acc = fmaf(e.y, t.y, acc);
        acc = fmaf(e.z, t.z, acc);
        acc = fmaf(e.w, t.w, acc);
    }
    y[((size_t)b * KK + lane) * HWSZ + hw] = fmaxf(acc, 0.f);
}

// ---------------------------------------------------------------------------
// first-occurrence argmax per (b,k)
// ---------------------------------------------------------------------------
__global__ __launch_bounds__(256) void argmax_kernel(const float* __restrict__ y,
                                                     int* __restrict__ idxout) {
    int bk = blockIdx.x;
    const float* p = y + (size_t)bk * HWSZ;
    int t = threadIdx.x;
    float best = -1.f; int bi = 1 << 30;
    for (int i = t; i < HWSZ; i += 256) {
        float v = p[i];
        if (v > best) { best = v; bi = i; }
    }
    __shared__ float sv[256];
    __shared__ int   si[256];
    sv[t] = best; si[t] = bi;
    __syncthreads();
    for (int s = 128; s > 0; s >>= 1) {
        if (t < s) {
            float v2 = sv[t + s]; int i2 = si[t + s];
            if (v2 > sv[t] || (v2 == sv[t] && i2 < si[t])) { sv[t] = v2; si[t] = i2; }
        }
        __syncthreads();
    }
    if (t == 0) idxout[bk] = si[0];
}

// ---------------------------------------------------------------------------
// s[b,hw] = sum_k y * mask
// ---------------------------------------------------------------------------
__global__ __launch_bounds__(256) void smap_kernel(const float* __restrict__ y,
                                                   const int* __restrict__ idx,
                                                   float* __restrict__ s) {
    int b  = blockIdx.y;
    int hw = blockIdx.x * 256 + threadIdx.x;
    int h  = hw >> 7, w = hw & 127;
    __shared__ int ai[KK], aj[KK];
    if (threadIdx.x < KK) {
        int v = idx[b * KK + threadIdx.x];
        ai[threadIdx.x] = v >> 7;
        aj[threadIdx.x] = v & 127;
    }
    __syncthreads();
    const float* yb = y + (size_t)b * KK * HWSZ;
    float acc = 0.f;
    #pragma unroll 8
    for (int k = 0; k < KK; k++) {
        float v = yb[(size_t)k * HWSZ + hw];
        bool in = (h >= ai[k] - 8) && (h < ai[k] + 8) && (w >= aj[k] - 8) && (w < aj[k] + 8);
        acc += in ? v : 0.f;
    }
    s[(size_t)b * HWSZ + hw] = acc;
}

__global__ __launch_bounds__(256) void smax_kernel(const float* __restrict__ s,
                                                   float* __restrict__ invmax) {
    int b = blockIdx.x;
    const float* p = s + (size_t)b * HWSZ;
    float m = -1e30f;
    for (int i = threadIdx.x; i < HWSZ; i += 256) m = fmaxf(m, p[i]);
    __shared__ float sm[256];
    sm[threadIdx.x] = m;
    __syncthreads();
    for (int st = 128; st > 0; st >>= 1) {
        if (threadIdx.x < st) sm[threadIdx.x] = fmaxf(sm[threadIdx.x], sm[threadIdx.x + st]);
        __syncthreads();
    }
    if (threadIdx.x == 0) invmax[b] = 1.f / sm[0];
}

// ---------------------------------------------------------------------------
// grouped deconvs -> bf16 out
// ---------------------------------------------------------------------------
__global__ __launch_bounds__(256) void deconv_kernel(const float* __restrict__ l1,
                                                     const float* __restrict__ l2,
                                                     const float* __restrict__ w2,
                                                     const float* __restrict__ w3,
                                                     unsigned short* __restrict__ out) {
    int x = blockIdx.x * 32 + threadIdx.x;
    int y = blockIdx.y * 8 + threadIdx.y;
    int g = blockIdx.z & 255;
    int b = blockIdx.z >> 8;

    float acc = 0.f;
    {
        const float* l1b = l1 + ((size_t)b * 2 * CC + 2 * g) * 4096;
        const float* w2g = w2 + (size_t)g * 32;
        int pyo = y & 1, pxo = x & 1;
        int my0 = (y + pyo - 2) >> 1;
        int mx0 = (x + pxo - 2) >> 1;
        #pragma unroll
        for (int i = 0; i < 2; i++) {
            const float* li = l1b + (size_t)i * 4096;
            const float* wi = w2g + i * 16;
            #pragma unroll
            for (int a = 0; a < 2; a++) {
                int m = my0 + a;
                if ((unsigned)m >= 64u) continue;
                int p = pyo + 2 * a;
                #pragma unroll
                for (int c = 0; c < 2; c++) {
                    int n = mx0 + c;
                    if ((unsigned)n >= 64u) continue;
                    int q = pxo + 2 * c;
                    acc = fmaf(wi[p * 4 + q], li[m * 64 + n], acc);
                }
            }
        }
    }
    {
        const float* l2b = l2 + ((size_t)b * 4 * CC + 4 * g) * 1024;
        const float* w3g = w3 + (size_t)g * 256;
        int py3 = (5 - (y & 3)) & 3, px3 = (5 - (x & 3)) & 3;
        int my0 = (y + py3 - 5) >> 2;
        int mx0 = (x + px3 - 5) >> 2;
        #pragma unroll
        for (int i = 0; i < 4; i++) {
            const float* li = l2b + (size_t)i * 1024;
            const float* wi = w3g + i * 64;
            #pragma unroll
            for (int a = 0; a < 2; a++) {
                int m = my0 + a;
                if ((unsigned)m >= 32u) continue;
                int p = py3 + 4 * a;
                #pragma unroll
                for (int c = 0; c < 2; c++) {
                    int n = mx0 + c;
                    if ((unsigned)n >= 32u) continue;
                    int q = px3 + 4 * c;
                    acc = fmaf(wi[p * 8 + q], li[m * 32 + n], acc);
                }
            }
        }
    }
    out[(((size_t)b * CC + g) * HWSZ) + y * WW + x] = f2b(acc);
}

// ---------------------------------------------------------------------------
// BIG conv 256->256 3x3, bf16 MFMA implicit GEMM.
// ---------------------------------------------------------------------------
template <int ADDB>
__global__ __launch_bounds__(256) void conv_mfma_kernel(
    const unsigned short* __restrict__ in,    // bf16 NCHW
    const unsigned short* __restrict__ wt,    // bf16 [9][8][256][32]
    const float* __restrict__ bias,
    const unsigned short* __restrict__ addb,  // bf16 NCHW (ADDB=1)
    unsigned short* __restrict__ out)
{
    __shared__ __align__(16) unsigned short Alds[3 * 130 * 40];
    __shared__ __align__(16) unsigned short Blds[2 * 128 * 40];

    const int tid  = threadIdx.x;
    const int lane = tid & 63;
    const int wv   = tid >> 6;
    const int wco  = wv >> 1;
    const int wpx  = wv & 1;
    const int l15  = lane & 15;
    const int kg   = lane >> 4;

    const int y0  = blockIdx.x;
    const int co0 = blockIdx.y * 128;
    const int b   = blockIdx.z;

    const unsigned short* inb = in + (size_t)b * CC * HWSZ;

    int pixbase[4], wbase[4];
    #pragma unroll
    for (int f = 0; f < 4; f++) {
        int x = wpx * 64 + f * 16 + l15;
        pixbase[f] = x * 40 + kg * 8;
        int cr = wco * 64 + f * 16 + l15;
        wbase[f] = cr * 40 + kg * 8;
    }

    f32x4_t acc[4][4];
    #pragma unroll
    for (int i = 0; i < 4; i++)
        #pragma unroll
        for (int j = 0; j < 4; j++)
            acc[i][j] = (f32x4_t){0.f, 0.f, 0.f, 0.f};

    auto stage_A = [&](int cb) {
        int cbase = cb * 32;
        for (int q = tid; q < 1560; q += 256) {
            int rg = q / 130;
            int xx = q - rg * 130;
            int r = rg >> 2, g = rg & 3;
            int gy = y0 - 1 + r;
            int gx = xx - 1;
            bool ok = ((unsigned)gy < 128u) && ((unsigned)gx < 128u);
            const unsigned short* src = inb + (size_t)(cbase + g * 8) * HWSZ + (gy * 128 + gx);
            union { unsigned short u[8]; uint4 v; } pk;
            #pragma unroll
            for (int e = 0; e < 8; e++)
                pk.u[e] = ok ? src[(size_t)e * HWSZ] : (unsigned short)0;
            *reinterpret_cast<uint4*>(&Alds[(r * 130 + xx) * 40 + g * 8]) = pk.v;
        }
    };
    auto stage_B = [&](int sn) {
        int cbn = sn / 9;
        int tn  = sn - cbn * 9;
        int pn  = sn & 1;
        size_t base = ((size_t)(tn * 8 + cbn) * 256 + co0) * 32;
        #pragma unroll
        for (int h = 0; h < 2; h++) {
            int chunk = tid + h * 256;
            uint4 v = *reinterpret_cast<const uint4*>(wt + base + (size_t)chunk * 8);
            int co = chunk >> 2, g = chunk & 3;
            *reinterpret_cast<uint4*>(&Blds[(pn * 128 + co) * 40 + g * 8]) = v;
        }
    };

    stage_B(0);
    for (int s = 0; s < 72; ++s) {
        int cb = s / 9;
        int t  = s - cb * 9;
        if (t == 0) {
            if (s) __syncthreads();
            stage_A(cb);
        }
        __syncthreads();
        if (s + 1 < 72) stage_B(s + 1);

        int ky = t / 3, kx = t - ky * 3;
        int tapoff = (ky * 130 + kx) * 40;
        int bofs = (s & 1) * (128 * 40);

        bf16x8_t pfr[4], wfr[4];
        #pragma unroll
        for (int f = 0; f < 4; f++)
            pfr[f] = *reinterpret_cast<const bf16x8_t*>(&Alds[pixbase[f] + tapoff]);
        #pragma unroll
        for (int f = 0; f < 4; f++)
            wfr[f] = *reinterpret_cast<const bf16x8_t*>(&Blds[wbase[f] + bofs]);

        #pragma unroll
        for (int cf = 0; cf < 4; cf++)
            #pragma unroll
            for (int pf = 0; pf < 4; pf++)
                acc[cf][pf] = __builtin_amdgcn_mfma_f32_16x16x32_bf16(
                    wfr[cf], pfr[pf], acc[cf][pf], 0, 0, 0);
    }

    size_t outB = (size_t)b * CC * HWSZ + (size_t)y0 * 128;
    #pragma unroll
    for (int cf = 0; cf < 4; cf++) {
        int cobase = co0 + wco * 64 + cf * 16 + kg * 4;
        #pragma unroll
        for (int j = 0; j < 4; j++) {
            int co = cobase + j;
            float bs = bias[co];
            size_t rowp = outB + (size_t)co * HWSZ;
            #pragma unroll
            for (int pf = 0; pf < 4; pf++) {
                int x = wpx * 64 + pf * 16 + l15;
                float v = silu_f(acc[cf][pf][j] + bs);
                if (ADDB) v += b2f(addb[rowp + x]);
                out[rowp + x] = f2b(v);
            }
        }
    }
}

// ---------------------------------------------------------------------------
// conv 1->256 (input = s * invmax), + bias, silu -> bf16
// ---------------------------------------------------------------------------
__global__ __launch_bounds__(256) void conv_c1a_kernel(const float* __restrict__ s,
                                                       const float* __restrict__ invmax,
                                                       const float* __restrict__ w,
                                                       const float* __restrict__ bias,
                                                       unsigned short* __restrict__ out) {
    int x = blockIdx.x * 32 + threadIdx.x;
    int y = blockIdx.y * 8 + threadIdx.y;
    int co = blockIdx.z & 255;
    int b  = blockIdx.z >> 8;
    float im = invmax[b];
    const float* sb = s + (size_t)b * HWSZ;
    const float* wp = w + (size_t)co * 9;
    float sum = 0.f;
    #pragma unroll
    for (int dy = 0; dy < 3; dy++) {
        int yy = y + dy - 1;
        if ((unsigned)yy >= 128u) continue;
        #pragma unroll
        for (int dx = 0; dx < 3; dx++) {
            int xx = x + dx - 1;
            if ((unsigned)xx >= 128u) continue;
            sum = fmaf(wp[dy * 3 + dx], sb[yy * WW + xx], sum);
        }
    }
    float v = silu_f(sum * im + bias[co]);
    out[(((size_t)b * CC + co) * HWSZ) + y * WW + x] = f2b(v);
}

// ---------------------------------------------------------------------------
// Small conv 256 -> COUT (COUT in {1,4}), bf16 NCHW input, fp32 weights OIHW.
// Block: 64 px (half row) x 4 ci-quarters = 256 threads. Grid: (2*H, B).
// LDS-staged fp32 stripes, per-thread 64-ci partials, 4-way LDS reduce.
// MODE 0: NHWC float4 out (c2box). MODE 1: plain fp32 plane. MODE 2: sigmoid.
// ---------------------------------------------------------------------------
template <int COUT, int MODE>
__global__ __launch_bounds__(256) void small_conv_kernel(
    const unsigned short* __restrict__ in,
    const float* __restrict__ w,        // [COUT][256][3][3]
    const float* __restrict__ bias,
    float* __restrict__ out)
{
    __shared__ __align__(16) float stripe[16][3][72];
    __shared__ float sacc[4][64][COUT];

    const int tid = threadIdx.x;
    const int p   = tid & 63;
    const int qd  = __builtin_amdgcn_readfirstlane(tid >> 6);  // wave id = ci quarter
    const int xh  = blockIdx.x & 1;
    const int y   = blockIdx.x >> 1;
    const int b   = blockIdx.y;
    const int x0  = xh * 64;
    const int x   = x0 + p;

    const unsigned short* inb = in + (size_t)b * CC * HWSZ;

    float acc[COUT];
    #pragma unroll
    for (int c = 0; c < COUT; c++) acc[c] = 0.f;

    for (int it = 0; it < 16; ++it) {
        __syncthreads();
        // stage 16 ci planes (3 rows x 66 px halo, chunks of 8)
        for (int q = tid; q < 432; q += 256) {
            int ciq = q / 27;
            int rem = q - ciq * 27;
            int r   = rem / 9;
            int c8  = rem - r * 9;
            int ci  = it * 16 + ciq;
            int gy  = y - 1 + r;
            int gx0 = x0 - 1 + c8 * 8;
            const unsigned short* src = inb + (size_t)ci * HWSZ + gy * 128;
            float v[8];
            #pragma unroll
            for (int e = 0; e < 8; e++) {
                int gx = gx0 + e;
                v[e] = ((unsigned)gy < 128u && (unsigned)gx < 128u) ? b2f(src[gx]) : 0.f;
            }
            float4* dst = (float4*)&stripe[ciq][r][c8 * 8];
            dst[0] = make_float4(v[0], v[1], v[2], v[3]);
            dst[1] = make_float4(v[4], v[5], v[6], v[7]);
        }
        __syncthreads();
        #pragma unroll
        for (int j = 0; j < 4; j++) {
            int ciq = qd * 4 + j;
            int ci  = it * 16 + ciq;
            float i00 = stripe[ciq][0][p], i01 = stripe[ciq][0][p + 1], i02 = stripe[ciq][0][p + 2];
            float i10 = stripe[ciq][1][p], i11 = stripe[ciq][1][p + 1], i12 = stripe[ciq][1][p + 2];
            float i20 = stripe[ciq][2][p], i21 = stripe[ciq][2][p + 1], i22 = stripe[ciq][2][p + 2];
            #pragma unroll
            for (int co = 0; co < COUT; co++) {
                const float* wc = w + ((size_t)co * CC + ci) * 9;
                float a = acc[co];
                a = fmaf(i00, wc[0], a);
                a = fmaf(i01, wc[1], a);
                a = fmaf(i02, wc[2], a);
                a = fmaf(i10, wc[3], a);
                a = fmaf(i11, wc[4], a);
                a = fmaf(i12, wc[5], a);
                a = fmaf(i20, wc[6], a);
                a = fmaf(i21, wc[7], a);
                a = fmaf(i22, wc[8], a);
                acc[co] = a;
            }
        }
    }

    #pragma unroll
    for (int c = 0; c < COUT; c++) sacc[qd][p][c] = acc[c];
    __syncthreads();
    if (tid < 64) {
        float r[COUT];
        #pragma unroll
        for (int c = 0; c < COUT; c++)
            r[c] = sacc[0][tid][c] + sacc[1][tid][c] + sacc[2][tid][c] + sacc[3][tid][c] + bias[c];
        size_t pixidx = (size_t)b * HWSZ + (size_t)y * WW + x0 + tid;
        if (MODE == 0) {
            ((float4*)out)[pixidx] = make_float4(r[0], r[COUT > 1 ? 1 : 0],
                                                 r[COUT > 2 ? 2 : 0], r[COUT > 3 ? 3 : 0]);
        } else if (MODE == 1) {
            out[pixidx] = r[0];
        } else {
            out[pixidx] = sigm_f(r[0]);
        }
    }
}

// ---------------------------------------------------------------------------
// t = xf(fp32,[b,hw]) * xd(bf16) -> bf16
// ---------------------------------------------------------------------------
__global__ __launch_bounds__(256) void mul_kernel(const float* __restrict__ xf,
                                                  const unsigned short* __restrict__ xd,
                                                  unsigned short* __restrict__ out) {
    size_t base = ((size_t)blockIdx.x * 256 + threadIdx.x) * 8;
    int b  = (int)(base >> 22);
    int hw = (int)(base & (HWSZ - 1));
    union { unsigned short u[8]; uint4 v; } d, r;
    d.v = *(const uint4*)(xd + base);
    const float* xfp = xf + (size_t)b * HWSZ + hw;
    float4 f0 = *(const float4*)xfp;
    float4 f1 = *(const float4*)(xfp + 4);
    r.u[0] = f2b(b2f(d.u[0]) * f0.x);
    r.u[1] = f2b(b2f(d.u[1]) * f0.y);
    r.u[2] = f2b(b2f(d.u[2]) * f0.z);
    r.u[3] = f2b(b2f(d.u[3]) * f0.w);
    r.u[4] = f2b(b2f(d.u[4]) * f1.x);
    r.u[5] = f2b(b2f(d.u[5]) * f1.y);
    r.u[6] = f2b(b2f(d.u[6]) * f1.z);
    r.u[7] = f2b(b2f(d.u[7]) * f1.w);
    *(uint4*)(out + base) = r.v;
}

// ---------------------------------------------------------------------------
extern "C" void kernel_launch(void* const* d_in, const int* in_sizes, int n_in,
                              void* d_out, int out_size, void* d_ws, size_t ws_size,
                              hipStream_t stream) {
    const float* emb    = (const float*)d_in[0];
    const float* trk    = (const float*)d_in[1];
    const float* l0     = (const float*)d_in[2];
    const float* l1     = (const float*)d_in[3];
    const float* l2     = (const float*)d_in[4];
    const float* b_p1w  = (const float*)d_in[5];
    const float* b_p1b  = (const float*)d_in[6];
    const float* b_p2w  = (const float*)d_in[7];
    const float* b_p3w  = (const float*)d_in[8];
    const float* b_c1w  = (const float*)d_in[9];
    const float* b_c1b  = (const float*)d_in[10];
    const float* b_c2w  = (const float*)d_in[11];
    const float* b_c2b  = (const float*)d_in[12];
    const float* h_p1w  = (const float*)d_in[13];
    const float* h_p1b  = (const float*)d_in[14];
    const float* h_p2w  = (const float*)d_in[15];
    const float* h_p3w  = (const float*)d_in[16];
    const float* h_c1aw = (const float*)d_in[17];
    const float* h_c1ab = (const float*)d_in[18];
    const float* h_c1bw = (const float*)d_in[19];
    const float* h_c1bb = (const float*)d_in[20];
    const float* h_c2aw = (const float*)d_in[21];
    const float* h_c2ab = (const float*)d_in[22];
    const float* h_c2bw = (const float*)d_in[23];
    const float* h_c2bb = (const float*)d_in[24];
    const float* h_c2cw = (const float*)d_in[25];
    const float* h_c2cb = (const float*)d_in[26];

    float* outp = (float*)d_out;   // [0,32768): hmmap ; [32768,163840): siambox NHWC

    const size_t ACT = (size_t)BB * CC * HWSZ;   // 8,388,608 elems
    const size_t WT  = 9 * 8 * 256 * 32;         // 589,824 elems

    unsigned short* l0bf = (unsigned short*)d_ws;
    unsigned short* wt0  = l0bf + ACT;
    unsigned short* wt1  = wt0 + WT;
    unsigned short* wt2  = wt1 + WT;
    unsigned short* wt3  = wt2 + WT;
    unsigned short* wt4  = wt3 + WT;
    unsigned short* Db   = wt4 + WT;
    unsigned short* X1   = Db + ACT;
    unsigned short* X2   = X1 + ACT;
    float* sbuf   = (float*)(X2 + ACT);
    float* xfb    = sbuf + (size_t)BB * HWSZ;
    float* tn     = xfb + (size_t)BB * HWSZ;
    float* invmax = tn + (size_t)BB * KK * CC;
    int*   idxb   = (int*)(invmax + 2);
    float* ybuf   = (float*)X1;   // alias: y consumed before X1 first written

    dim3 blk2d(32, 8);
    dim3 grdConvM(128, 2, 2);
    dim3 grdPerBC(4, 16, BB * CC);
    dim3 grdSmall(256, BB);

    // ---- preps ----
    cvtbf_kernel<<<(unsigned)(ACT / 8 / 256), 256, 0, stream>>>(l0, l0bf);
    wprep_kernel<<<(unsigned)(WT / 256), 256, 0, stream>>>(b_p1w, wt0);
    wprep_kernel<<<(unsigned)(WT / 256), 256, 0, stream>>>(b_c1w, wt1);
    wprep_kernel<<<(unsigned)(WT / 256), 256, 0, stream>>>(h_p1w, wt2);
    wprep_kernel<<<(unsigned)(WT / 256), 256, 0, stream>>>(h_c2aw, wt3);
    wprep_kernel<<<(unsigned)(WT / 256), 256, 0, stream>>>(h_c2bw, wt4);

    // ---- correlation map ----
    tnorm_kernel<<<1, 128, 0, stream>>>(trk, tn);
    y_kernel<<<8192, 256, 0, stream>>>(emb, tn, ybuf);
    argmax_kernel<<<BB * KK, 256, 0, stream>>>(ybuf, idxb);
    smap_kernel<<<dim3(64, BB), 256, 0, stream>>>(ybuf, idxb, sbuf);
    smax_kernel<<<BB, 256, 0, stream>>>(sbuf, invmax);

    // ---- box head ----
    deconv_kernel<<<grdPerBC, blk2d, 0, stream>>>(l1, l2, b_p2w, b_p3w, Db);
    conv_mfma_kernel<1><<<grdConvM, 256, 0, stream>>>(l0bf, wt0, b_p1b, Db, X1);     // xd_box
    conv_mfma_kernel<0><<<grdConvM, 256, 0, stream>>>(X1, wt1, b_c1b, nullptr, X2);  // xb
    small_conv_kernel<4, 0><<<grdSmall, 256, 0, stream>>>(X2, b_c2w, b_c2b, outp + BB * HWSZ);

    // ---- heatmap head ----
    deconv_kernel<<<grdPerBC, blk2d, 0, stream>>>(l1, l2, h_p2w, h_p3w, Db);
    conv_mfma_kernel<1><<<grdConvM, 256, 0, stream>>>(l0bf, wt2, h_p1b, Db, X1);     // xd_hm
    conv_c1a_kernel<<<grdPerBC, blk2d, 0, stream>>>(sbuf, invmax, h_c1aw, h_c1ab, X2);   // t1 (bf16)
    small_conv_kernel<1, 1><<<grdSmall, 256, 0, stream>>>(X2, h_c1bw, h_c1bb, xfb);  // xf
    mul_kernel<<<4096, 256, 0, stream>>>(xfb, X1, X2);                               // t
    conv_mfma_kernel<0><<<grdConvM, 256, 0, stream>>>(X2, wt3, h_c2ab, nullptr, Db); // t2
    conv_mfma_kernel<0><<<grdConvM, 256, 0, stream>>>(Db, wt4, h_c2bb, nullptr, X1); // t3
    small_conv_kernel<1, 2><<<grdSmall, 256, 0, stream>>>(X1, h_c2cw, h_c2cb, outp); // hmmap
}

// Round 4
// 927.963 us; speedup vs baseline: 7.6252x; 1.2492x over previous
//
#include <hip/hip_runtime.h>
#include <math.h>

#define HH 128
#define WW 128
#define HWSZ 16384   // 128*128
#define CC 256
#define KK 64
#define BB 2

typedef __bf16 bf16x8_t __attribute__((ext_vector_type(8)));
typedef float  f32x4_t  __attribute__((ext_vector_type(4)));

__device__ __forceinline__ float silu_f(float v) { return v / (1.f + expf(-v)); }
__device__ __forceinline__ float sigm_f(float v) { return 1.f / (1.f + expf(-v)); }

__device__ __forceinline__ float b2f(unsigned short u) {
    union { unsigned int i; float f; } x; x.i = ((unsigned int)u) << 16; return x.f;
}
__device__ __forceinline__ unsigned short f2b(float f) {
    union { float f; unsigned int i; } x; x.f = f;
    unsigned int r = x.i + 0x7FFFu + ((x.i >> 16) & 1u);
    return (unsigned short)(r >> 16);
}

// ---------------------------------------------------------------------------
// prep: fp32 -> bf16 copy (8 elems/thread)
// ---------------------------------------------------------------------------
__global__ __launch_bounds__(256) void cvtbf_kernel(const float* __restrict__ in,
                                                    unsigned short* __restrict__ out) {
    size_t i = ((size_t)blockIdx.x * 256 + threadIdx.x) * 8;
    float4 a = *(const float4*)(in + i);
    float4 b = *(const float4*)(in + i + 4);
    union { unsigned short u[8]; uint4 v; } pk;
    pk.u[0] = f2b(a.x); pk.u[1] = f2b(a.y); pk.u[2] = f2b(a.z); pk.u[3] = f2b(a.w);
    pk.u[4] = f2b(b.x); pk.u[5] = f2b(b.y); pk.u[6] = f2b(b.z); pk.u[7] = f2b(b.w);
    *(uint4*)(out + i) = pk.v;
}

// ---------------------------------------------------------------------------
// prep: weights OIHW fp32 [256][256][3][3] -> bf16 [9][8][256][32]
// ---------------------------------------------------------------------------
__global__ __launch_bounds__(256) void wprep_kernel(const float* __restrict__ w,
                                                    unsigned short* __restrict__ wt) {
    int idx = blockIdx.x * 256 + threadIdx.x;       // 0 .. 589823
    int ci  = idx & 31;
    int co  = (idx >> 5) & 255;
    int tcb = idx >> 13;                            // 0..71
    int t   = tcb >> 3;
    int cb  = tcb & 7;
    wt[idx] = f2b(w[((size_t)co * 256 + cb * 32 + ci) * 9 + t]);
}

// ---------------------------------------------------------------------------
// tracklet normalize
// ---------------------------------------------------------------------------
__global__ __launch_bounds__(128) void tnorm_kernel(const float* __restrict__ trk,
                                                    float* __restrict__ tn) {
    int r = threadIdx.x;
    if (r >= BB * KK) return;
    const float* p = trk + (size_t)r * CC;
    float ss = 0.f;
    for (int c = 0; c < CC; c++) { float v = p[c]; ss += v * v; }
    float sc = 1.f / fmaxf(sqrtf(ss), 1e-12f);
    float* q = tn + (size_t)r * CC;
    for (int c = 0; c < CC; c++) q[c] = p[c] * sc;
}

// ---------------------------------------------------------------------------
// ycorr: y[b,k,hw] = s_e[hw] * relu(dot(e_raw[hw], tn[k]))   (s_e>0 commutes
// with relu).  Block: 32 px x 64 k, LDS rank-k update, pad stride 260
// (float4-group stride 65 odd -> conflict-free strided b128).
// ---------------------------------------------------------------------------
#define EPAD 260
__global__ __launch_bounds__(256) void ycorr_kernel(const float* __restrict__ emb,
                                                    const float* __restrict__ tn,
                                                    float* __restrict__ y) {
    __shared__ __align__(16) float E[32 * EPAD];
    __shared__ __align__(16) float T[64 * EPAD];
    __shared__ float SE[32];

    const int tid = threadIdx.x;
    const int b   = blockIdx.y;
    const int hw0 = blockIdx.x * 32;

    // stage raw E tile (32 px x 256 c)
    const float4* esrc = (const float4*)(emb + ((size_t)b * HWSZ + hw0) * CC);
    #pragma unroll
    for (int i = 0; i < 8; i++) {
        int q  = tid + i * 256;            // 0..2047
        int px = q >> 6, c4 = q & 63;
        *(float4*)&E[px * EPAD + c4 * 4] = esrc[(size_t)px * 64 + c4];
    }
    // stage all 64 normalized tracklets
    const float4* tsrc = (const float4*)(tn + (size_t)b * KK * CC);
    #pragma unroll
    for (int i = 0; i < 16; i++) {
        int q = tid + i * 256;             // 0..4095
        int k = q >> 6, c4 = q & 63;
        *(float4*)&T[k * EPAD + c4 * 4] = tsrc[(size_t)k * 64 + c4];
    }
    __syncthreads();

    if (tid < 32) {
        float ss = 0.f;
        const float4* ep = (const float4*)&E[tid * EPAD];
        #pragma unroll 8
        for (int c4 = 0; c4 < 64; c4++) {
            float4 v = ep[c4];
            ss += v.x * v.x + v.y * v.y + v.z * v.z + v.w * v.w;
        }
        SE[tid] = 1.f / fmaxf(sqrtf(ss), 1e-12f);
    }
    __syncthreads();

    const int pg = tid & 15;       // px = j*16 + pg, j = 0..1
    const int kg = tid >> 4;       // k  = kk*16 + kg, kk = 0..3

    float acc[2][4];
    #pragma unroll
    for (int j = 0; j < 2; j++)
        #pragma unroll
        for (int kk = 0; kk < 4; kk++) acc[j][kk] = 0.f;

    const float* E0 = &E[(0 * 16 + pg) * EPAD];
    const float* E1 = &E[(1 * 16 + pg) * EPAD];
    const float* T0 = &T[(0 * 16 + kg) * EPAD];
    const float* T1 = &T[(1 * 16 + kg) * EPAD];
    const float* T2 = &T[(2 * 16 + kg) * EPAD];
    const float* T3 = &T[(3 * 16 + kg) * EPAD];

    #pragma unroll 4
    for (int c4 = 0; c4 < 64; ++c4) {
        float4 e0 = *(const float4*)(E0 + c4 * 4);
        float4 e1 = *(const float4*)(E1 + c4 * 4);
        float4 t0 = *(const float4*)(T0 + c4 * 4);
        float4 t1 = *(const float4*)(T1 + c4 * 4);
        float4 t2 = *(const float4*)(T2 + c4 * 4);
        float4 t3 = *(const float4*)(T3 + c4 * 4);
        #define DOT4(a, t) (fmaf(a.w, t.w, fmaf(a.z, t.z, fmaf(a.y, t.y, a.x * t.x))))
        acc[0][0] += DOT4(e0, t0); acc[0][1] += DOT4(e0, t1);
        acc[0][2] += DOT4(e0, t2); acc[0][3] += DOT4(e0, t3);
        acc[1][0] += DOT4(e1, t0); acc[1][1] += DOT4(e1, t1);
        acc[1][2] += DOT4(e1, t2); acc[1][3] += DOT4(e1, t3);
        #undef DOT4
    }

    #pragma unroll
    for (int j = 0; j < 2; j++) {
        int px = j * 16 + pg;
        float se = SE[px];
        #pragma unroll
        for (int kk = 0; kk < 4; kk++) {
            int k = kk * 16 + kg;
            y[((size_t)b * KK + k) * HWSZ + hw0 + px] = fmaxf(acc[j][kk], 0.f) * se;
        }
    }
}

// ---------------------------------------------------------------------------
// first-occurrence argmax per (b,k)
// ---------------------------------------------------------------------------
__global__ __launch_bounds__(256) void argmax_kernel(const float* __restrict__ y,
                                                     int* __restrict__ idxout) {
    int bk = blockIdx.x;
    const float* p = y + (size_t)bk * HWSZ;
    int t = threadIdx.x;
    float best = -1.f; int bi = 1 << 30;
    for (int i = t; i < HWSZ; i += 256) {
        float v = p[i];
        if (v > best) { best = v; bi = i; }
    }
    __shared__ float sv[256];
    __shared__ int   si[256];
    sv[t] = best; si[t] = bi;
    __syncthreads();
    for (int s = 128; s > 0; s >>= 1) {
        if (t < s) {
            float v2 = sv[t + s]; int i2 = si[t + s];
            if (v2 > sv[t] || (v2 == sv[t] && i2 < si[t])) { sv[t] = v2; si[t] = i2; }
        }
        __syncthreads();
    }
    if (t == 0) idxout[bk] = si[0];
}

// ---------------------------------------------------------------------------
// s[b,hw] = sum_k y * mask
// ---------------------------------------------------------------------------
__global__ __launch_bounds__(256) void smap_kernel(const float* __restrict__ y,
                                                   const int* __restrict__ idx,
                                                   float* __restrict__ s) {
    int b  = blockIdx.y;
    int hw = blockIdx.x * 256 + threadIdx.x;
    int h  = hw >> 7, w = hw & 127;
    __shared__ int ai[KK], aj[KK];
    if (threadIdx.x < KK) {
        int v = idx[b * KK + threadIdx.x];
        ai[threadIdx.x] = v >> 7;
        aj[threadIdx.x] = v & 127;
    }
    __syncthreads();
    const float* yb = y + (size_t)b * KK * HWSZ;
    float acc = 0.f;
    #pragma unroll 8
    for (int k = 0; k < KK; k++) {
        float v = yb[(size_t)k * HWSZ + hw];
        bool in = (h >= ai[k] - 8) && (h < ai[k] + 8) && (w >= aj[k] - 8) && (w < aj[k] + 8);
        acc += in ? v : 0.f;
    }
    s[(size_t)b * HWSZ + hw] = acc;
}

__global__ __launch_bounds__(256) void smax_kernel(const float* __restrict__ s,
                                                   float* __restrict__ invmax) {
    int b = blockIdx.x;
    const float* p = s + (size_t)b * HWSZ;
    float m = -1e30f;
    for (int i = threadIdx.x; i < HWSZ; i += 256) m = fmaxf(m, p[i]);
    __shared__ float sm[256];
    sm[threadIdx.x] = m;
    __syncthreads();
    for (int st = 128; st > 0; st >>= 1) {
        if (threadIdx.x < st) sm[threadIdx.x] = fmaxf(sm[threadIdx.x], sm[threadIdx.x + st]);
        __syncthreads();
    }
    if (threadIdx.x == 0) invmax[b] = 1.f / sm[0];
}

// ---------------------------------------------------------------------------
// grouped deconvs -> bf16 out
// ---------------------------------------------------------------------------
__global__ __launch_bounds__(256) void deconv_kernel(const float* __restrict__ l1,
                                                     const float* __restrict__ l2,
                                                     const float* __restrict__ w2,
                                                     const float* __restrict__ w3,
                                                     unsigned short* __restrict__ out) {
    int x = blockIdx.x * 32 + threadIdx.x;
    int y = blockIdx.y * 8 + threadIdx.y;
    int g = blockIdx.z & 255;
    int b = blockIdx.z >> 8;

    float acc = 0.f;
    {
        const float* l1b = l1 + ((size_t)b * 2 * CC + 2 * g) * 4096;
        const float* w2g = w2 + (size_t)g * 32;
        int pyo = y & 1, pxo = x & 1;
        int my0 = (y + pyo - 2) >> 1;
        int mx0 = (x + pxo - 2) >> 1;
        #pragma unroll
        for (int i = 0; i < 2; i++) {
            const float* li = l1b + (size_t)i * 4096;
            const float* wi = w2g + i * 16;
            #pragma unroll
            for (int a = 0; a < 2; a++) {
                int m = my0 + a;
                if ((unsigned)m >= 64u) continue;
                int p = pyo + 2 * a;
                #pragma unroll
                for (int c = 0; c < 2; c++) {
                    int n = mx0 + c;
                    if ((unsigned)n >= 64u) continue;
                    int q = pxo + 2 * c;
                    acc = fmaf(wi[p * 4 + q], li[m * 64 + n], acc);
                }
            }
        }
    }
    {
        const float* l2b = l2 + ((size_t)b * 4 * CC + 4 * g) * 1024;
        const float* w3g = w3 + (size_t)g * 256;
        int py3 = (5 - (y & 3)) & 3, px3 = (5 - (x & 3)) & 3;
        int my0 = (y + py3 - 5) >> 2;
        int mx0 = (x + px3 - 5) >> 2;
        #pragma unroll
        for (int i = 0; i < 4; i++) {
            const float* li = l2b + (size_t)i * 1024;
            const float* wi = w3g + i * 64;
            #pragma unroll
            for (int a = 0; a < 2; a++) {
                int m = my0 + a;
                if ((unsigned)m >= 32u) continue;
                int p = py3 + 4 * a;
                #pragma unroll
                for (int c = 0; c < 2; c++) {
                    int n = mx0 + c;
                    if ((unsigned)n >= 32u) continue;
                    int q = px3 + 4 * c;
                    acc = fmaf(wi[p * 8 + q], li[m * 32 + n], acc);
                }
            }
        }
    }
    out[(((size_t)b * CC + g) * HWSZ) + y * WW + x] = f2b(acc);
}

// ---------------------------------------------------------------------------
// BIG conv 256->256 3x3, bf16 MFMA implicit GEMM.
// ---------------------------------------------------------------------------
template <int ADDB>
__global__ __launch_bounds__(256) void conv_mfma_kernel(
    const unsigned short* __restrict__ in,    // bf16 NCHW
    const unsigned short* __restrict__ wt,    // bf16 [9][8][256][32]
    const float* __restrict__ bias,
    const unsigned short* __restrict__ addb,  // bf16 NCHW (ADDB=1)
    unsigned short* __restrict__ out)
{
    __shared__ __align__(16) unsigned short Alds[3 * 130 * 40];
    __shared__ __align__(16) unsigned short Blds[2 * 128 * 40];

    const int tid  = threadIdx.x;
    const int lane = tid & 63;
    const int wv   = tid >> 6;
    const int wco  = wv >> 1;
    const int wpx  = wv & 1;
    const int l15  = lane & 15;
    const int kg   = lane >> 4;

    const int y0  = blockIdx.x;
    const int co0 = blockIdx.y * 128;
    const int b   = blockIdx.z;

    const unsigned short* inb = in + (size_t)b * CC * HWSZ;

    int pixbase[4], wbase[4];
    #pragma unroll
    for (int f = 0; f < 4; f++) {
        int x = wpx * 64 + f * 16 + l15;
        pixbase[f] = x * 40 + kg * 8;
        int cr = wco * 64 + f * 16 + l15;
        wbase[f] = cr * 40 + kg * 8;
    }

    f32x4_t acc[4][4];
    #pragma unroll
    for (int i = 0; i < 4; i++)
        #pragma unroll
        for (int j = 0; j < 4; j++)
            acc[i][j] = (f32x4_t){0.f, 0.f, 0.f, 0.f};

    auto stage_A = [&](int cb) {
        int cbase = cb * 32;
        for (int q = tid; q < 1560; q += 256) {
            int rg = q / 130;
            int xx = q - rg * 130;
            int r = rg >> 2, g = rg & 3;
            int gy = y0 - 1 + r;
            int gx = xx - 1;
            bool ok = ((unsigned)gy < 128u) && ((unsigned)gx < 128u);
            const unsigned short* src = inb + (size_t)(cbase + g * 8) * HWSZ + (gy * 128 + gx);
            union { unsigned short u[8]; uint4 v; } pk;
            #pragma unroll
            for (int e = 0; e < 8; e++)
                pk.u[e] = ok ? src[(size_t)e * HWSZ] : (unsigned short)0;
            *reinterpret_cast<uint4*>(&Alds[(r * 130 + xx) * 40 + g * 8]) = pk.v;
        }
    };
    auto stage_B = [&](int cbn, int tn, int pn) {
        size_t base = ((size_t)(tn * 8 + cbn) * 256 + co0) * 32;
        #pragma unroll
        for (int h = 0; h < 2; h++) {
            int chunk = tid + h * 256;
            uint4 v = *reinterpret_cast<const uint4*>(wt + base + (size_t)chunk * 8);
            int co = chunk >> 2, g = chunk & 3;
            *reinterpret_cast<uint4*>(&Blds[(pn * 128 + co) * 40 + g * 8]) = v;
        }
    };

    stage_B(0, 0, 0);
    for (int cb = 0; cb < 8; ++cb) {
        if (cb) __syncthreads();      // prior taps done before overwriting A
        stage_A(cb);
        #pragma unroll
        for (int t = 0; t < 9; ++t) {
            __syncthreads();          // A + B(s) visible; prev compute done
            if (t < 8)            stage_B(cb, t + 1, (cb + t + 1) & 1);
            else if (cb < 7)      stage_B(cb + 1, 0, (cb + 1) & 1);

            const int tapoff = ((t / 3) * 130 + (t % 3)) * 40;
            const int bofs   = ((cb + t) & 1) * (128 * 40);

            bf16x8_t pfr[4], wfr[4];
            #pragma unroll
            for (int f = 0; f < 4; f++)
                pfr[f] = *reinterpret_cast<const bf16x8_t*>(&Alds[pixbase[f] + tapoff]);
            #pragma unroll
            for (int f = 0; f < 4; f++)
                wfr[f] = *reinterpret_cast<const bf16x8_t*>(&Blds[wbase[f] + bofs]);

            #pragma unroll
            for (int cf = 0; cf < 4; cf++)
                #pragma unroll
                for (int pf = 0; pf < 4; pf++)
                    acc[cf][pf] = __builtin_amdgcn_mfma_f32_16x16x32_bf16(
                        wfr[cf], pfr[pf], acc[cf][pf], 0, 0, 0);
        }
    }

    size_t outB = (size_t)b * CC * HWSZ + (size_t)y0 * 128;
    #pragma unroll
    for (int cf = 0; cf < 4; cf++) {
        int cobase = co0 + wco * 64 + cf * 16 + kg * 4;
        #pragma unroll
        for (int j = 0; j < 4; j++) {
            int co = cobase + j;
            float bs = bias[co];
            size_t rowp = outB + (size_t)co * HWSZ;
            #pragma unroll
            for (int pf = 0; pf < 4; pf++) {
                int x = wpx * 64 + pf * 16 + l15;
                float v = silu_f(acc[cf][pf][j] + bs);
                if (ADDB) v += b2f(addb[rowp + x]);
                out[rowp + x] = f2b(v);
            }
        }
    }
}

// ---------------------------------------------------------------------------
// conv 1->256 (input = s * invmax), + bias, silu -> bf16
// ---------------------------------------------------------------------------
__global__ __launch_bounds__(256) void conv_c1a_kernel(const float* __restrict__ s,
                                                       const float* __restrict__ invmax,
                                                       const float* __restrict__ w,
                                                       const float* __restrict__ bias,
                                                       unsigned short* __restrict__ out) {
    int x = blockIdx.x * 32 + threadIdx.x;
    int y = blockIdx.y * 8 + threadIdx.y;
    int co = blockIdx.z & 255;
    int b  = blockIdx.z >> 8;
    float im = invmax[b];
    const float* sb = s + (size_t)b * HWSZ;
    const float* wp = w + (size_t)co * 9;
    float sum = 0.f;
    #pragma unroll
    for (int dy = 0; dy < 3; dy++) {
        int yy = y + dy - 1;
        if ((unsigned)yy >= 128u) continue;
        #pragma unroll
        for (int dx = 0; dx < 3; dx++) {
            int xx = x + dx - 1;
            if ((unsigned)xx >= 128u) continue;
            sum = fmaf(wp[dy * 3 + dx], sb[yy * WW + xx], sum);
        }
    }
    float v = silu_f(sum * im + bias[co]);
    out[(((size_t)b * CC + co) * HWSZ) + y * WW + x] = f2b(v);
}

// ---------------------------------------------------------------------------
// Small conv 256 -> COUT (COUT in {1,4}), bf16 NCHW input, fp32 weights OIHW.
// ---------------------------------------------------------------------------
template <int COUT, int MODE>
__global__ __launch_bounds__(256) void small_conv_kernel(
    const unsigned short* __restrict__ in,
    const float* __restrict__ w,        // [COUT][256][3][3]
    const float* __restrict__ bias,
    float* __restrict__ out)
{
    __shared__ __align__(16) float stripe[16][3][72];
    __shared__ float sacc[4][64][COUT];

    const int tid = threadIdx.x;
    const int p   = tid & 63;
    const int qd  = __builtin_amdgcn_readfirstlane(tid >> 6);  // wave id = ci quarter
    const int xh  = blockIdx.x & 1;
    const int y   = blockIdx.x >> 1;
    const int b   = blockIdx.y;
    const int x0  = xh * 64;

    const unsigned short* inb = in + (size_t)b * CC * HWSZ;

    float acc[COUT];
    #pragma unroll
    for (int c = 0; c < COUT; c++) acc[c] = 0.f;

    for (int it = 0; it < 16; ++it) {
        __syncthreads();
        for (int q = tid; q < 432; q += 256) {
            int ciq = q / 27;
            int rem = q - ciq * 27;
            int r   = rem / 9;
            int c8  = rem - r * 9;
            int ci  = it * 16 + ciq;
            int gy  = y - 1 + r;
            int gx0 = x0 - 1 + c8 * 8;
            const unsigned short* src = inb + (size_t)ci * HWSZ + gy * 128;
            float v[8];
            #pragma unroll
            for (int e = 0; e < 8; e++) {
                int gx = gx0 + e;
                v[e] = ((unsigned)gy < 128u && (unsigned)gx < 128u) ? b2f(src[gx]) : 0.f;
            }
            float4* dst = (float4*)&stripe[ciq][r][c8 * 8];
            dst[0] = make_float4(v[0], v[1], v[2], v[3]);
            dst[1] = make_float4(v[4], v[5], v[6], v[7]);
        }
        __syncthreads();
        #pragma unroll
        for (int j = 0; j < 4; j++) {
            int ciq = qd * 4 + j;
            int ci  = it * 16 + ciq;
            float i00 = stripe[ciq][0][p], i01 = stripe[ciq][0][p + 1], i02 = stripe[ciq][0][p + 2];
            float i10 = stripe[ciq][1][p], i11 = stripe[ciq][1][p + 1], i12 = stripe[ciq][1][p + 2];
            float i20 = stripe[ciq][2][p], i21 = stripe[ciq][2][p + 1], i22 = stripe[ciq][2][p + 2];
            #pragma unroll
            for (int co = 0; co < COUT; co++) {
                const float* wc = w + ((size_t)co * CC + ci) * 9;
                float a = acc[co];
                a = fmaf(i00, wc[0], a);
                a = fmaf(i01, wc[1], a);
                a = fmaf(i02, wc[2], a);
                a = fmaf(i10, wc[3], a);
                a = fmaf(i11, wc[4], a);
                a = fmaf(i12, wc[5], a);
                a = fmaf(i20, wc[6], a);
                a = fmaf(i21, wc[7], a);
                a = fmaf(i22, wc[8], a);
                acc[co] = a;
            }
        }
    }

    #pragma unroll
    for (int c = 0; c < COUT; c++) sacc[qd][p][c] = acc[c];
    __syncthreads();
    if (tid < 64) {
        float r[COUT];
        #pragma unroll
        for (int c = 0; c < COUT; c++)
            r[c] = sacc[0][tid][c] + sacc[1][tid][c] + sacc[2][tid][c] + sacc[3][tid][c] + bias[c];
        size_t pixidx = (size_t)b * HWSZ + (size_t)y * WW + x0 + tid;
        if (MODE == 0) {
            ((float4*)out)[pixidx] = make_float4(r[0], r[COUT > 1 ? 1 : 0],
                                                 r[COUT > 2 ? 2 : 0], r[COUT > 3 ? 3 : 0]);
        } else if (MODE == 1) {
            out[pixidx] = r[0];
        } else {
            out[pixidx] = sigm_f(r[0]);
        }
    }
}

// ---------------------------------------------------------------------------
// t = xf(fp32,[b,hw]) * xd(bf16) -> bf16
// ---------------------------------------------------------------------------
__global__ __launch_bounds__(256) void mul_kernel(const float* __restrict__ xf,
                                                  const unsigned short* __restrict__ xd,
                                                  unsigned short* __restrict__ out) {
    size_t base = ((size_t)blockIdx.x * 256 + threadIdx.x) * 8;
    int b  = (int)(base >> 22);
    int hw = (int)(base & (HWSZ - 1));
    union { unsigned short u[8]; uint4 v; } d, r;
    d.v = *(const uint4*)(xd + base);
    const float* xfp = xf + (size_t)b * HWSZ + hw;
    float4 f0 = *(const float4*)xfp;
    float4 f1 = *(const float4*)(xfp + 4);
    r.u[0] = f2b(b2f(d.u[0]) * f0.x);
    r.u[1] = f2b(b2f(d.u[1]) * f0.y);
    r.u[2] = f2b(b2f(d.u[2]) * f0.z);
    r.u[3] = f2b(b2f(d.u[3]) * f0.w);
    r.u[4] = f2b(b2f(d.u[4]) * f1.x);
    r.u[5] = f2b(b2f(d.u[5]) * f1.y);
    r.u[6] = f2b(b2f(d.u[6]) * f1.z);
    r.u[7] = f2b(b2f(d.u[7]) * f1.w);
    *(uint4*)(out + base) = r.v;
}

// ---------------------------------------------------------------------------
extern "C" void kernel_launch(void* const* d_in, const int* in_sizes, int n_in,
                              void* d_out, int out_size, void* d_ws, size_t ws_size,
                              hipStream_t stream) {
    const float* emb    = (const float*)d_in[0];
    const float* trk    = (const float*)d_in[1];
    const float* l0     = (const float*)d_in[2];
    const float* l1     = (const float*)d_in[3];
    const float* l2     = (const float*)d_in[4];
    const float* b_p1w  = (const float*)d_in[5];
    const float* b_p1b  = (const float*)d_in[6];
    const float* b_p2w  = (const float*)d_in[7];
    const float* b_p3w  = (const float*)d_in[8];
    const float* b_c1w  = (const float*)d_in[9];
    const float* b_c1b  = (const float*)d_in[10];
    const float* b_c2w  = (const float*)d_in[11];
    const float* b_c2b  = (const float*)d_in[12];
    const float* h_p1w  = (const float*)d_in[13];
    const float* h_p1b  = (const float*)d_in[14];
    const float* h_p2w  = (const float*)d_in[15];
    const float* h_p3w  = (const float*)d_in[16];
    const float* h_c1aw = (const float*)d_in[17];
    const float* h_c1ab = (const float*)d_in[18];
    const float* h_c1bw = (const float*)d_in[19];
    const float* h_c1bb = (const float*)d_in[20];
    const float* h_c2aw = (const float*)d_in[21];
    const float* h_c2ab = (const float*)d_in[22];
    const float* h_c2bw = (const float*)d_in[23];
    const float* h_c2bb = (const float*)d_in[24];
    const float* h_c2cw = (const float*)d_in[25];
    const float* h_c2cb = (const float*)d_in[26];

    float* outp = (float*)d_out;   // [0,32768): hmmap ; [32768,163840): siambox NHWC

    const size_t ACT = (size_t)BB * CC * HWSZ;   // 8,388,608 elems
    const size_t WT  = 9 * 8 * 256 * 32;         // 589,824 elems

    unsigned short* l0bf = (unsigned short*)d_ws;
    unsigned short* wt0  = l0bf + ACT;
    unsigned short* wt1  = wt0 + WT;
    unsigned short* wt2  = wt1 + WT;
    unsigned short* wt3  = wt2 + WT;
    unsigned short* wt4  = wt3 + WT;
    unsigned short* Db   = wt4 + WT;
    unsigned short* X1   = Db + ACT;
    unsigned short* X2   = X1 + ACT;
    float* sbuf   = (float*)(X2 + ACT);
    float* xfb    = sbuf + (size_t)BB * HWSZ;
    float* tn     = xfb + (size_t)BB * HWSZ;
    float* invmax = tn + (size_t)BB * KK * CC;
    int*   idxb   = (int*)(invmax + 2);
    float* ybuf   = (float*)X1;   // alias: y consumed before X1 first written

    dim3 blk2d(32, 8);
    dim3 grdConvM(128, 2, 2);
    dim3 grdPerBC(4, 16, BB * CC);
    dim3 grdSmall(256, BB);

    // ---- preps ----
    cvtbf_kernel<<<(unsigned)(ACT / 8 / 256), 256, 0, stream>>>(l0, l0bf);
    wprep_kernel<<<(unsigned)(WT / 256), 256, 0, stream>>>(b_p1w, wt0);
    wprep_kernel<<<(unsigned)(WT / 256), 256, 0, stream>>>(b_c1w, wt1);
    wprep_kernel<<<(unsigned)(WT / 256), 256, 0, stream>>>(h_p1w, wt2);
    wprep_kernel<<<(unsigned)(WT / 256), 256, 0, stream>>>(h_c2aw, wt3);
    wprep_kernel<<<(unsigned)(WT / 256), 256, 0, stream>>>(h_c2bw, wt4);

    // ---- correlation map ----
    tnorm_kernel<<<1, 128, 0, stream>>>(trk, tn);
    ycorr_kernel<<<dim3(512, BB), 256, 0, stream>>>(emb, tn, ybuf);
    argmax_kernel<<<BB * KK, 256, 0, stream>>>(ybuf, idxb);
    smap_kernel<<<dim3(64, BB), 256, 0, stream>>>(ybuf, idxb, sbuf);
    smax_kernel<<<BB, 256, 0, stream>>>(sbuf, invmax);

    // ---- box head ----
    deconv_kernel<<<grdPerBC, blk2d, 0, stream>>>(l1, l2, b_p2w, b_p3w, Db);
    conv_mfma_kernel<1><<<grdConvM, 256, 0, stream>>>(l0bf, wt0, b_p1b, Db, X1);     // xd_box
    conv_mfma_kernel<0><<<grdConvM, 256, 0, stream>>>(X1, wt1, b_c1b, nullptr, X2);  // xb
    small_conv_kernel<4, 0><<<grdSmall, 256, 0, stream>>>(X2, b_c2w, b_c2b, outp + BB * HWSZ);

    // ---- heatmap head ----
    deconv_kernel<<<grdPerBC, blk2d, 0, stream>>>(l1, l2, h_p2w, h_p3w, Db);
    conv_mfma_kernel<1><<<grdConvM, 256, 0, stream>>>(l0bf, wt2, h_p1b, Db, X1);     // xd_hm
    conv_c1a_kernel<<<grdPerBC, blk2d, 0, stream>>>(sbuf, invmax, h_c1aw, h_c1ab, X2);   // t1 (bf16)
    small_conv_kernel<1, 1><<<grdSmall, 256, 0, stream>>>(X2, h_c1bw, h_c1bb, xfb);  // xf
    mul_kernel<<<4096, 256, 0, stream>>>(xfb, X1, X2);                               // t
    conv_mfma_kernel<0><<<grdConvM, 256, 0, stream>>>(X2, wt3, h_c2ab, nullptr, Db); // t2
    conv_mfma_kernel<0><<<grdConvM, 256, 0, stream>>>(Db, wt4, h_c2bb, nullptr, X1); // t3
    small_conv_kernel<1, 2><<<grdSmall, 256, 0, stream>>>(X1, h_c2cw, h_c2cb, outp); // hmmap
}

// Round 5
// 748.008 us; speedup vs baseline: 9.4596x; 1.2406x over previous
//
#include <hip/hip_runtime.h>
#include <math.h>

#define HH 128
#define WW 128
#define HWSZ 16384   // 128*128
#define CC 256
#define KK 64
#define BB 2

typedef __bf16 bf16x8_t __attribute__((ext_vector_type(8)));
typedef float  f32x4_t  __attribute__((ext_vector_type(4)));

__device__ __forceinline__ float silu_f(float v) { return v / (1.f + expf(-v)); }
__device__ __forceinline__ float sigm_f(float v) { return 1.f / (1.f + expf(-v)); }

__device__ __forceinline__ float b2f(unsigned short u) {
    union { unsigned int i; float f; } x; x.i = ((unsigned int)u) << 16; return x.f;
}
__device__ __forceinline__ unsigned short f2b(float f) {
    union { float f; unsigned int i; } x; x.f = f;
    unsigned int r = x.i + 0x7FFFu + ((x.i >> 16) & 1u);
    return (unsigned short)(r >> 16);
}

// ---------------------------------------------------------------------------
// prep: fp32 -> bf16 copy (8 elems/thread)
// ---------------------------------------------------------------------------
__global__ __launch_bounds__(256) void cvtbf_kernel(const float* __restrict__ in,
                                                    unsigned short* __restrict__ out) {
    size_t i = ((size_t)blockIdx.x * 256 + threadIdx.x) * 8;
    float4 a = *(const float4*)(in + i);
    float4 b = *(const float4*)(in + i + 4);
    union { unsigned short u[8]; uint4 v; } pk;
    pk.u[0] = f2b(a.x); pk.u[1] = f2b(a.y); pk.u[2] = f2b(a.z); pk.u[3] = f2b(a.w);
    pk.u[4] = f2b(b.x); pk.u[5] = f2b(b.y); pk.u[6] = f2b(b.z); pk.u[7] = f2b(b.w);
    *(uint4*)(out + i) = pk.v;
}

// ---------------------------------------------------------------------------
// prep: weights OIHW fp32 [256][256][3][3] -> bf16 [9][8][256][32]
// ---------------------------------------------------------------------------
__global__ __launch_bounds__(256) void wprep_kernel(const float* __restrict__ w,
                                                    unsigned short* __restrict__ wt) {
    int idx = blockIdx.x * 256 + threadIdx.x;       // 0 .. 589823
    int ci  = idx & 31;
    int co  = (idx >> 5) & 255;
    int tcb = idx >> 13;                            // 0..71
    int t   = tcb >> 3;
    int cb  = tcb & 7;
    wt[idx] = f2b(w[((size_t)co * 256 + cb * 32 + ci) * 9 + t]);
}

// ---------------------------------------------------------------------------
// tracklet normalize
// ---------------------------------------------------------------------------
__global__ __launch_bounds__(128) void tnorm_kernel(const float* __restrict__ trk,
                                                    float* __restrict__ tn) {
    int r = threadIdx.x;
    if (r >= BB * KK) return;
    const float* p = trk + (size_t)r * CC;
    float ss = 0.f;
    for (int c = 0; c < CC; c++) { float v = p[c]; ss += v * v; }
    float sc = 1.f / fmaxf(sqrtf(ss), 1e-12f);
    float* q = tn + (size_t)r * CC;
    for (int c = 0; c < CC; c++) q[c] = p[c] * sc;
}

// ---------------------------------------------------------------------------
// ycorr: y[b,k,hw] = s_e[hw] * relu(dot(e_raw[hw], tn[k]))
// ---------------------------------------------------------------------------
#define EPAD 260
__global__ __launch_bounds__(256) void ycorr_kernel(const float* __restrict__ emb,
                                                    const float* __restrict__ tn,
                                                    float* __restrict__ y) {
    __shared__ __align__(16) float E[32 * EPAD];
    __shared__ __align__(16) float T[64 * EPAD];
    __shared__ float SE[32];

    const int tid = threadIdx.x;
    const int b   = blockIdx.y;
    const int hw0 = blockIdx.x * 32;

    const float4* esrc = (const float4*)(emb + ((size_t)b * HWSZ + hw0) * CC);
    #pragma unroll
    for (int i = 0; i < 8; i++) {
        int q  = tid + i * 256;
        int px = q >> 6, c4 = q & 63;
        *(float4*)&E[px * EPAD + c4 * 4] = esrc[(size_t)px * 64 + c4];
    }
    const float4* tsrc = (const float4*)(tn + (size_t)b * KK * CC);
    #pragma unroll
    for (int i = 0; i < 16; i++) {
        int q = tid + i * 256;
        int k = q >> 6, c4 = q & 63;
        *(float4*)&T[k * EPAD + c4 * 4] = tsrc[(size_t)k * 64 + c4];
    }
    __syncthreads();

    if (tid < 32) {
        float ss = 0.f;
        const float4* ep = (const float4*)&E[tid * EPAD];
        #pragma unroll 8
        for (int c4 = 0; c4 < 64; c4++) {
            float4 v = ep[c4];
            ss += v.x * v.x + v.y * v.y + v.z * v.z + v.w * v.w;
        }
        SE[tid] = 1.f / fmaxf(sqrtf(ss), 1e-12f);
    }
    __syncthreads();

    const int pg = tid & 15;
    const int kg = tid >> 4;

    float acc[2][4];
    #pragma unroll
    for (int j = 0; j < 2; j++)
        #pragma unroll
        for (int kk = 0; kk < 4; kk++) acc[j][kk] = 0.f;

    const float* E0 = &E[(0 * 16 + pg) * EPAD];
    const float* E1 = &E[(1 * 16 + pg) * EPAD];
    const float* T0 = &T[(0 * 16 + kg) * EPAD];
    const float* T1 = &T[(1 * 16 + kg) * EPAD];
    const float* T2 = &T[(2 * 16 + kg) * EPAD];
    const float* T3 = &T[(3 * 16 + kg) * EPAD];

    #pragma unroll 4
    for (int c4 = 0; c4 < 64; ++c4) {
        float4 e0 = *(const float4*)(E0 + c4 * 4);
        float4 e1 = *(const float4*)(E1 + c4 * 4);
        float4 t0 = *(const float4*)(T0 + c4 * 4);
        float4 t1 = *(const float4*)(T1 + c4 * 4);
        float4 t2 = *(const float4*)(T2 + c4 * 4);
        float4 t3 = *(const float4*)(T3 + c4 * 4);
        #define DOT4(a, t) (fmaf(a.w, t.w, fmaf(a.z, t.z, fmaf(a.y, t.y, a.x * t.x))))
        acc[0][0] += DOT4(e0, t0); acc[0][1] += DOT4(e0, t1);
        acc[0][2] += DOT4(e0, t2); acc[0][3] += DOT4(e0, t3);
        acc[1][0] += DOT4(e1, t0); acc[1][1] += DOT4(e1, t1);
        acc[1][2] += DOT4(e1, t2); acc[1][3] += DOT4(e1, t3);
        #undef DOT4
    }

    #pragma unroll
    for (int j = 0; j < 2; j++) {
        int px = j * 16 + pg;
        float se = SE[px];
        #pragma unroll
        for (int kk = 0; kk < 4; kk++) {
            int k = kk * 16 + kg;
            y[((size_t)b * KK + k) * HWSZ + hw0 + px] = fmaxf(acc[j][kk], 0.f) * se;
        }
    }
}

// ---------------------------------------------------------------------------
// first-occurrence argmax per (b,k)
// ---------------------------------------------------------------------------
__global__ __launch_bounds__(256) void argmax_kernel(const float* __restrict__ y,
                                                     int* __restrict__ idxout) {
    int bk = blockIdx.x;
    const float* p = y + (size_t)bk * HWSZ;
    int t = threadIdx.x;
    float best = -1.f; int bi = 1 << 30;
    for (int i = t; i < HWSZ; i += 256) {
        float v = p[i];
        if (v > best) { best = v; bi = i; }
    }
    __shared__ float sv[256];
    __shared__ int   si[256];
    sv[t] = best; si[t] = bi;
    __syncthreads();
    for (int s = 128; s > 0; s >>= 1) {
        if (t < s) {
            float v2 = sv[t + s]; int i2 = si[t + s];
            if (v2 > sv[t] || (v2 == sv[t] && i2 < si[t])) { sv[t] = v2; si[t] = i2; }
        }
        __syncthreads();
    }
    if (t == 0) idxout[bk] = si[0];
}

// ---------------------------------------------------------------------------
// s[b,hw] = sum_k y * mask
// ---------------------------------------------------------------------------
__global__ __launch_bounds__(256) void smap_kernel(const float* __restrict__ y,
                                                   const int* __restrict__ idx,
                                                   float* __restrict__ s) {
    int b  = blockIdx.y;
    int hw = blockIdx.x * 256 + threadIdx.x;
    int h  = hw >> 7, w = hw & 127;
    __shared__ int ai[KK], aj[KK];
    if (threadIdx.x < KK) {
        int v = idx[b * KK + threadIdx.x];
        ai[threadIdx.x] = v >> 7;
        aj[threadIdx.x] = v & 127;
    }
    __syncthreads();
    const float* yb = y + (size_t)b * KK * HWSZ;
    float acc = 0.f;
    #pragma unroll 8
    for (int k = 0; k < KK; k++) {
        float v = yb[(size_t)k * HWSZ + hw];
        bool in = (h >= ai[k] - 8) && (h < ai[k] + 8) && (w >= aj[k] - 8) && (w < aj[k] + 8);
        acc += in ? v : 0.f;
    }
    s[(size_t)b * HWSZ + hw] = acc;
}

__global__ __launch_bounds__(256) void smax_kernel(const float* __restrict__ s,
                                                   float* __restrict__ invmax) {
    int b = blockIdx.x;
    const float* p = s + (size_t)b * HWSZ;
    float m = -1e30f;
    for (int i = threadIdx.x; i < HWSZ; i += 256) m = fmaxf(m, p[i]);
    __shared__ float sm[256];
    sm[threadIdx.x] = m;
    __syncthreads();
    for (int st = 128; st > 0; st >>= 1) {
        if (threadIdx.x < st) sm[threadIdx.x] = fmaxf(sm[threadIdx.x], sm[threadIdx.x + st]);
        __syncthreads();
    }
    if (threadIdx.x == 0) invmax[b] = 1.f / sm[0];
}

// ---------------------------------------------------------------------------
// grouped deconvs, LDS-resident: one block per (b,g).
// Stage l1 slice [2][64][64] (32KB) + l2 slice [4][32][32] (16KB) into LDS,
// coalesced float4, each HBM element read exactly once. Thread layout
// px = i*256+tid fixes x and y-parity per thread -> 40 tap weights in regs.
// ---------------------------------------------------------------------------
__global__ __launch_bounds__(256) void deconv_kernel(const float* __restrict__ l1,
                                                     const float* __restrict__ l2,
                                                     const float* __restrict__ w2,
                                                     const float* __restrict__ w3,
                                                     unsigned short* __restrict__ out) {
    __shared__ float L1[2][64][64];
    __shared__ float L2[4][32][32];

    const int tid = threadIdx.x;
    const int g   = blockIdx.x & 255;
    const int b   = blockIdx.x >> 8;

    // ---- stage inputs (contiguous slices) ----
    const float4* l1b = (const float4*)(l1 + ((size_t)b * 2 * CC + 2 * g) * 4096);
    float4* L1p = (float4*)&L1[0][0][0];
    #pragma unroll
    for (int i = 0; i < 8; i++) L1p[tid + i * 256] = l1b[tid + i * 256];
    const float4* l2b = (const float4*)(l2 + ((size_t)b * 4 * CC + 4 * g) * 1024);
    float4* L2p = (float4*)&L2[0][0][0];
    #pragma unroll
    for (int i = 0; i < 4; i++) L2p[tid + i * 256] = l2b[tid + i * 256];

    // ---- per-thread constants ----
    const int x    = tid & 127;
    const int ytop = tid >> 7;                 // y = 2*i + ytop
    const float* w2g = w2 + (size_t)g * 32;    // [2][4][4]
    const float* w3g = w3 + (size_t)g * 256;   // [4][8][8]

    // b2 (k4, dil2, pad2)
    const int pxo = x & 1, pyo = ytop & 1;
    const int mx0 = (x + pxo - 2) >> 1;        // fixed col base
    const int dy2 = (ytop + pyo - 2) >> 1;     // my0 = i + dy2
    const bool nok0 = (unsigned)mx0 < 64u;
    const bool nok1 = (unsigned)(mx0 + 1) < 64u;
    const int nc0 = mx0 & 63, nc1 = (mx0 + 1) & 63;
    float W2[2][2][2];
    #pragma unroll
    for (int ci = 0; ci < 2; ci++)
        #pragma unroll
        for (int a = 0; a < 2; a++)
            #pragma unroll
            for (int c = 0; c < 2; c++)
                W2[ci][a][c] = w2g[ci * 16 + (pyo + 2 * a) * 4 + (pxo + 2 * c)];

    // b3 (k8, dil4, pad5); two y-phases: ph=0 -> y&3=ytop, ph=1 -> y&3=ytop+2
    const int px3 = (5 - (x & 3)) & 3;
    const int n30 = (x + px3 - 5) >> 2;        // fixed col base
    const bool n3ok0 = (unsigned)n30 < 32u;
    const bool n3ok1 = (unsigned)(n30 + 1) < 32u;
    const int n3c0 = n30 & 31, n3c1 = (n30 + 1) & 31;
    int dy3[2];
    float W3[2][4][2][2];
    #pragma unroll
    for (int ph = 0; ph < 2; ph++) {
        int py3 = (5 - ((ytop + 2 * ph) & 3)) & 3;
        dy3[ph] = (2 * ph + ytop + py3 - 5) >> 2;   // my0_3 = ii + dy3[ph]
        #pragma unroll
        for (int ci = 0; ci < 4; ci++)
            #pragma unroll
            for (int a = 0; a < 2; a++)
                #pragma unroll
                for (int c = 0; c < 2; c++)
                    W3[ph][ci][a][c] = w3g[ci * 64 + (py3 + 4 * a) * 8 + (px3 + 4 * c)];
    }

    __syncthreads();

    unsigned short* outb = out + ((size_t)b * CC + g) * HWSZ;

    #pragma unroll 2
    for (int ii = 0; ii < 32; ++ii) {
        #pragma unroll
        for (int ph = 0; ph < 2; ph++) {
            const int i = 2 * ii + ph;
            float acc = 0.f;
            // ---- b2 ----
            {
                const int m0 = i + dy2;
                #pragma unroll
                for (int a = 0; a < 2; a++) {
                    int m = m0 + a;
                    bool mok = (unsigned)m < 64u;
                    int mc = m & 63;
                    #pragma unroll
                    for (int ci = 0; ci < 2; ci++) {
                        float v0 = (mok && nok0) ? L1[ci][mc][nc0] : 0.f;
                        float v1 = (mok && nok1) ? L1[ci][mc][nc1] : 0.f;
                        acc = fmaf(W2[ci][a][0], v0, acc);
                        acc = fmaf(W2[ci][a][1], v1, acc);
                    }
                }
            }
            // ---- b3 ----
            {
                const int m0 = ii + dy3[ph];
                #pragma unroll
                for (int a = 0; a < 2; a++) {
                    int m = m0 + a;
                    bool mok = (unsigned)m < 32u;
                    int mc = m & 31;
                    #pragma unroll
                    for (int ci = 0; ci < 4; ci++) {
                        float v0 = (mok && n3ok0) ? L2[ci][mc][n3c0] : 0.f;
                        float v1 = (mok && n3ok1) ? L2[ci][mc][n3c1] : 0.f;
                        acc = fmaf(W3[ph][ci][a][0], v0, acc);
                        acc = fmaf(W3[ph][ci][a][1], v1, acc);
                    }
                }
            }
            outb[(size_t)i * 256 + tid] = f2b(acc);
        }
    }
}

// ---------------------------------------------------------------------------
// BIG conv 256->256 3x3, bf16 MFMA implicit GEMM.
// ---------------------------------------------------------------------------
template <int ADDB>
__global__ __launch_bounds__(256) void conv_mfma_kernel(
    const unsigned short* __restrict__ in,    // bf16 NCHW
    const unsigned short* __restrict__ wt,    // bf16 [9][8][256][32]
    const float* __restrict__ bias,
    const unsigned short* __restrict__ addb,  // bf16 NCHW (ADDB=1)
    unsigned short* __restrict__ out)
{
    __shared__ __align__(16) unsigned short Alds[3 * 130 * 40];
    __shared__ __align__(16) unsigned short Blds[2 * 128 * 40];

    const int tid  = threadIdx.x;
    const int lane = tid & 63;
    const int wv   = tid >> 6;
    const int wco  = wv >> 1;
    const int wpx  = wv & 1;
    const int l15  = lane & 15;
    const int kg   = lane >> 4;

    const int y0  = blockIdx.x;
    const int co0 = blockIdx.y * 128;
    const int b   = blockIdx.z;

    const unsigned short* inb = in + (size_t)b * CC * HWSZ;

    int pixbase[4], wbase[4];
    #pragma unroll
    for (int f = 0; f < 4; f++) {
        int x = wpx * 64 + f * 16 + l15;
        pixbase[f] = x * 40 + kg * 8;
        int cr = wco * 64 + f * 16 + l15;
        wbase[f] = cr * 40 + kg * 8;
    }

    f32x4_t acc[4][4];
    #pragma unroll
    for (int i = 0; i < 4; i++)
        #pragma unroll
        for (int j = 0; j < 4; j++)
            acc[i][j] = (f32x4_t){0.f, 0.f, 0.f, 0.f};

    auto stage_A = [&](int cb) {
        int cbase = cb * 32;
        for (int q = tid; q < 1560; q += 256) {
            int rg = q / 130;
            int xx = q - rg * 130;
            int r = rg >> 2, g = rg & 3;
            int gy = y0 - 1 + r;
            int gx = xx - 1;
            bool ok = ((unsigned)gy < 128u) && ((unsigned)gx < 128u);
            const unsigned short* src = inb + (size_t)(cbase + g * 8) * HWSZ + (gy * 128 + gx);
            union { unsigned short u[8]; uint4 v; } pk;
            #pragma unroll
            for (int e = 0; e < 8; e++)
                pk.u[e] = ok ? src[(size_t)e * HWSZ] : (unsigned short)0;
            *reinterpret_cast<uint4*>(&Alds[(r * 130 + xx) * 40 + g * 8]) = pk.v;
        }
    };
    auto stage_B = [&](int cbn, int tn, int pn) {
        size_t base = ((size_t)(tn * 8 + cbn) * 256 + co0) * 32;
        #pragma unroll
        for (int h = 0; h < 2; h++) {
            int chunk = tid + h * 256;
            uint4 v = *reinterpret_cast<const uint4*>(wt + base + (size_t)chunk * 8);
            int co = chunk >> 2, g = chunk & 3;
            *reinterpret_cast<uint4*>(&Blds[(pn * 128 + co) * 40 + g * 8]) = v;
        }
    };

    stage_B(0, 0, 0);
    for (int cb = 0; cb < 8; ++cb) {
        if (cb) __syncthreads();
        stage_A(cb);
        #pragma unroll
        for (int t = 0; t < 9; ++t) {
            __syncthreads();
            if (t < 8)            stage_B(cb, t + 1, (cb + t + 1) & 1);
            else if (cb < 7)      stage_B(cb + 1, 0, (cb + 1) & 1);

            const int tapoff = ((t / 3) * 130 + (t % 3)) * 40;
            const int bofs   = ((cb + t) & 1) * (128 * 40);

            bf16x8_t pfr[4], wfr[4];
            #pragma unroll
            for (int f = 0; f < 4; f++)
                pfr[f] = *reinterpret_cast<const bf16x8_t*>(&Alds[pixbase[f] + tapoff]);
            #pragma unroll
            for (int f = 0; f < 4; f++)
                wfr[f] = *reinterpret_cast<const bf16x8_t*>(&Blds[wbase[f] + bofs]);

            #pragma unroll
            for (int cf = 0; cf < 4; cf++)
                #pragma unroll
                for (int pf = 0; pf < 4; pf++)
                    acc[cf][pf] = __builtin_amdgcn_mfma_f32_16x16x32_bf16(
                        wfr[cf], pfr[pf], acc[cf][pf], 0, 0, 0);
        }
    }

    size_t outB = (size_t)b * CC * HWSZ + (size_t)y0 * 128;
    #pragma unroll
    for (int cf = 0; cf < 4; cf++) {
        int cobase = co0 + wco * 64 + cf * 16 + kg * 4;
        #pragma unroll
        for (int j = 0; j < 4; j++) {
            int co = cobase + j;
            float bs = bias[co];
            size_t rowp = outB + (size_t)co * HWSZ;
            #pragma unroll
            for (int pf = 0; pf < 4; pf++) {
                int x = wpx * 64 + pf * 16 + l15;
                float v = silu_f(acc[cf][pf][j] + bs);
                if (ADDB) v += b2f(addb[rowp + x]);
                out[rowp + x] = f2b(v);
            }
        }
    }
}

// ---------------------------------------------------------------------------
// conv 1->256 (input = s * invmax), + bias, silu -> bf16
// ---------------------------------------------------------------------------
__global__ __launch_bounds__(256) void conv_c1a_kernel(const float* __restrict__ s,
                                                       const float* __restrict__ invmax,
                                                       const float* __restrict__ w,
                                                       const float* __restrict__ bias,
                                                       unsigned short* __restrict__ out) {
    int x = blockIdx.x * 32 + threadIdx.x;
    int y = blockIdx.y * 8 + threadIdx.y;
    int co = blockIdx.z & 255;
    int b  = blockIdx.z >> 8;
    float im = invmax[b];
    const float* sb = s + (size_t)b * HWSZ;
    const float* wp = w + (size_t)co * 9;
    float sum = 0.f;
    #pragma unroll
    for (int dy = 0; dy < 3; dy++) {
        int yy = y + dy - 1;
        if ((unsigned)yy >= 128u) continue;
        #pragma unroll
        for (int dx = 0; dx < 3; dx++) {
            int xx = x + dx - 1;
            if ((unsigned)xx >= 128u) continue;
            sum = fmaf(wp[dy * 3 + dx], sb[yy * WW + xx], sum);
        }
    }
    float v = silu_f(sum * im + bias[co]);
    out[(((size_t)b * CC + co) * HWSZ) + y * WW + x] = f2b(v);
}

// ---------------------------------------------------------------------------
// Small conv 256 -> COUT (COUT in {1,4}), bf16 NCHW input, fp32 weights OIHW.
// ---------------------------------------------------------------------------
template <int COUT, int MODE>
__global__ __launch_bounds__(256) void small_conv_kernel(
    const unsigned short* __restrict__ in,
    const float* __restrict__ w,        // [COUT][256][3][3]
    const float* __restrict__ bias,
    float* __restrict__ out)
{
    __shared__ __align__(16) float stripe[16][3][72];
    __shared__ float sacc[4][64][COUT];

    const int tid = threadIdx.x;
    const int p   = tid & 63;
    const int qd  = __builtin_amdgcn_readfirstlane(tid >> 6);
    const int xh  = blockIdx.x & 1;
    const int y   = blockIdx.x >> 1;
    const int b   = blockIdx.y;
    const int x0  = xh * 64;

    const unsigned short* inb = in + (size_t)b * CC * HWSZ;

    float acc[COUT];
    #pragma unroll
    for (int c = 0; c < COUT; c++) acc[c] = 0.f;

    for (int it = 0; it < 16; ++it) {
        __syncthreads();
        for (int q = tid; q < 432; q += 256) {
            int ciq = q / 27;
            int rem = q - ciq * 27;
            int r   = rem / 9;
            int c8  = rem - r * 9;
            int ci  = it * 16 + ciq;
            int gy  = y - 1 + r;
            int gx0 = x0 - 1 + c8 * 8;
            const unsigned short* src = inb + (size_t)ci * HWSZ + gy * 128;
            float v[8];
            #pragma unroll
            for (int e = 0; e < 8; e++) {
                int gx = gx0 + e;
                v[e] = ((unsigned)gy < 128u && (unsigned)gx < 128u) ? b2f(src[gx]) : 0.f;
            }
            float4* dst = (float4*)&stripe[ciq][r][c8 * 8];
            dst[0] = make_float4(v[0], v[1], v[2], v[3]);
            dst[1] = make_float4(v[4], v[5], v[6], v[7]);
        }
        __syncthreads();
        #pragma unroll
        for (int j = 0; j < 4; j++) {
            int ciq = qd * 4 + j;
            int ci  = it * 16 + ciq;
            float i00 = stripe[ciq][0][p], i01 = stripe[ciq][0][p + 1], i02 = stripe[ciq][0][p + 2];
            float i10 = stripe[ciq][1][p], i11 = stripe[ciq][1][p + 1], i12 = stripe[ciq][1][p + 2];
            float i20 = stripe[ciq][2][p], i21 = stripe[ciq][2][p + 1], i22 = stripe[ciq][2][p + 2];
            #pragma unroll
            for (int co = 0; co < COUT; co++) {
                const float* wc = w + ((size_t)co * CC + ci) * 9;
                float a = acc[co];
                a = fmaf(i00, wc[0], a);
                a = fmaf(i01, wc[1], a);
                a = fmaf(i02, wc[2], a);
                a = fmaf(i10, wc[3], a);
                a = fmaf(i11, wc[4], a);
                a = fmaf(i12, wc[5], a);
                a = fmaf(i20, wc[6], a);
                a = fmaf(i21, wc[7], a);
                a = fmaf(i22, wc[8], a);
                acc[co] = a;
            }
        }
    }

    #pragma unroll
    for (int c = 0; c < COUT; c++) sacc[qd][p][c] = acc[c];
    __syncthreads();
    if (tid < 64) {
        float r[COUT];
        #pragma unroll
        for (int c = 0; c < COUT; c++)
            r[c] = sacc[0][tid][c] + sacc[1][tid][c] + sacc[2][tid][c] + sacc[3][tid][c] + bias[c];
        size_t pixidx = (size_t)b * HWSZ + (size_t)y * WW + x0 + tid;
        if (MODE == 0) {
            ((float4*)out)[pixidx] = make_float4(r[0], r[COUT > 1 ? 1 : 0],
                                                 r[COUT > 2 ? 2 : 0], r[COUT > 3 ? 3 : 0]);
        } else if (MODE == 1) {
            out[pixidx] = r[0];
        } else {
            out[pixidx] = sigm_f(r[0]);
        }
    }
}

// ---------------------------------------------------------------------------
// t = xf(fp32,[b,hw]) * xd(bf16) -> bf16
// ---------------------------------------------------------------------------
__global__ __launch_bounds__(256) void mul_kernel(const float* __restrict__ xf,
                                                  const unsigned short* __restrict__ xd,
                                                  unsigned short* __restrict__ out) {
    size_t base = ((size_t)blockIdx.x * 256 + threadIdx.x) * 8;
    int b  = (int)(base >> 22);
    int hw = (int)(base & (HWSZ - 1));
    union { unsigned short u[8]; uint4 v; } d, r;
    d.v = *(const uint4*)(xd + base);
    const float* xfp = xf + (size_t)b * HWSZ + hw;
    float4 f0 = *(const float4*)xfp;
    float4 f1 = *(const float4*)(xfp + 4);
    r.u[0] = f2b(b2f(d.u[0]) * f0.x);
    r.u[1] = f2b(b2f(d.u[1]) * f0.y);
    r.u[2] = f2b(b2f(d.u[2]) * f0.z);
    r.u[3] = f2b(b2f(d.u[3]) * f0.w);
    r.u[4] = f2b(b2f(d.u[4]) * f1.x);
    r.u[5] = f2b(b2f(d.u[5]) * f1.y);
    r.u[6] = f2b(b2f(d.u[6]) * f1.z);
    r.u[7] = f2b(b2f(d.u[7]) * f1.w);
    *(uint4*)(out + base) = r.v;
}

// ---------------------------------------------------------------------------
extern "C" void kernel_launch(void* const* d_in, const int* in_sizes, int n_in,
                              void* d_out, int out_size, void* d_ws, size_t ws_size,
                              hipStream_t stream) {
    const float* emb    = (const float*)d_in[0];
    const float* trk    = (const float*)d_in[1];
    const float* l0     = (const float*)d_in[2];
    const float* l1     = (const float*)d_in[3];
    const float* l2     = (const float*)d_in[4];
    const float* b_p1w  = (const float*)d_in[5];
    const float* b_p1b  = (const float*)d_in[6];
    const float* b_p2w  = (const float*)d_in[7];
    const float* b_p3w  = (const float*)d_in[8];
    const float* b_c1w  = (const float*)d_in[9];
    const float* b_c1b  = (const float*)d_in[10];
    const float* b_c2w  = (const float*)d_in[11];
    const float* b_c2b  = (const float*)d_in[12];
    const float* h_p1w  = (const float*)d_in[13];
    const float* h_p1b  = (const float*)d_in[14];
    const float* h_p2w  = (const float*)d_in[15];
    const float* h_p3w  = (const float*)d_in[16];
    const float* h_c1aw = (const float*)d_in[17];
    const float* h_c1ab = (const float*)d_in[18];
    const float* h_c1bw = (const float*)d_in[19];
    const float* h_c1bb = (const float*)d_in[20];
    const float* h_c2aw = (const float*)d_in[21];
    const float* h_c2ab = (const float*)d_in[22];
    const float* h_c2bw = (const float*)d_in[23];
    const float* h_c2bb = (const float*)d_in[24];
    const float* h_c2cw = (const float*)d_in[25];
    const float* h_c2cb = (const float*)d_in[26];

    float* outp = (float*)d_out;   // [0,32768): hmmap ; [32768,163840): siambox NHWC

    const size_t ACT = (size_t)BB * CC * HWSZ;   // 8,388,608 elems
    const size_t WT  = 9 * 8 * 256 * 32;         // 589,824 elems

    unsigned short* l0bf = (unsigned short*)d_ws;
    unsigned short* wt0  = l0bf + ACT;
    unsigned short* wt1  = wt0 + WT;
    unsigned short* wt2  = wt1 + WT;
    unsigned short* wt3  = wt2 + WT;
    unsigned short* wt4  = wt3 + WT;
    unsigned short* Db   = wt4 + WT;
    unsigned short* X1   = Db + ACT;
    unsigned short* X2   = X1 + ACT;
    float* sbuf   = (float*)(X2 + ACT);
    float* xfb    = sbuf + (size_t)BB * HWSZ;
    float* tn     = xfb + (size_t)BB * HWSZ;
    float* invmax = tn + (size_t)BB * KK * CC;
    int*   idxb   = (int*)(invmax + 2);
    float* ybuf   = (float*)X1;   // alias: y consumed before X1 first written

    dim3 grdConvM(128, 2, 2);
    dim3 grdPerBC(4, 16, BB * CC);
    dim3 grdSmall(256, BB);
    dim3 blk2d(32, 8);

    // ---- preps ----
    cvtbf_kernel<<<(unsigned)(ACT / 8 / 256), 256, 0, stream>>>(l0, l0bf);
    wprep_kernel<<<(unsigned)(WT / 256), 256, 0, stream>>>(b_p1w, wt0);
    wprep_kernel<<<(unsigned)(WT / 256), 256, 0, stream>>>(b_c1w, wt1);
    wprep_kernel<<<(unsigned)(WT / 256), 256, 0, stream>>>(h_p1w, wt2);
    wprep_kernel<<<(unsigned)(WT / 256), 256, 0, stream>>>(h_c2aw, wt3);
    wprep_kernel<<<(unsigned)(WT / 256), 256, 0, stream>>>(h_c2bw, wt4);

    // ---- correlation map ----
    tnorm_kernel<<<1, 128, 0, stream>>>(trk, tn);
    ycorr_kernel<<<dim3(512, BB), 256, 0, stream>>>(emb, tn, ybuf);
    argmax_kernel<<<BB * KK, 256, 0, stream>>>(ybuf, idxb);
    smap_kernel<<<dim3(64, BB), 256, 0, stream>>>(ybuf, idxb, sbuf);
    smax_kernel<<<BB, 256, 0, stream>>>(sbuf, invmax);

    // ---- box head ----
    deconv_kernel<<<BB * CC, 256, 0, stream>>>(l1, l2, b_p2w, b_p3w, Db);
    conv_mfma_kernel<1><<<grdConvM, 256, 0, stream>>>(l0bf, wt0, b_p1b, Db, X1);     // xd_box
    conv_mfma_kernel<0><<<grdConvM, 256, 0, stream>>>(X1, wt1, b_c1b, nullptr, X2);  // xb
    small_conv_kernel<4, 0><<<grdSmall, 256, 0, stream>>>(X2, b_c2w, b_c2b, outp + BB * HWSZ);

    // ---- heatmap head ----
    deconv_kernel<<<BB * CC, 256, 0, stream>>>(l1, l2, h_p2w, h_p3w, Db);
    conv_mfma_kernel<1><<<grdConvM, 256, 0, stream>>>(l0bf, wt2, h_p1b, Db, X1);     // xd_hm
    conv_c1a_kernel<<<grdPerBC, blk2d, 0, stream>>>(sbuf, invmax, h_c1aw, h_c1ab, X2);   // t1 (bf16)
    small_conv_kernel<1, 1><<<grdSmall, 256, 0, stream>>>(X2, h_c1bw, h_c1bb, xfb);  // xf
    mul_kernel<<<4096, 256, 0, stream>>>(xfb, X1, X2);                               // t
    conv_mfma_kernel<0><<<grdConvM, 256, 0, stream>>>(X2, wt3, h_c2ab, nullptr, Db); // t2
    conv_mfma_kernel<0><<<grdConvM, 256, 0, stream>>>(Db, wt4, h_c2bb, nullptr, X1); // t3
    small_conv_kernel<1, 2><<<grdSmall, 256, 0, stream>>>(X1, h_c2cw, h_c2cb, outp); // hmmap
}

// Round 6
// 694.545 us; speedup vs baseline: 10.1878x; 1.0770x over previous
//
#include <hip/hip_runtime.h>
#include <math.h>

#define HH 128
#define WW 128
#define HWSZ 16384   // 128*128
#define CC 256
#define KK 64
#define BB 2

typedef __bf16 bf16x8_t __attribute__((ext_vector_type(8)));
typedef float  f32x4_t  __attribute__((ext_vector_type(4)));

__device__ __forceinline__ float silu_f(float v) { return v / (1.f + expf(-v)); }
__device__ __forceinline__ float sigm_f(float v) { return 1.f / (1.f + expf(-v)); }

__device__ __forceinline__ float b2f(unsigned short u) {
    union { unsigned int i; float f; } x; x.i = ((unsigned int)u) << 16; return x.f;
}
__device__ __forceinline__ unsigned short f2b(float f) {
    union { float f; unsigned int i; } x; x.f = f;
    unsigned int r = x.i + 0x7FFFu + ((x.i >> 16) & 1u);
    return (unsigned short)(r >> 16);
}

// ---------------------------------------------------------------------------
// prep: fp32 -> bf16 copy (8 elems/thread)
// ---------------------------------------------------------------------------
__global__ __launch_bounds__(256) void cvtbf_kernel(const float* __restrict__ in,
                                                    unsigned short* __restrict__ out) {
    size_t i = ((size_t)blockIdx.x * 256 + threadIdx.x) * 8;
    float4 a = *(const float4*)(in + i);
    float4 b = *(const float4*)(in + i + 4);
    union { unsigned short u[8]; uint4 v; } pk;
    pk.u[0] = f2b(a.x); pk.u[1] = f2b(a.y); pk.u[2] = f2b(a.z); pk.u[3] = f2b(a.w);
    pk.u[4] = f2b(b.x); pk.u[5] = f2b(b.y); pk.u[6] = f2b(b.z); pk.u[7] = f2b(b.w);
    *(uint4*)(out + i) = pk.v;
}

// ---------------------------------------------------------------------------
// prep: weights OIHW fp32 [256co][256ci][3][3] -> bf16 [8cb][9t][4g][256co][8e]
// wt[(((cb*9+t)*4+g)*256+co)*8+e] = w[(co*256 + cb*32 + g*8 + e)*9 + t]
// ---------------------------------------------------------------------------
__global__ __launch_bounds__(256) void wprep_kernel(const float* __restrict__ w,
                                                    unsigned short* __restrict__ wt) {
    int idx = blockIdx.x * 256 + threadIdx.x;       // 0 .. 589823
    int e   = idx & 7;
    int co  = (idx >> 3) & 255;
    int g   = (idx >> 11) & 3;
    int v   = idx >> 13;                            // 0..71 = cb*9 + t
    int cb  = v / 9;
    int t   = v - cb * 9;
    wt[idx] = f2b(w[((size_t)co * 256 + cb * 32 + g * 8 + e) * 9 + t]);
}

// ---------------------------------------------------------------------------
// tracklet normalize
// ---------------------------------------------------------------------------
__global__ __launch_bounds__(128) void tnorm_kernel(const float* __restrict__ trk,
                                                    float* __restrict__ tn) {
    int r = threadIdx.x;
    if (r >= BB * KK) return;
    const float* p = trk + (size_t)r * CC;
    float ss = 0.f;
    for (int c = 0; c < CC; c++) { float v = p[c]; ss += v * v; }
    float sc = 1.f / fmaxf(sqrtf(ss), 1e-12f);
    float* q = tn + (size_t)r * CC;
    for (int c = 0; c < CC; c++) q[c] = p[c] * sc;
}

// ---------------------------------------------------------------------------
// ycorr: y[b,k,hw] = s_e[hw] * relu(dot(e_raw[hw], tn[k]))
// ---------------------------------------------------------------------------
#define EPAD 260
__global__ __launch_bounds__(256) void ycorr_kernel(const float* __restrict__ emb,
                                                    const float* __restrict__ tn,
                                                    float* __restrict__ y) {
    __shared__ __align__(16) float E[32 * EPAD];
    __shared__ __align__(16) float T[64 * EPAD];
    __shared__ float SE[32];

    const int tid = threadIdx.x;
    const int b   = blockIdx.y;
    const int hw0 = blockIdx.x * 32;

    const float4* esrc = (const float4*)(emb + ((size_t)b * HWSZ + hw0) * CC);
    #pragma unroll
    for (int i = 0; i < 8; i++) {
        int q  = tid + i * 256;
        int px = q >> 6, c4 = q & 63;
        *(float4*)&E[px * EPAD + c4 * 4] = esrc[(size_t)px * 64 + c4];
    }
    const float4* tsrc = (const float4*)(tn + (size_t)b * KK * CC);
    #pragma unroll
    for (int i = 0; i < 16; i++) {
        int q = tid + i * 256;
        int k = q >> 6, c4 = q & 63;
        *(float4*)&T[k * EPAD + c4 * 4] = tsrc[(size_t)k * 64 + c4];
    }
    __syncthreads();

    if (tid < 32) {
        float ss = 0.f;
        const float4* ep = (const float4*)&E[tid * EPAD];
        #pragma unroll 8
        for (int c4 = 0; c4 < 64; c4++) {
            float4 v = ep[c4];
            ss += v.x * v.x + v.y * v.y + v.z * v.z + v.w * v.w;
        }
        SE[tid] = 1.f / fmaxf(sqrtf(ss), 1e-12f);
    }
    __syncthreads();

    const int pg = tid & 15;
    const int kg = tid >> 4;

    float acc[2][4];
    #pragma unroll
    for (int j = 0; j < 2; j++)
        #pragma unroll
        for (int kk = 0; kk < 4; kk++) acc[j][kk] = 0.f;

    const float* E0 = &E[(0 * 16 + pg) * EPAD];
    const float* E1 = &E[(1 * 16 + pg) * EPAD];
    const float* T0 = &T[(0 * 16 + kg) * EPAD];
    const float* T1 = &T[(1 * 16 + kg) * EPAD];
    const float* T2 = &T[(2 * 16 + kg) * EPAD];
    const float* T3 = &T[(3 * 16 + kg) * EPAD];

    #pragma unroll 4
    for (int c4 = 0; c4 < 64; ++c4) {
        float4 e0 = *(const float4*)(E0 + c4 * 4);
        float4 e1 = *(const float4*)(E1 + c4 * 4);
        float4 t0 = *(const float4*)(T0 + c4 * 4);
        float4 t1 = *(const float4*)(T1 + c4 * 4);
        float4 t2 = *(const float4*)(T2 + c4 * 4);
        float4 t3 = *(const float4*)(T3 + c4 * 4);
        #define DOT4(a, t) (fmaf(a.w, t.w, fmaf(a.z, t.z, fmaf(a.y, t.y, a.x * t.x))))
        acc[0][0] += DOT4(e0, t0); acc[0][1] += DOT4(e0, t1);
        acc[0][2] += DOT4(e0, t2); acc[0][3] += DOT4(e0, t3);
        acc[1][0] += DOT4(e1, t0); acc[1][1] += DOT4(e1, t1);
        acc[1][2] += DOT4(e1, t2); acc[1][3] += DOT4(e1, t3);
        #undef DOT4
    }

    #pragma unroll
    for (int j = 0; j < 2; j++) {
        int px = j * 16 + pg;
        float se = SE[px];
        #pragma unroll
        for (int kk = 0; kk < 4; kk++) {
            int k = kk * 16 + kg;
            y[((size_t)b * KK + k) * HWSZ + hw0 + px] = fmaxf(acc[j][kk], 0.f) * se;
        }
    }
}

// ---------------------------------------------------------------------------
// first-occurrence argmax per (b,k)
// ---------------------------------------------------------------------------
__global__ __launch_bounds__(256) void argmax_kernel(const float* __restrict__ y,
                                                     int* __restrict__ idxout) {
    int bk = blockIdx.x;
    const float* p = y + (size_t)bk * HWSZ;
    int t = threadIdx.x;
    float best = -1.f; int bi = 1 << 30;
    for (int i = t; i < HWSZ; i += 256) {
        float v = p[i];
        if (v > best) { best = v; bi = i; }
    }
    __shared__ float sv[256];
    __shared__ int   si[256];
    sv[t] = best; si[t] = bi;
    __syncthreads();
    for (int s = 128; s > 0; s >>= 1) {
        if (t < s) {
            float v2 = sv[t + s]; int i2 = si[t + s];
            if (v2 > sv[t] || (v2 == sv[t] && i2 < si[t])) { sv[t] = v2; si[t] = i2; }
        }
        __syncthreads();
    }
    if (t == 0) idxout[bk] = si[0];
}

// ---------------------------------------------------------------------------
// s[b,hw] = sum_k y * mask
// ---------------------------------------------------------------------------
__global__ __launch_bounds__(256) void smap_kernel(const float* __restrict__ y,
                                                   const int* __restrict__ idx,
                                                   float* __restrict__ s) {
    int b  = blockIdx.y;
    int hw = blockIdx.x * 256 + threadIdx.x;
    int h  = hw >> 7, w = hw & 127;
    __shared__ int ai[KK], aj[KK];
    if (threadIdx.x < KK) {
        int v = idx[b * KK + threadIdx.x];
        ai[threadIdx.x] = v >> 7;
        aj[threadIdx.x] = v & 127;
    }
    __syncthreads();
    const float* yb = y + (size_t)b * KK * HWSZ;
    float acc = 0.f;
    #pragma unroll 8
    for (int k = 0; k < KK; k++) {
        float v = yb[(size_t)k * HWSZ + hw];
        bool in = (h >= ai[k] - 8) && (h < ai[k] + 8) && (w >= aj[k] - 8) && (w < aj[k] + 8);
        acc += in ? v : 0.f;
    }
    s[(size_t)b * HWSZ + hw] = acc;
}

__global__ __launch_bounds__(256) void smax_kernel(const float* __restrict__ s,
                                                   float* __restrict__ invmax) {
    int b = blockIdx.x;
    const float* p = s + (size_t)b * HWSZ;
    float m = -1e30f;
    for (int i = threadIdx.x; i < HWSZ; i += 256) m = fmaxf(m, p[i]);
    __shared__ float sm[256];
    sm[threadIdx.x] = m;
    __syncthreads();
    for (int st = 128; st > 0; st >>= 1) {
        if (threadIdx.x < st) sm[threadIdx.x] = fmaxf(sm[threadIdx.x], sm[threadIdx.x + st]);
        __syncthreads();
    }
    if (threadIdx.x == 0) invmax[b] = 1.f / sm[0];
}

// ---------------------------------------------------------------------------
// grouped deconvs, LDS-resident: one block per (b,g).
// ---------------------------------------------------------------------------
__global__ __launch_bounds__(256) void deconv_kernel(const float* __restrict__ l1,
                                                     const float* __restrict__ l2,
                                                     const float* __restrict__ w2,
                                                     const float* __restrict__ w3,
                                                     unsigned short* __restrict__ out) {
    __shared__ float L1[2][64][64];
    __shared__ float L2[4][32][32];

    const int tid = threadIdx.x;
    const int g   = blockIdx.x & 255;
    const int b   = blockIdx.x >> 8;

    const float4* l1b = (const float4*)(l1 + ((size_t)b * 2 * CC + 2 * g) * 4096);
    float4* L1p = (float4*)&L1[0][0][0];
    #pragma unroll
    for (int i = 0; i < 8; i++) L1p[tid + i * 256] = l1b[tid + i * 256];
    const float4* l2b = (const float4*)(l2 + ((size_t)b * 4 * CC + 4 * g) * 1024);
    float4* L2p = (float4*)&L2[0][0][0];
    #pragma unroll
    for (int i = 0; i < 4; i++) L2p[tid + i * 256] = l2b[tid + i * 256];

    const int x    = tid & 127;
    const int ytop = tid >> 7;
    const float* w2g = w2 + (size_t)g * 32;
    const float* w3g = w3 + (size_t)g * 256;

    const int pxo = x & 1, pyo = ytop & 1;
    const int mx0 = (x + pxo - 2) >> 1;
    const int dy2 = (ytop + pyo - 2) >> 1;
    const bool nok0 = (unsigned)mx0 < 64u;
    const bool nok1 = (unsigned)(mx0 + 1) < 64u;
    const int nc0 = mx0 & 63, nc1 = (mx0 + 1) & 63;
    float W2[2][2][2];
    #pragma unroll
    for (int ci = 0; ci < 2; ci++)
        #pragma unroll
        for (int a = 0; a < 2; a++)
            #pragma unroll
            for (int c = 0; c < 2; c++)
                W2[ci][a][c] = w2g[ci * 16 + (pyo + 2 * a) * 4 + (pxo + 2 * c)];

    const int px3 = (5 - (x & 3)) & 3;
    const int n30 = (x + px3 - 5) >> 2;
    const bool n3ok0 = (unsigned)n30 < 32u;
    const bool n3ok1 = (unsigned)(n30 + 1) < 32u;
    const int n3c0 = n30 & 31, n3c1 = (n30 + 1) & 31;
    int dy3[2];
    float W3[2][4][2][2];
    #pragma unroll
    for (int ph = 0; ph < 2; ph++) {
        int py3 = (5 - ((ytop + 2 * ph) & 3)) & 3;
        dy3[ph] = (2 * ph + ytop + py3 - 5) >> 2;
        #pragma unroll
        for (int ci = 0; ci < 4; ci++)
            #pragma unroll
            for (int a = 0; a < 2; a++)
                #pragma unroll
                for (int c = 0; c < 2; c++)
                    W3[ph][ci][a][c] = w3g[ci * 64 + (py3 + 4 * a) * 8 + (px3 + 4 * c)];
    }

    __syncthreads();

    unsigned short* outb = out + ((size_t)b * CC + g) * HWSZ;

    #pragma unroll 2
    for (int ii = 0; ii < 32; ++ii) {
        #pragma unroll
        for (int ph = 0; ph < 2; ph++) {
            const int i = 2 * ii + ph;
            float acc = 0.f;
            {
                const int m0 = i + dy2;
                #pragma unroll
                for (int a = 0; a < 2; a++) {
                    int m = m0 + a;
                    bool mok = (unsigned)m < 64u;
                    int mc = m & 63;
                    #pragma unroll
                    for (int ci = 0; ci < 2; ci++) {
                        float v0 = (mok && nok0) ? L1[ci][mc][nc0] : 0.f;
                        float v1 = (mok && nok1) ? L1[ci][mc][nc1] : 0.f;
                        acc = fmaf(W2[ci][a][0], v0, acc);
                        acc = fmaf(W2[ci][a][1], v1, acc);
                    }
                }
            }
            {
                const int m0 = ii + dy3[ph];
                #pragma unroll
                for (int a = 0; a < 2; a++) {
                    int m = m0 + a;
                    bool mok = (unsigned)m < 32u;
                    int mc = m & 31;
                    #pragma unroll
                    for (int ci = 0; ci < 4; ci++) {
                        float v0 = (mok && n3ok0) ? L2[ci][mc][n3c0] : 0.f;
                        float v1 = (mok && n3ok1) ? L2[ci][mc][n3c1] : 0.f;
                        acc = fmaf(W3[ph][ci][a][0], v0, acc);
                        acc = fmaf(W3[ph][ci][a][1], v1, acc);
                    }
                }
            }
            outb[(size_t)i * 256 + tid] = f2b(acc);
        }
    }
}

// ---------------------------------------------------------------------------
// BIG conv 256->256 3x3, bf16 MFMA implicit GEMM.
// Block: 1 row (128 px) x 128 co, 4 waves (64co x 64px each).
// A: single buffer [3][130][40] shorts (pad 40 -> 2-way-free reads).
// B: double buffer, group = 3 taps (one ky): [2][3tl][4g][128co][8e] shorts,
//    linear-write staging (0 conflicts), 16B-stride reads (2-way free).
// Schedule: per group {barrier; [stage_A]; stage_B(next); [barrier]; 48 MFMA}.
// 32 barriers/kernel vs 81 before.
// ---------------------------------------------------------------------------
template <int ADDB>
__global__ __launch_bounds__(256, 2) void conv_mfma_kernel(
    const unsigned short* __restrict__ in,    // bf16 NCHW
    const unsigned short* __restrict__ wt,    // bf16 [8cb][9t][4g][256co][8e]
    const float* __restrict__ bias,
    const unsigned short* __restrict__ addb,  // bf16 NCHW (ADDB=1)
    unsigned short* __restrict__ out)
{
    __shared__ __align__(16) unsigned short Alds[3 * 130 * 40];      // 31200 B
    __shared__ __align__(16) unsigned short Blds[2 * 3 * 4 * 128 * 8]; // 49152 B

    const int tid  = threadIdx.x;
    const int lane = tid & 63;
    const int wv   = tid >> 6;
    const int wco  = wv >> 1;
    const int wpx  = wv & 1;
    const int l15  = lane & 15;
    const int kg   = lane >> 4;

    const int y0  = blockIdx.x;
    const int co0 = blockIdx.y * 128;
    const int b   = blockIdx.z;

    const unsigned short* inb = in + (size_t)b * CC * HWSZ;

    int pixbase[4], wbase[4];
    #pragma unroll
    for (int f = 0; f < 4; f++) {
        int x = wpx * 64 + f * 16 + l15;
        pixbase[f] = x * 40 + kg * 8;
        int crl = wco * 64 + f * 16 + l15;          // co within block (0..127)
        wbase[f] = (kg * 128 + crl) * 8;
    }

    f32x4_t acc[4][4];
    #pragma unroll
    for (int i = 0; i < 4; i++)
        #pragma unroll
        for (int j = 0; j < 4; j++)
            acc[i][j] = (f32x4_t){0.f, 0.f, 0.f, 0.f};

    auto stage_A = [&](int cb) {
        int cbase = cb * 32;
        for (int q = tid; q < 1560; q += 256) {
            int rg = q / 130;
            int xx = q - rg * 130;
            int r = rg >> 2, g = rg & 3;
            int gy = y0 - 1 + r;
            int gx = xx - 1;
            bool ok = ((unsigned)gy < 128u) && ((unsigned)gx < 128u);
            const unsigned short* src = inb + (size_t)(cbase + g * 8) * HWSZ + (gy * 128 + gx);
            union { unsigned short u[8]; uint4 v; } pk;
            #pragma unroll
            for (int e = 0; e < 8; e++)
                pk.u[e] = ok ? src[(size_t)e * HWSZ] : (unsigned short)0;
            *reinterpret_cast<uint4*>(&Alds[(r * 130 + xx) * 40 + g * 8]) = pk.v;
        }
    };
    // stage one 3-tap group: (cb, ky) -> buffer par
    auto stage_B = [&](int cb_, int ky_, int par_) {
        #pragma unroll
        for (int i = 0; i < 6; i++) {
            int c    = tid + i * 256;                 // 0..1535 chunks of 16B
            int tl   = c >> 9;                        // 0..2
            int rest = c & 511;                       // g*128 + co_l
            size_t src = (((size_t)((cb_ * 9 + ky_ * 3 + tl) * 4) + (rest >> 7)) * 256
                          + co0 + (rest & 127)) * 8;
            *reinterpret_cast<uint4*>(&Blds[par_ * 12288 + c * 8]) =
                *reinterpret_cast<const uint4*>(wt + src);
        }
    };

    stage_B(0, 0, 0);
    for (int cb = 0; cb < 8; ++cb) {
        #pragma unroll
        for (int ky = 0; ky < 3; ++ky) {
            const int par = (cb + ky) & 1;            // (cb*3+ky)&1
            __syncthreads();                          // prev compute done
            if (ky == 0) stage_A(cb);
            if (!(cb == 7 && ky == 2)) {
                int cbn = (ky == 2) ? cb + 1 : cb;
                int kyn = (ky == 2) ? 0 : ky + 1;
                stage_B(cbn, kyn, par ^ 1);
            }
            if (ky == 0) __syncthreads();             // A ready

            #pragma unroll
            for (int tl = 0; tl < 3; ++tl) {
                const int aoff = (ky * 130 + tl) * 40;
                const int boff = par * 12288 + tl * 4096;
                bf16x8_t pfr[4], wfr[4];
                #pragma unroll
                for (int f = 0; f < 4; f++)
                    pfr[f] = *reinterpret_cast<const bf16x8_t*>(&Alds[pixbase[f] + aoff]);
                #pragma unroll
                for (int f = 0; f < 4; f++)
                    wfr[f] = *reinterpret_cast<const bf16x8_t*>(&Blds[boff + wbase[f]]);
                #pragma unroll
                for (int cf = 0; cf < 4; cf++)
                    #pragma unroll
                    for (int pf = 0; pf < 4; pf++)
                        acc[cf][pf] = __builtin_amdgcn_mfma_f32_16x16x32_bf16(
                            wfr[cf], pfr[pf], acc[cf][pf], 0, 0, 0);
            }
        }
    }

    size_t outB = (size_t)b * CC * HWSZ + (size_t)y0 * 128;
    #pragma unroll
    for (int cf = 0; cf < 4; cf++) {
        int cobase = co0 + wco * 64 + cf * 16 + kg * 4;
        #pragma unroll
        for (int j = 0; j < 4; j++) {
            int co = cobase + j;
            float bs = bias[co];
            size_t rowp = outB + (size_t)co * HWSZ;
            #pragma unroll
            for (int pf = 0; pf < 4; pf++) {
                int x = wpx * 64 + pf * 16 + l15;
                float v = silu_f(acc[cf][pf][j] + bs);
                if (ADDB) v += b2f(addb[rowp + x]);
                out[rowp + x] = f2b(v);
            }
        }
    }
}

// ---------------------------------------------------------------------------
// conv 1->256 (input = s * invmax), + bias, silu -> bf16
// ---------------------------------------------------------------------------
__global__ __launch_bounds__(256) void conv_c1a_kernel(const float* __restrict__ s,
                                                       const float* __restrict__ invmax,
                                                       const float* __restrict__ w,
                                                       const float* __restrict__ bias,
                                                       unsigned short* __restrict__ out) {
    int x = blockIdx.x * 32 + threadIdx.x;
    int y = blockIdx.y * 8 + threadIdx.y;
    int co = blockIdx.z & 255;
    int b  = blockIdx.z >> 8;
    float im = invmax[b];
    const float* sb = s + (size_t)b * HWSZ;
    const float* wp = w + (size_t)co * 9;
    float sum = 0.f;
    #pragma unroll
    for (int dy = 0; dy < 3; dy++) {
        int yy = y + dy - 1;
        if ((unsigned)yy >= 128u) continue;
        #pragma unroll
        for (int dx = 0; dx < 3; dx++) {
            int xx = x + dx - 1;
            if ((unsigned)xx >= 128u) continue;
            sum = fmaf(wp[dy * 3 + dx], sb[yy * WW + xx], sum);
        }
    }
    float v = silu_f(sum * im + bias[co]);
    out[(((size_t)b * CC + co) * HWSZ) + y * WW + x] = f2b(v);
}

// ---------------------------------------------------------------------------
// Small conv 256 -> COUT (COUT in {1,4}), bf16 NCHW input, fp32 weights OIHW.
// ---------------------------------------------------------------------------
template <int COUT, int MODE>
__global__ __launch_bounds__(256) void small_conv_kernel(
    const unsigned short* __restrict__ in,
    const float* __restrict__ w,        // [COUT][256][3][3]
    const float* __restrict__ bias,
    float* __restrict__ out)
{
    __shared__ __align__(16) float stripe[16][3][72];
    __shared__ float sacc[4][64][COUT];

    const int tid = threadIdx.x;
    const int p   = tid & 63;
    const int qd  = __builtin_amdgcn_readfirstlane(tid >> 6);
    const int xh  = blockIdx.x & 1;
    const int y   = blockIdx.x >> 1;
    const int b   = blockIdx.y;
    const int x0  = xh * 64;

    const unsigned short* inb = in + (size_t)b * CC * HWSZ;

    float acc[COUT];
    #pragma unroll
    for (int c = 0; c < COUT; c++) acc[c] = 0.f;

    for (int it = 0; it < 16; ++it) {
        __syncthreads();
        for (int q = tid; q < 432; q += 256) {
            int ciq = q / 27;
            int rem = q - ciq * 27;
            int r   = rem / 9;
            int c8  = rem - r * 9;
            int ci  = it * 16 + ciq;
            int gy  = y - 1 + r;
            int gx0 = x0 - 1 + c8 * 8;
            const unsigned short* src = inb + (size_t)ci * HWSZ + gy * 128;
            float v[8];
            #pragma unroll
            for (int e = 0; e < 8; e++) {
                int gx = gx0 + e;
                v[e] = ((unsigned)gy < 128u && (unsigned)gx < 128u) ? b2f(src[gx]) : 0.f;
            }
            float4* dst = (float4*)&stripe[ciq][r][c8 * 8];
            dst[0] = make_float4(v[0], v[1], v[2], v[3]);
            dst[1] = make_float4(v[4], v[5], v[6], v[7]);
        }
        __syncthreads();
        #pragma unroll
        for (int j = 0; j < 4; j++) {
            int ciq = qd * 4 + j;
            int ci  = it * 16 + ciq;
            float i00 = stripe[ciq][0][p], i01 = stripe[ciq][0][p + 1], i02 = stripe[ciq][0][p + 2];
            float i10 = stripe[ciq][1][p], i11 = stripe[ciq][1][p + 1], i12 = stripe[ciq][1][p + 2];
            float i20 = stripe[ciq][2][p], i21 = stripe[ciq][2][p + 1], i22 = stripe[ciq][2][p + 2];
            #pragma unroll
            for (int co = 0; co < COUT; co++) {
                const float* wc = w + ((size_t)co * CC + ci) * 9;
                float a = acc[co];
                a = fmaf(i00, wc[0], a);
                a = fmaf(i01, wc[1], a);
                a = fmaf(i02, wc[2], a);
                a = fmaf(i10, wc[3], a);
                a = fmaf(i11, wc[4], a);
                a = fmaf(i12, wc[5], a);
                a = fmaf(i20, wc[6], a);
                a = fmaf(i21, wc[7], a);
                a = fmaf(i22, wc[8], a);
                acc[co] = a;
            }
        }
    }

    #pragma unroll
    for (int c = 0; c < COUT; c++) sacc[qd][p][c] = acc[c];
    __syncthreads();
    if (tid < 64) {
        float r[COUT];
        #pragma unroll
        for (int c = 0; c < COUT; c++)
            r[c] = sacc[0][tid][c] + sacc[1][tid][c] + sacc[2][tid][c] + sacc[3][tid][c] + bias[c];
        size_t pixidx = (size_t)b * HWSZ + (size_t)y * WW + x0 + tid;
        if (MODE == 0) {
            ((float4*)out)[pixidx] = make_float4(r[0], r[COUT > 1 ? 1 : 0],
                                                 r[COUT > 2 ? 2 : 0], r[COUT > 3 ? 3 : 0]);
        } else if (MODE == 1) {
            out[pixidx] = r[0];
        } else {
            out[pixidx] = sigm_f(r[0]);
        }
    }
}

// ---------------------------------------------------------------------------
// t = xf(fp32,[b,hw]) * xd(bf16) -> bf16
// ---------------------------------------------------------------------------
__global__ __launch_bounds__(256) void mul_kernel(const float* __restrict__ xf,
                                                  const unsigned short* __restrict__ xd,
                                                  unsigned short* __restrict__ out) {
    size_t base = ((size_t)blockIdx.x * 256 + threadIdx.x) * 8;
    int b  = (int)(base >> 22);
    int hw = (int)(base & (HWSZ - 1));
    union { unsigned short u[8]; uint4 v; } d, r;
    d.v = *(const uint4*)(xd + base);
    const float* xfp = xf + (size_t)b * HWSZ + hw;
    float4 f0 = *(const float4*)xfp;
    float4 f1 = *(const float4*)(xfp + 4);
    r.u[0] = f2b(b2f(d.u[0]) * f0.x);
    r.u[1] = f2b(b2f(d.u[1]) * f0.y);
    r.u[2] = f2b(b2f(d.u[2]) * f0.z);
    r.u[3] = f2b(b2f(d.u[3]) * f0.w);
    r.u[4] = f2b(b2f(d.u[4]) * f1.x);
    r.u[5] = f2b(b2f(d.u[5]) * f1.y);
    r.u[6] = f2b(b2f(d.u[6]) * f1.z);
    r.u[7] = f2b(b2f(d.u[7]) * f1.w);
    *(uint4*)(out + base) = r.v;
}

// ---------------------------------------------------------------------------
extern "C" void kernel_launch(void* const* d_in, const int* in_sizes, int n_in,
                              void* d_out, int out_size, void* d_ws, size_t ws_size,
                              hipStream_t stream) {
    const float* emb    = (const float*)d_in[0];
    const float* trk    = (const float*)d_in[1];
    const float* l0     = (const float*)d_in[2];
    const float* l1     = (const float*)d_in[3];
    const float* l2     = (const float*)d_in[4];
    const float* b_p1w  = (const float*)d_in[5];
    const float* b_p1b  = (const float*)d_in[6];
    const float* b_p2w  = (const float*)d_in[7];
    const float* b_p3w  = (const float*)d_in[8];
    const float* b_c1w  = (const float*)d_in[9];
    const float* b_c1b  = (const float*)d_in[10];
    const float* b_c2w  = (const float*)d_in[11];
    const float* b_c2b  = (const float*)d_in[12];
    const float* h_p1w  = (const float*)d_in[13];
    const float* h_p1b  = (const float*)d_in[14];
    const float* h_p2w  = (const float*)d_in[15];
    const float* h_p3w  = (const float*)d_in[16];
    const float* h_c1aw = (const float*)d_in[17];
    const float* h_c1ab = (const float*)d_in[18];
    const float* h_c1bw = (const float*)d_in[19];
    const float* h_c1bb = (const float*)d_in[20];
    const float* h_c2aw = (const float*)d_in[21];
    const float* h_c2ab = (const float*)d_in[22];
    const float* h_c2bw = (const float*)d_in[23];
    const float* h_c2bb = (const float*)d_in[24];
    const float* h_c2cw = (const float*)d_in[25];
    const float* h_c2cb = (const float*)d_in[26];

    float* outp = (float*)d_out;   // [0,32768): hmmap ; [32768,163840): siambox NHWC

    const size_t ACT = (size_t)BB * CC * HWSZ;   // 8,388,608 elems
    const size_t WT  = 9 * 8 * 256 * 32;         // 589,824 elems

    unsigned short* l0bf = (unsigned short*)d_ws;
    unsigned short* wt0  = l0bf + ACT;
    unsigned short* wt1  = wt0 + WT;
    unsigned short* wt2  = wt1 + WT;
    unsigned short* wt3  = wt2 + WT;
    unsigned short* wt4  = wt3 + WT;
    unsigned short* Db   = wt4 + WT;
    unsigned short* X1   = Db + ACT;
    unsigned short* X2   = X1 + ACT;
    float* sbuf   = (float*)(X2 + ACT);
    float* xfb    = sbuf + (size_t)BB * HWSZ;
    float* tn     = xfb + (size_t)BB * HWSZ;
    float* invmax = tn + (size_t)BB * KK * CC;
    int*   idxb   = (int*)(invmax + 2);
    float* ybuf   = (float*)X1;   // alias: y consumed before X1 first written

    dim3 grdConvM(128, 2, 2);
    dim3 grdPerBC(4, 16, BB * CC);
    dim3 grdSmall(256, BB);
    dim3 blk2d(32, 8);

    // ---- preps ----
    cvtbf_kernel<<<(unsigned)(ACT / 8 / 256), 256, 0, stream>>>(l0, l0bf);
    wprep_kernel<<<(unsigned)(WT / 256), 256, 0, stream>>>(b_p1w, wt0);
    wprep_kernel<<<(unsigned)(WT / 256), 256, 0, stream>>>(b_c1w, wt1);
    wprep_kernel<<<(unsigned)(WT / 256), 256, 0, stream>>>(h_p1w, wt2);
    wprep_kernel<<<(unsigned)(WT / 256), 256, 0, stream>>>(h_c2aw, wt3);
    wprep_kernel<<<(unsigned)(WT / 256), 256, 0, stream>>>(h_c2bw, wt4);

    // ---- correlation map ----
    tnorm_kernel<<<1, 128, 0, stream>>>(trk, tn);
    ycorr_kernel<<<dim3(512, BB), 256, 0, stream>>>(emb, tn, ybuf);
    argmax_kernel<<<BB * KK, 256, 0, stream>>>(ybuf, idxb);
    smap_kernel<<<dim3(64, BB), 256, 0, stream>>>(ybuf, idxb, sbuf);
    smax_kernel<<<BB, 256, 0, stream>>>(sbuf, invmax);

    // ---- box head ----
    deconv_kernel<<<BB * CC, 256, 0, stream>>>(l1, l2, b_p2w, b_p3w, Db);
    conv_mfma_kernel<1><<<grdConvM, 256, 0, stream>>>(l0bf, wt0, b_p1b, Db, X1);     // xd_box
    conv_mfma_kernel<0><<<grdConvM, 256, 0, stream>>>(X1, wt1, b_c1b, nullptr, X2);  // xb
    small_conv_kernel<4, 0><<<grdSmall, 256, 0, stream>>>(X2, b_c2w, b_c2b, outp + BB * HWSZ);

    // ---- heatmap head ----
    deconv_kernel<<<BB * CC, 256, 0, stream>>>(l1, l2, h_p2w, h_p3w, Db);
    conv_mfma_kernel<1><<<grdConvM, 256, 0, stream>>>(l0bf, wt2, h_p1b, Db, X1);     // xd_hm
    conv_c1a_kernel<<<grdPerBC, blk2d, 0, stream>>>(sbuf, invmax, h_c1aw, h_c1ab, X2);   // t1 (bf16)
    small_conv_kernel<1, 1><<<grdSmall, 256, 0, stream>>>(X2, h_c1bw, h_c1bb, xfb);  // xf
    mul_kernel<<<4096, 256, 0, stream>>>(xfb, X1, X2);                               // t
    conv_mfma_kernel<0><<<grdConvM, 256, 0, stream>>>(X2, wt3, h_c2ab, nullptr, Db); // t2
    conv_mfma_kernel<0><<<grdConvM, 256, 0, stream>>>(Db, wt4, h_c2bb, nullptr, X1); // t3
    small_conv_kernel<1, 2><<<grdSmall, 256, 0, stream>>>(X1, h_c2cw, h_c2cb, outp); // hmmap
}

// Round 8
// 554.322 us; speedup vs baseline: 12.7649x; 1.2530x over previous
//
#include <hip/hip_runtime.h>
#include <math.h>

#define HH 128
#define WW 128
#define HWSZ 16384   // 128*128
#define CC 256
#define KK 64
#define BB 2

typedef __bf16 bf16x8_t __attribute__((ext_vector_type(8)));
typedef float  f32x4_t  __attribute__((ext_vector_type(4)));

__device__ __forceinline__ float silu_f(float v) { return v / (1.f + expf(-v)); }
__device__ __forceinline__ float sigm_f(float v) { return 1.f / (1.f + expf(-v)); }

__device__ __forceinline__ float b2f(unsigned short u) {
    union { unsigned int i; float f; } x; x.i = ((unsigned int)u) << 16; return x.f;
}
__device__ __forceinline__ unsigned short f2b(float f) {
    union { float f; unsigned int i; } x; x.f = f;
    unsigned int r = x.i + 0x7FFFu + ((x.i >> 16) & 1u);
    return (unsigned short)(r >> 16);
}

// ---------------------------------------------------------------------------
// prep: l0 NCHW fp32 -> NHWC bf16, LDS transpose. Block per (b,y).
// ---------------------------------------------------------------------------
__global__ __launch_bounds__(256) void cvt_nhwc_kernel(const float* __restrict__ in,
                                                       unsigned short* __restrict__ out) {
    __shared__ float T[32][128];
    const int tid = threadIdx.x;
    const int y = blockIdx.x & 127;
    const int b = blockIdx.x >> 7;
    const float* inb = in + (size_t)b * CC * HWSZ + y * 128;
    unsigned short* outb = out + ((size_t)b * HWSZ + (size_t)y * 128) * CC;

    for (int c0 = 0; c0 < CC; c0 += 32) {
        __syncthreads();
        {
            int cl = tid >> 3;          // 0..31
            int xq = tid & 7;           // 0..7 -> 4 float4 each
            const float4* src = (const float4*)(inb + (size_t)(c0 + cl) * HWSZ);
            float4* dst = (float4*)&T[cl][0];
            #pragma unroll
            for (int j = 0; j < 4; j++) dst[xq * 4 + j] = src[xq * 4 + j];
        }
        __syncthreads();
        {
            int x = tid & 127, ch = tid >> 7;   // 16 c each
            union { unsigned short u[16]; uint4 v[2]; } pk;
            #pragma unroll
            for (int j = 0; j < 16; j++) pk.u[j] = f2b(T[ch * 16 + j][x]);
            uint4* dst = (uint4*)&outb[(size_t)x * CC + c0 + ch * 16];
            dst[0] = pk.v[0];
            dst[1] = pk.v[1];
        }
    }
}

// ---------------------------------------------------------------------------
// prep: weights OIHW fp32 [256co][256ci][3][3] -> bf16 [8cb][9t][4g][256co][8e]
// ---------------------------------------------------------------------------
__global__ __launch_bounds__(256) void wprep_kernel(const float* __restrict__ w,
                                                    unsigned short* __restrict__ wt) {
    int idx = blockIdx.x * 256 + threadIdx.x;       // 0 .. 589823
    int e   = idx & 7;
    int co  = (idx >> 3) & 255;
    int g   = (idx >> 11) & 3;
    int v   = idx >> 13;                            // 0..71 = cb*9 + t
    int cb  = v / 9;
    int t   = v - cb * 9;
    wt[idx] = f2b(w[((size_t)co * 256 + cb * 32 + g * 8 + e) * 9 + t]);
}

// ---------------------------------------------------------------------------
// tracklet normalize
// ---------------------------------------------------------------------------
__global__ __launch_bounds__(128) void tnorm_kernel(const float* __restrict__ trk,
                                                    float* __restrict__ tn) {
    int r = threadIdx.x;
    if (r >= BB * KK) return;
    const float* p = trk + (size_t)r * CC;
    float ss = 0.f;
    for (int c = 0; c < CC; c++) { float v = p[c]; ss += v * v; }
    float sc = 1.f / fmaxf(sqrtf(ss), 1e-12f);
    float* q = tn + (size_t)r * CC;
    for (int c = 0; c < CC; c++) q[c] = p[c] * sc;
}

// ---------------------------------------------------------------------------
// ycorr: y[b,k,hw] = s_e[hw] * relu(dot(e_raw[hw], tn[k]))
// ---------------------------------------------------------------------------
#define EPAD 260
__global__ __launch_bounds__(256) void ycorr_kernel(const float* __restrict__ emb,
                                                    const float* __restrict__ tn,
                                                    float* __restrict__ y) {
    __shared__ __align__(16) float E[32 * EPAD];
    __shared__ __align__(16) float T[64 * EPAD];
    __shared__ float SE[32];

    const int tid = threadIdx.x;
    const int b   = blockIdx.y;
    const int hw0 = blockIdx.x * 32;

    const float4* esrc = (const float4*)(emb + ((size_t)b * HWSZ + hw0) * CC);
    #pragma unroll
    for (int i = 0; i < 8; i++) {
        int q  = tid + i * 256;
        int px = q >> 6, c4 = q & 63;
        *(float4*)&E[px * EPAD + c4 * 4] = esrc[(size_t)px * 64 + c4];
    }
    const float4* tsrc = (const float4*)(tn + (size_t)b * KK * CC);
    #pragma unroll
    for (int i = 0; i < 16; i++) {
        int q = tid + i * 256;
        int k = q >> 6, c4 = q & 63;
        *(float4*)&T[k * EPAD + c4 * 4] = tsrc[(size_t)k * 64 + c4];
    }
    __syncthreads();

    if (tid < 32) {
        float ss = 0.f;
        const float4* ep = (const float4*)&E[tid * EPAD];
        #pragma unroll 8
        for (int c4 = 0; c4 < 64; c4++) {
            float4 v = ep[c4];
            ss += v.x * v.x + v.y * v.y + v.z * v.z + v.w * v.w;
        }
        SE[tid] = 1.f / fmaxf(sqrtf(ss), 1e-12f);
    }
    __syncthreads();

    const int pg = tid & 15;
    const int kg = tid >> 4;

    float acc[2][4];
    #pragma unroll
    for (int j = 0; j < 2; j++)
        #pragma unroll
        for (int kk = 0; kk < 4; kk++) acc[j][kk] = 0.f;

    const float* E0 = &E[(0 * 16 + pg) * EPAD];
    const float* E1 = &E[(1 * 16 + pg) * EPAD];
    const float* T0 = &T[(0 * 16 + kg) * EPAD];
    const float* T1 = &T[(1 * 16 + kg) * EPAD];
    const float* T2 = &T[(2 * 16 + kg) * EPAD];
    const float* T3 = &T[(3 * 16 + kg) * EPAD];

    #pragma unroll 4
    for (int c4 = 0; c4 < 64; ++c4) {
        float4 e0 = *(const float4*)(E0 + c4 * 4);
        float4 e1 = *(const float4*)(E1 + c4 * 4);
        float4 t0 = *(const float4*)(T0 + c4 * 4);
        float4 t1 = *(const float4*)(T1 + c4 * 4);
        float4 t2 = *(const float4*)(T2 + c4 * 4);
        float4 t3 = *(const float4*)(T3 + c4 * 4);
        #define DOT4(a, t) (fmaf(a.w, t.w, fmaf(a.z, t.z, fmaf(a.y, t.y, a.x * t.x))))
        acc[0][0] += DOT4(e0, t0); acc[0][1] += DOT4(e0, t1);
        acc[0][2] += DOT4(e0, t2); acc[0][3] += DOT4(e0, t3);
        acc[1][0] += DOT4(e1, t0); acc[1][1] += DOT4(e1, t1);
        acc[1][2] += DOT4(e1, t2); acc[1][3] += DOT4(e1, t3);
        #undef DOT4
    }

    #pragma unroll
    for (int j = 0; j < 2; j++) {
        int px = j * 16 + pg;
        float se = SE[px];
        #pragma unroll
        for (int kk = 0; kk < 4; kk++) {
            int k = kk * 16 + kg;
            y[((size_t)b * KK + k) * HWSZ + hw0 + px] = fmaxf(acc[j][kk], 0.f) * se;
        }
    }
}

// ---------------------------------------------------------------------------
// first-occurrence argmax per (b,k)
// ---------------------------------------------------------------------------
__global__ __launch_bounds__(256) void argmax_kernel(const float* __restrict__ y,
                                                     int* __restrict__ idxout) {
    int bk = blockIdx.x;
    const float* p = y + (size_t)bk * HWSZ;
    int t = threadIdx.x;
    float best = -1.f; int bi = 1 << 30;
    for (int i = t; i < HWSZ; i += 256) {
        float v = p[i];
        if (v > best) { best = v; bi = i; }
    }
    __shared__ float sv[256];
    __shared__ int   si[256];
    sv[t] = best; si[t] = bi;
    __syncthreads();
    for (int s = 128; s > 0; s >>= 1) {
        if (t < s) {
            float v2 = sv[t + s]; int i2 = si[t + s];
            if (v2 > sv[t] || (v2 == sv[t] && i2 < si[t])) { sv[t] = v2; si[t] = i2; }
        }
        __syncthreads();
    }
    if (t == 0) idxout[bk] = si[0];
}

// ---------------------------------------------------------------------------
// s[b,hw] = sum_k y * mask
// ---------------------------------------------------------------------------
__global__ __launch_bounds__(256) void smap_kernel(const float* __restrict__ y,
                                                   const int* __restrict__ idx,
                                                   float* __restrict__ s) {
    int b  = blockIdx.y;
    int hw = blockIdx.x * 256 + threadIdx.x;
    int h  = hw >> 7, w = hw & 127;
    __shared__ int ai[KK], aj[KK];
    if (threadIdx.x < KK) {
        int v = idx[b * KK + threadIdx.x];
        ai[threadIdx.x] = v >> 7;
        aj[threadIdx.x] = v & 127;
    }
    __syncthreads();
    const float* yb = y + (size_t)b * KK * HWSZ;
    float acc = 0.f;
    #pragma unroll 8
    for (int k = 0; k < KK; k++) {
        float v = yb[(size_t)k * HWSZ + hw];
        bool in = (h >= ai[k] - 8) && (h < ai[k] + 8) && (w >= aj[k] - 8) && (w < aj[k] + 8);
        acc += in ? v : 0.f;
    }
    s[(size_t)b * HWSZ + hw] = acc;
}

__global__ __launch_bounds__(256) void smax_kernel(const float* __restrict__ s,
                                                   float* __restrict__ invmax) {
    int b = blockIdx.x;
    const float* p = s + (size_t)b * HWSZ;
    float m = -1e30f;
    for (int i = threadIdx.x; i < HWSZ; i += 256) m = fmaxf(m, p[i]);
    __shared__ float sm[256];
    sm[threadIdx.x] = m;
    __syncthreads();
    for (int st = 128; st > 0; st >>= 1) {
        if (threadIdx.x < st) sm[threadIdx.x] = fmaxf(sm[threadIdx.x], sm[threadIdx.x + st]);
        __syncthreads();
    }
    if (threadIdx.x == 0) invmax[b] = 1.f / sm[0];
}

// ---------------------------------------------------------------------------
// grouped deconvs, LDS-resident: one block per (b,g). NCHW bf16 out (addb).
// ---------------------------------------------------------------------------
__global__ __launch_bounds__(256) void deconv_kernel(const float* __restrict__ l1,
                                                     const float* __restrict__ l2,
                                                     const float* __restrict__ w2,
                                                     const float* __restrict__ w3,
                                                     unsigned short* __restrict__ out) {
    __shared__ float L1[2][64][64];
    __shared__ float L2[4][32][32];

    const int tid = threadIdx.x;
    const int g   = blockIdx.x & 255;
    const int b   = blockIdx.x >> 8;

    const float4* l1b = (const float4*)(l1 + ((size_t)b * 2 * CC + 2 * g) * 4096);
    float4* L1p = (float4*)&L1[0][0][0];
    #pragma unroll
    for (int i = 0; i < 8; i++) L1p[tid + i * 256] = l1b[tid + i * 256];
    const float4* l2b = (const float4*)(l2 + ((size_t)b * 4 * CC + 4 * g) * 1024);
    float4* L2p = (float4*)&L2[0][0][0];
    #pragma unroll
    for (int i = 0; i < 4; i++) L2p[tid + i * 256] = l2b[tid + i * 256];

    const int x    = tid & 127;
    const int ytop = tid >> 7;
    const float* w2g = w2 + (size_t)g * 32;
    const float* w3g = w3 + (size_t)g * 256;

    const int pxo = x & 1, pyo = ytop & 1;
    const int mx0 = (x + pxo - 2) >> 1;
    const int dy2 = (ytop + pyo - 2) >> 1;
    const bool nok0 = (unsigned)mx0 < 64u;
    const bool nok1 = (unsigned)(mx0 + 1) < 64u;
    const int nc0 = mx0 & 63, nc1 = (mx0 + 1) & 63;
    float W2[2][2][2];
    #pragma unroll
    for (int ci = 0; ci < 2; ci++)
        #pragma unroll
        for (int a = 0; a < 2; a++)
            #pragma unroll
            for (int c = 0; c < 2; c++)
                W2[ci][a][c] = w2g[ci * 16 + (pyo + 2 * a) * 4 + (pxo + 2 * c)];

    const int px3 = (5 - (x & 3)) & 3;
    const int n30 = (x + px3 - 5) >> 2;
    const bool n3ok0 = (unsigned)n30 < 32u;
    const bool n3ok1 = (unsigned)(n30 + 1) < 32u;
    const int n3c0 = n30 & 31, n3c1 = (n30 + 1) & 31;
    int dy3[2];
    float W3[2][4][2][2];
    #pragma unroll
    for (int ph = 0; ph < 2; ph++) {
        int py3 = (5 - ((ytop + 2 * ph) & 3)) & 3;
        dy3[ph] = (2 * ph + ytop + py3 - 5) >> 2;
        #pragma unroll
        for (int ci = 0; ci < 4; ci++)
            #pragma unroll
            for (int a = 0; a < 2; a++)
                #pragma unroll
                for (int c = 0; c < 2; c++)
                    W3[ph][ci][a][c] = w3g[ci * 64 + (py3 + 4 * a) * 8 + (px3 + 4 * c)];
    }

    __syncthreads();

    unsigned short* outb = out + ((size_t)b * CC + g) * HWSZ;

    #pragma unroll 2
    for (int ii = 0; ii < 32; ++ii) {
        #pragma unroll
        for (int ph = 0; ph < 2; ph++) {
            const int i = 2 * ii + ph;
            float acc = 0.f;
            {
                const int m0 = i + dy2;
                #pragma unroll
                for (int a = 0; a < 2; a++) {
                    int m = m0 + a;
                    bool mok = (unsigned)m < 64u;
                    int mc = m & 63;
                    #pragma unroll
                    for (int ci = 0; ci < 2; ci++) {
                        float v0 = (mok && nok0) ? L1[ci][mc][nc0] : 0.f;
                        float v1 = (mok && nok1) ? L1[ci][mc][nc1] : 0.f;
                        acc = fmaf(W2[ci][a][0], v0, acc);
                        acc = fmaf(W2[ci][a][1], v1, acc);
                    }
                }
            }
            {
                const int m0 = ii + dy3[ph];
                #pragma unroll
                for (int a = 0; a < 2; a++) {
                    int m = m0 + a;
                    bool mok = (unsigned)m < 32u;
                    int mc = m & 31;
                    #pragma unroll
                    for (int ci = 0; ci < 4; ci++) {
                        float v0 = (mok && n3ok0) ? L2[ci][mc][n3c0] : 0.f;
                        float v1 = (mok && n3ok1) ? L2[ci][mc][n3c1] : 0.f;
                        acc = fmaf(W3[ph][ci][a][0], v0, acc);
                        acc = fmaf(W3[ph][ci][a][1], v1, acc);
                    }
                }
            }
            outb[(size_t)i * 256 + tid] = f2b(acc);
        }
    }
}

// ---------------------------------------------------------------------------
// BIG conv 256->256 3x3, bf16 MFMA implicit GEMM, NHWC activations.
// ---------------------------------------------------------------------------
template <int ADDB>
__global__ __launch_bounds__(256, 2) void conv_mfma_kernel(
    const unsigned short* __restrict__ in,    // bf16 NHWC
    const unsigned short* __restrict__ wt,    // bf16 [8cb][9t][4g][256co][8e]
    const float* __restrict__ bias,
    const unsigned short* __restrict__ addb,  // bf16 NCHW (ADDB=1)
    unsigned short* __restrict__ out)         // bf16 NHWC
{
    __shared__ __align__(16) unsigned short Alds[3 * 130 * 40];        // 31200 B
    __shared__ __align__(16) unsigned short Blds[2 * 3 * 4 * 128 * 8]; // 49152 B

    const int tid  = threadIdx.x;
    const int lane = tid & 63;
    const int wv   = tid >> 6;
    const int wco  = wv >> 1;
    const int wpx  = wv & 1;
    const int l15  = lane & 15;
    const int kg   = lane >> 4;

    const int y0  = blockIdx.x;
    const int co0 = blockIdx.y * 128;
    const int b   = blockIdx.z;

    const unsigned short* inb = in + (size_t)b * HWSZ * CC;

    int pixbase[4], wbase[4];
    #pragma unroll
    for (int f = 0; f < 4; f++) {
        int x = wpx * 64 + f * 16 + l15;
        pixbase[f] = x * 40 + kg * 8;
        int crl = wco * 64 + f * 16 + l15;
        wbase[f] = (kg * 128 + crl) * 8;
    }

    f32x4_t acc[4][4];
    #pragma unroll
    for (int i = 0; i < 4; i++)
        #pragma unroll
        for (int j = 0; j < 4; j++)
            acc[i][j] = (f32x4_t){0.f, 0.f, 0.f, 0.f};

    auto stage_A = [&](int cb) {
        for (int q = tid; q < 1560; q += 256) {
            int q4 = q & 3;
            int rp = q >> 2;            // 0..389
            int px = rp % 130;
            int r  = rp / 130;
            int gy = y0 - 1 + r;
            int gx = px - 1;
            uint4 v = make_uint4(0u, 0u, 0u, 0u);
            if (((unsigned)gy < 128u) && ((unsigned)gx < 128u))
                v = *reinterpret_cast<const uint4*>(
                        inb + ((size_t)(gy * 128 + gx)) * CC + cb * 32 + q4 * 8);
            *reinterpret_cast<uint4*>(&Alds[(r * 130 + px) * 40 + q4 * 8]) = v;
        }
    };
    auto stage_B = [&](int cb_, int ky_, int par_) {
        #pragma unroll
        for (int i = 0; i < 6; i++) {
            int c    = tid + i * 256;
            int tl   = c >> 9;
            int rest = c & 511;
            size_t src = (((size_t)((cb_ * 9 + ky_ * 3 + tl) * 4) + (rest >> 7)) * 256
                          + co0 + (rest & 127)) * 8;
            *reinterpret_cast<uint4*>(&Blds[par_ * 12288 + c * 8]) =
                *reinterpret_cast<const uint4*>(wt + src);
        }
    };

    stage_B(0, 0, 0);
    for (int cb = 0; cb < 8; ++cb) {
        #pragma unroll
        for (int ky = 0; ky < 3; ++ky) {
            const int par = (cb + ky) & 1;
            __syncthreads();
            if (ky == 0) stage_A(cb);
            if (!(cb == 7 && ky == 2)) {
                int cbn = (ky == 2) ? cb + 1 : cb;
                int kyn = (ky == 2) ? 0 : ky + 1;
                stage_B(cbn, kyn, par ^ 1);
            }
            if (ky == 0) __syncthreads();

            #pragma unroll
            for (int tl = 0; tl < 3; ++tl) {
                const int aoff = (ky * 130 + tl) * 40;
                const int boff = par * 12288 + tl * 4096;
                bf16x8_t pfr[4], wfr[4];
                #pragma unroll
                for (int f = 0; f < 4; f++)
                    pfr[f] = *reinterpret_cast<const bf16x8_t*>(&Alds[pixbase[f] + aoff]);
                #pragma unroll
                for (int f = 0; f < 4; f++)
                    wfr[f] = *reinterpret_cast<const bf16x8_t*>(&Blds[boff + wbase[f]]);
                #pragma unroll
                for (int cf = 0; cf < 4; cf++)
                    #pragma unroll
                    for (int pf = 0; pf < 4; pf++)
                        acc[cf][pf] = __builtin_amdgcn_mfma_f32_16x16x32_bf16(
                            wfr[cf], pfr[pf], acc[cf][pf], 0, 0, 0);
            }
        }
    }

    // epilogue: NHWC, lane writes 4 consecutive co (8B) per (cf,pf)
    size_t outB = ((size_t)b * HWSZ + (size_t)y0 * 128) * CC;
    #pragma unroll
    for (int cf = 0; cf < 4; cf++) {
        int co = co0 + wco * 64 + cf * 16 + kg * 4;
        float bs0 = bias[co], bs1 = bias[co + 1], bs2 = bias[co + 2], bs3 = bias[co + 3];
        #pragma unroll
        for (int pf = 0; pf < 4; pf++) {
            int x = wpx * 64 + pf * 16 + l15;
            float v0 = silu_f(acc[cf][pf][0] + bs0);
            float v1 = silu_f(acc[cf][pf][1] + bs1);
            float v2 = silu_f(acc[cf][pf][2] + bs2);
            float v3 = silu_f(acc[cf][pf][3] + bs3);
            if (ADDB) {
                size_t ab = ((size_t)b * CC + co) * HWSZ + (size_t)y0 * 128 + x;
                v0 += b2f(addb[ab]);
                v1 += b2f(addb[ab + HWSZ]);
                v2 += b2f(addb[ab + 2 * HWSZ]);
                v3 += b2f(addb[ab + 3 * HWSZ]);
            }
            union { unsigned short u[4]; uint2 v; } pk;
            pk.u[0] = f2b(v0); pk.u[1] = f2b(v1); pk.u[2] = f2b(v2); pk.u[3] = f2b(v3);
            *reinterpret_cast<uint2*>(&out[outB + (size_t)x * CC + co]) = pk.v;
        }
    }
}

// ---------------------------------------------------------------------------
// conv 1->256 (input = s * invmax), + bias, silu -> bf16 NHWC.
// Block: 32 px x 8 co-groups of 32 channels each (FULL 256 co coverage).
// ---------------------------------------------------------------------------
__global__ __launch_bounds__(256) void conv_c1a_kernel(const float* __restrict__ s,
                                                       const float* __restrict__ invmax,
                                                       const float* __restrict__ w,
                                                       const float* __restrict__ bias,
                                                       unsigned short* __restrict__ out) {
    __shared__ float W[2304];
    __shared__ float S[3][34];

    const int tid = threadIdx.x;
    const int idx = blockIdx.x;            // 0..1023
    const int b   = idx >> 9;
    const int seg = idx & 511;
    const int y   = seg >> 2;
    const int x0  = (seg & 3) * 32;

    for (int i = tid; i < 2304; i += 256) W[i] = w[i];
    if (tid < 102) {
        int r = tid / 34, xx = tid - r * 34;
        int gy = y - 1 + r, gx = x0 - 1 + xx;
        S[r][xx] = ((unsigned)gy < 128u && (unsigned)gx < 128u)
                       ? s[(size_t)b * HWSZ + gy * 128 + gx] : 0.f;
    }
    __syncthreads();

    const float im = invmax[b];
    const int cog = tid >> 5;      // 0..7 -> channels cog*32 .. cog*32+31
    const int px  = tid & 31;

    float sv[9];
    #pragma unroll
    for (int r = 0; r < 3; r++)
        #pragma unroll
        for (int d = 0; d < 3; d++)
            sv[r * 3 + d] = S[r][px + d];

    unsigned short* op =
        &out[((size_t)b * HWSZ + (size_t)y * 128 + x0 + px) * CC + cog * 32];
    #pragma unroll
    for (int q = 0; q < 4; q++) {
        union { unsigned short u[8]; uint4 v; } pk;
        #pragma unroll
        for (int j = 0; j < 8; j++) {
            int co = cog * 32 + q * 8 + j;
            float a = 0.f;
            #pragma unroll
            for (int t = 0; t < 9; t++) a = fmaf(W[co * 9 + t], sv[t], a);
            pk.u[j] = f2b(silu_f(a * im + bias[co]));
        }
        *reinterpret_cast<uint4*>(op + q * 8) = pk.v;
    }
}

// ---------------------------------------------------------------------------
// Small conv 256 -> COUT (1 or 4), NHWC bf16 input, fp32 weights OIHW.
// Wave = 2 px; lane = (ps, c32). Coalesced row reads, LDS weights, shfl reduce.
// MODE 0: NHWC float4 (c2box). MODE 1: fp32 plane. MODE 2: sigmoid plane.
// ---------------------------------------------------------------------------
template <int COUT, int MODE>
__global__ __launch_bounds__(256) void small_conv_kernel(
    const unsigned short* __restrict__ in,   // NHWC bf16
    const float* __restrict__ w,             // [COUT][256][3][3]
    const float* __restrict__ bias,
    float* __restrict__ out)
{
    __shared__ float WL[COUT * 9 * 32 * 12];

    const int tid = threadIdx.x;
    for (int i = tid; i < COUT * 2304; i += 256) {
        int e = i & 7;
        int g = (i >> 3) & 31;
        int rest = i >> 8;              // 0 .. 9*COUT-1
        int t = rest % 9;
        int co = rest / 9;
        WL[((co * 9 + t) * 32 + g) * 12 + e] = w[((size_t)co * 256 + g * 8 + e) * 9 + t];
    }
    __syncthreads();

    const int lane = tid & 63;
    const int wv   = tid >> 6;
    const int c32  = lane & 31;
    const int ps   = lane >> 5;
    const int pixg = blockIdx.x * 8 + wv * 2 + ps;   // 0..32767
    const int b    = pixg >> 14;
    const int pix  = pixg & (HWSZ - 1);
    const int y    = pix >> 7, x = pix & 127;

    const unsigned short* inb = in + (size_t)b * HWSZ * CC;

    float acc[COUT];
    #pragma unroll
    for (int c = 0; c < COUT; c++) acc[c] = 0.f;

    #pragma unroll
    for (int t = 0; t < 9; t++) {
        int dy = t / 3 - 1, dx = t % 3 - 1;
        int gy = y + dy, gx = x + dx;
        if ((unsigned)gy < 128u && (unsigned)gx < 128u) {
            union { unsigned short u[8]; uint4 v; } d;
            d.v = *reinterpret_cast<const uint4*>(
                      inb + ((size_t)(gy * 128 + gx)) * CC + c32 * 8);
            float f[8];
            #pragma unroll
            for (int e = 0; e < 8; e++) f[e] = b2f(d.u[e]);
            #pragma unroll
            for (int co = 0; co < COUT; co++) {
                int base = ((co * 9 + t) * 32 + c32) * 12;
                float4 wa = *(const float4*)&WL[base];
                float4 wb = *(const float4*)&WL[base + 4];
                float a = acc[co];
                a = fmaf(f[0], wa.x, a); a = fmaf(f[1], wa.y, a);
                a = fmaf(f[2], wa.z, a); a = fmaf(f[3], wa.w, a);
                a = fmaf(f[4], wb.x, a); a = fmaf(f[5], wb.y, a);
                a = fmaf(f[6], wb.z, a); a = fmaf(f[7], wb.w, a);
                acc[co] = a;
            }
        }
    }

    #pragma unroll
    for (int m = 1; m <= 16; m <<= 1)
        #pragma unroll
        for (int co = 0; co < COUT; co++)
            acc[co] += __shfl_xor(acc[co], m);

    if (c32 == 0) {
        size_t pixidx = (size_t)b * HWSZ + pix;
        if (MODE == 0) {
            ((float4*)out)[pixidx] = make_float4(acc[0] + bias[0],
                                                 acc[COUT > 1 ? 1 : 0] + bias[COUT > 1 ? 1 : 0],
                                                 acc[COUT > 2 ? 2 : 0] + bias[COUT > 2 ? 2 : 0],
                                                 acc[COUT > 3 ? 3 : 0] + bias[COUT > 3 ? 3 : 0]);
        } else if (MODE == 1) {
            out[pixidx] = acc[0] + bias[0];
        } else {
            out[pixidx] = sigm_f(acc[0] + bias[0]);
        }
    }
}

// ---------------------------------------------------------------------------
// t = xf(fp32,[b,hw]) * xd(bf16 NHWC) -> bf16 NHWC
// ---------------------------------------------------------------------------
__global__ __launch_bounds__(256) void mul_kernel(const float* __restrict__ xf,
                                                  const unsigned short* __restrict__ xd,
                                                  unsigned short* __restrict__ out) {
    size_t base = ((size_t)blockIdx.x * 256 + threadIdx.x) * 8;
    int b   = (int)(base >> 22);
    int pix = (int)((base >> 8) & (HWSZ - 1));
    float f = xf[(size_t)b * HWSZ + pix];
    union { unsigned short u[8]; uint4 v; } d, r;
    d.v = *(const uint4*)(xd + base);
    #pragma unroll
    for (int e = 0; e < 8; e++) r.u[e] = f2b(b2f(d.u[e]) * f);
    *(uint4*)(out + base) = r.v;
}

// ---------------------------------------------------------------------------
extern "C" void kernel_launch(void* const* d_in, const int* in_sizes, int n_in,
                              void* d_out, int out_size, void* d_ws, size_t ws_size,
                              hipStream_t stream) {
    const float* emb    = (const float*)d_in[0];
    const float* trk    = (const float*)d_in[1];
    const float* l0     = (const float*)d_in[2];
    const float* l1     = (const float*)d_in[3];
    const float* l2     = (const float*)d_in[4];
    const float* b_p1w  = (const float*)d_in[5];
    const float* b_p1b  = (const float*)d_in[6];
    const float* b_p2w  = (const float*)d_in[7];
    const float* b_p3w  = (const float*)d_in[8];
    const float* b_c1w  = (const float*)d_in[9];
    const float* b_c1b  = (const float*)d_in[10];
    const float* b_c2w  = (const float*)d_in[11];
    const float* b_c2b  = (const float*)d_in[12];
    const float* h_p1w  = (const float*)d_in[13];
    const float* h_p1b  = (const float*)d_in[14];
    const float* h_p2w  = (const float*)d_in[15];
    const float* h_p3w  = (const float*)d_in[16];
    const float* h_c1aw = (const float*)d_in[17];
    const float* h_c1ab = (const float*)d_in[18];
    const float* h_c1bw = (const float*)d_in[19];
    const float* h_c1bb = (const float*)d_in[20];
    const float* h_c2aw = (const float*)d_in[21];
    const float* h_c2ab = (const float*)d_in[22];
    const float* h_c2bw = (const float*)d_in[23];
    const float* h_c2bb = (const float*)d_in[24];
    const float* h_c2cw = (const float*)d_in[25];
    const float* h_c2cb = (const float*)d_in[26];

    float* outp = (float*)d_out;   // [0,32768): hmmap ; [32768,163840): siambox NHWC

    const size_t ACT = (size_t)BB * CC * HWSZ;   // 8,388,608 elems
    const size_t WT  = 9 * 8 * 256 * 32;         // 589,824 elems

    unsigned short* l0nh = (unsigned short*)d_ws;
    unsigned short* wt0  = l0nh + ACT;
    unsigned short* wt1  = wt0 + WT;
    unsigned short* wt2  = wt1 + WT;
    unsigned short* wt3  = wt2 + WT;
    unsigned short* wt4  = wt3 + WT;
    unsigned short* Db   = wt4 + WT;
    unsigned short* X1   = Db + ACT;
    unsigned short* X2   = X1 + ACT;
    float* sbuf   = (float*)(X2 + ACT);
    float* xfb    = sbuf + (size_t)BB * HWSZ;
    float* tn     = xfb + (size_t)BB * HWSZ;
    float* invmax = tn + (size_t)BB * KK * CC;
    int*   idxb   = (int*)(invmax + 2);
    float* ybuf   = (float*)X1;   // alias: y consumed before X1 first written

    dim3 grdConvM(128, 2, 2);

    // ---- preps ----
    cvt_nhwc_kernel<<<BB * 128, 256, 0, stream>>>(l0, l0nh);
    wprep_kernel<<<(unsigned)(WT / 256), 256, 0, stream>>>(b_p1w, wt0);
    wprep_kernel<<<(unsigned)(WT / 256), 256, 0, stream>>>(b_c1w, wt1);
    wprep_kernel<<<(unsigned)(WT / 256), 256, 0, stream>>>(h_p1w, wt2);
    wprep_kernel<<<(unsigned)(WT / 256), 256, 0, stream>>>(h_c2aw, wt3);
    wprep_kernel<<<(unsigned)(WT / 256), 256, 0, stream>>>(h_c2bw, wt4);

    // ---- correlation map ----
    tnorm_kernel<<<1, 128, 0, stream>>>(trk, tn);
    ycorr_kernel<<<dim3(512, BB), 256, 0, stream>>>(emb, tn, ybuf);
    argmax_kernel<<<BB * KK, 256, 0, stream>>>(ybuf, idxb);
    smap_kernel<<<dim3(64, BB), 256, 0, stream>>>(ybuf, idxb, sbuf);
    smax_kernel<<<BB, 256, 0, stream>>>(sbuf, invmax);

    // ---- box head ----
    deconv_kernel<<<BB * CC, 256, 0, stream>>>(l1, l2, b_p2w, b_p3w, Db);
    conv_mfma_kernel<1><<<grdConvM, 256, 0, stream>>>(l0nh, wt0, b_p1b, Db, X1);     // xd_box
    conv_mfma_kernel<0><<<grdConvM, 256, 0, stream>>>(X1, wt1, b_c1b, nullptr, X2);  // xb
    small_conv_kernel<4, 0><<<4096, 256, 0, stream>>>(X2, b_c2w, b_c2b, outp + BB * HWSZ);

    // ---- heatmap head ----
    deconv_kernel<<<BB * CC, 256, 0, stream>>>(l1, l2, h_p2w, h_p3w, Db);
    conv_mfma_kernel<1><<<grdConvM, 256, 0, stream>>>(l0nh, wt2, h_p1b, Db, X1);     // xd_hm
    conv_c1a_kernel<<<1024, 256, 0, stream>>>(sbuf, invmax, h_c1aw, h_c1ab, X2);     // t1
    small_conv_kernel<1, 1><<<4096, 256, 0, stream>>>(X2, h_c1bw, h_c1bb, xfb);      // xf
    mul_kernel<<<4096, 256, 0, stream>>>(xfb, X1, X2);                               // t
    conv_mfma_kernel<0><<<grdConvM, 256, 0, stream>>>(X2, wt3, h_c2ab, nullptr, Db); // t2
    conv_mfma_kernel<0><<<grdConvM, 256, 0, stream>>>(Db, wt4, h_c2bb, nullptr, X1); // t3
    small_conv_kernel<1, 2><<<4096, 256, 0, stream>>>(X1, h_c2cw, h_c2cb, outp);     // hmmap
}